// Round 1
// baseline (1064.458 us; speedup 1.0000x reference)
//
#include <hip/hip_runtime.h>

#define B_TOT 4096
#define SDIM  1200
#define NA    32
#define NH    8
#define EMB   64
#define KHID  128
#define HYP   256
#define NSEL  2048   // NH*HYP
#define NTOT  2560   // NSEL + 256 (wh hid) + 256 (v hid)

// workspace layout (float offsets)
#define WS_H1  0
#define WS_M   (WS_H1 + (size_t)B_TOT * NTOT)            // 10,485,760
#define WS_WH  (WS_M  + (size_t)B_TOT * NH * KHID)       // +4,194,304
#define WS_V   (WS_WH + (size_t)B_TOT * NH)
#define WS_LG  (WS_V  + (size_t)B_TOT)
#define WS_ACC (WS_LG + (size_t)B_TOT * NH * NA)         // 16 floats of accumulators

__global__ void k_zero(float* __restrict__ acc) {
    if (threadIdx.x < 16) acc[threadIdx.x] = 0.0f;
}

// ---------------------------------------------------------------------------
// K1: fused hypernet first layers.
// h1_all[b][n] = relu( states[b]·W[n] + bias[n] ), n<2048: sel_W1 (h=n/256,e=n%256),
// 2048..2303: wh_W1, 2304..2559: v_W1.  GEMM M=4096 N=2560 K=1200, 128x128 tile,
// 256 threads, 8x8 per thread, BK=16.
// ---------------------------------------------------------------------------
__global__ __launch_bounds__(256) void k_gemm1(
    const float* __restrict__ states,
    const float* __restrict__ sel_W1, const float* __restrict__ sel_b1,
    const float* __restrict__ wh_W1,  const float* __restrict__ wh_b1,
    const float* __restrict__ v_W1,   const float* __restrict__ v_b1,
    float* __restrict__ h1_all)
{
    __shared__ __align__(16) float As[16][132];
    __shared__ __align__(16) float Bs[16][132];
    const int tid  = threadIdx.x;
    const int tx   = tid & 15;        // N sub-tile
    const int ty   = tid >> 4;        // M sub-tile
    const int row_l = tid >> 1;       // 0..127 staging row
    const int col8  = (tid & 1) * 8;  // 0 or 8 staging col
    const int arow = blockIdx.y * 128 + row_l;
    const int nrow = blockIdx.x * 128 + row_l;
    const float* wptr = (nrow < NSEL)       ? (sel_W1 + (size_t)nrow * SDIM)
                      : (nrow < NSEL + HYP) ? (wh_W1 + (size_t)(nrow - NSEL) * SDIM)
                                            : (v_W1  + (size_t)(nrow - NSEL - HYP) * SDIM);
    const float* aptr = states + (size_t)arow * SDIM;

    float c[8][8] = {};
    for (int k0 = 0; k0 < SDIM; k0 += 16) {
        float4 a0 = *(const float4*)(aptr + k0 + col8);
        float4 a1 = *(const float4*)(aptr + k0 + col8 + 4);
        float4 b0 = *(const float4*)(wptr + k0 + col8);
        float4 b1 = *(const float4*)(wptr + k0 + col8 + 4);
        As[col8 + 0][row_l] = a0.x; As[col8 + 1][row_l] = a0.y;
        As[col8 + 2][row_l] = a0.z; As[col8 + 3][row_l] = a0.w;
        As[col8 + 4][row_l] = a1.x; As[col8 + 5][row_l] = a1.y;
        As[col8 + 6][row_l] = a1.z; As[col8 + 7][row_l] = a1.w;
        Bs[col8 + 0][row_l] = b0.x; Bs[col8 + 1][row_l] = b0.y;
        Bs[col8 + 2][row_l] = b0.z; Bs[col8 + 3][row_l] = b0.w;
        Bs[col8 + 4][row_l] = b1.x; Bs[col8 + 5][row_l] = b1.y;
        Bs[col8 + 6][row_l] = b1.z; Bs[col8 + 7][row_l] = b1.w;
        __syncthreads();
        #pragma unroll
        for (int kk = 0; kk < 16; ++kk) {
            float4 x0 = *(const float4*)&As[kk][ty * 8];
            float4 x1 = *(const float4*)&As[kk][ty * 8 + 4];
            float4 y0 = *(const float4*)&Bs[kk][tx * 8];
            float4 y1 = *(const float4*)&Bs[kk][tx * 8 + 4];
            float am[8] = {x0.x, x0.y, x0.z, x0.w, x1.x, x1.y, x1.z, x1.w};
            float bn[8] = {y0.x, y0.y, y0.z, y0.w, y1.x, y1.y, y1.z, y1.w};
            #pragma unroll
            for (int i = 0; i < 8; ++i)
                #pragma unroll
                for (int j = 0; j < 8; ++j)
                    c[i][j] = fmaf(am[i], bn[j], c[i][j]);
        }
        __syncthreads();
    }

    const int colbase = blockIdx.x * 128 + tx * 8;   // segment boundaries are /8 aligned
    const float* bptr = (colbase < NSEL)       ? (sel_b1 + colbase)
                      : (colbase < NSEL + HYP) ? (wh_b1 + colbase - NSEL)
                                               : (v_b1  + colbase - NSEL - HYP);
    float bias[8];
    #pragma unroll
    for (int j = 0; j < 8; ++j) bias[j] = bptr[j];
    #pragma unroll
    for (int i = 0; i < 8; ++i) {
        const int row = blockIdx.y * 128 + ty * 8 + i;
        float4 o0, o1;
        o0.x = fmaxf(c[i][0] + bias[0], 0.f); o0.y = fmaxf(c[i][1] + bias[1], 0.f);
        o0.z = fmaxf(c[i][2] + bias[2], 0.f); o0.w = fmaxf(c[i][3] + bias[3], 0.f);
        o1.x = fmaxf(c[i][4] + bias[4], 0.f); o1.y = fmaxf(c[i][5] + bias[5], 0.f);
        o1.z = fmaxf(c[i][6] + bias[6], 0.f); o1.w = fmaxf(c[i][7] + bias[7], 0.f);
        *(float4*)(h1_all + (size_t)row * NTOT + colbase)     = o0;
        *(float4*)(h1_all + (size_t)row * NTOT + colbase + 4) = o1;
    }
}

// ---------------------------------------------------------------------------
// K2: second layers, 4 batch rows per block.
//   sel[h][d] = sum_e h1[h*256+e] * sel_W2[h][d][e]          (kept in LDS)
//   m[h][k]   = sum_d sel[h][d] * key_W2[h][d][k]            -> global
//   wh[h]     = abs(sum_e whh[e]*wh_W2[h][e] + wh_b2[h])     -> global
//   v         = sum_e vh[e]*v_W2[e] + v_b2                   -> global
// ---------------------------------------------------------------------------
#define BT 4
__global__ __launch_bounds__(256) void k_second(
    const float* __restrict__ h1_all, const float* __restrict__ sel_W2,
    const float* __restrict__ key_W2, const float* __restrict__ wh_W2,
    const float* __restrict__ wh_b2,  const float* __restrict__ v_W2,
    const float* __restrict__ v_b2,
    float* __restrict__ m_out, float* __restrict__ wh_out, float* __restrict__ v_out)
{
    __shared__ __align__(16) float rowbuf[BT][NTOT];
    __shared__ __align__(16) float sel_lds[BT][NH * EMB];
    const int t  = threadIdx.x;
    const int b0 = blockIdx.x * BT;

    #pragma unroll
    for (int bi = 0; bi < BT; ++bi)
        #pragma unroll
        for (int j = 0; j < NTOT / 256; ++j)
            rowbuf[bi][j * 256 + t] = h1_all[(size_t)(b0 + bi) * NTOT + j * 256 + t];
    __syncthreads();

    // sel: 512 outputs, 2 per thread (h wave-uniform -> broadcast LDS reads)
    #pragma unroll
    for (int rep = 0; rep < 2; ++rep) {
        const int o = t + rep * 256;
        const int h = o >> 6, d = o & 63;
        const float* w = sel_W2 + (size_t)(h * EMB + d) * HYP;
        float acc0 = 0.f, acc1 = 0.f, acc2 = 0.f, acc3 = 0.f;
        for (int e = 0; e < HYP; e += 4) {
            float4 wv = *(const float4*)(w + e);
            float4 r0 = *(const float4*)&rowbuf[0][h * HYP + e];
            float4 r1 = *(const float4*)&rowbuf[1][h * HYP + e];
            float4 r2 = *(const float4*)&rowbuf[2][h * HYP + e];
            float4 r3 = *(const float4*)&rowbuf[3][h * HYP + e];
            acc0 += r0.x * wv.x + r0.y * wv.y + r0.z * wv.z + r0.w * wv.w;
            acc1 += r1.x * wv.x + r1.y * wv.y + r1.z * wv.z + r1.w * wv.w;
            acc2 += r2.x * wv.x + r2.y * wv.y + r2.z * wv.z + r2.w * wv.w;
            acc3 += r3.x * wv.x + r3.y * wv.y + r3.z * wv.z + r3.w * wv.w;
        }
        sel_lds[0][o] = acc0; sel_lds[1][o] = acc1;
        sel_lds[2][o] = acc2; sel_lds[3][o] = acc3;
    }
    __syncthreads();

    // m: 1024 outputs, 4 per thread; key_W2 reads coalesced over k
    #pragma unroll
    for (int jj = 0; jj < 4; ++jj) {
        const int o = t + jj * 256;
        const int h = o >> 7, k = o & 127;
        float acc0 = 0.f, acc1 = 0.f, acc2 = 0.f, acc3 = 0.f;
        for (int d = 0; d < EMB; ++d) {
            const float wv = key_W2[(size_t)(h * EMB + d) * KHID + k];
            acc0 = fmaf(sel_lds[0][h * EMB + d], wv, acc0);
            acc1 = fmaf(sel_lds[1][h * EMB + d], wv, acc1);
            acc2 = fmaf(sel_lds[2][h * EMB + d], wv, acc2);
            acc3 = fmaf(sel_lds[3][h * EMB + d], wv, acc3);
        }
        m_out[((size_t)(b0 + 0) * NH + h) * KHID + k] = acc0;
        m_out[((size_t)(b0 + 1) * NH + h) * KHID + k] = acc1;
        m_out[((size_t)(b0 + 2) * NH + h) * KHID + k] = acc2;
        m_out[((size_t)(b0 + 3) * NH + h) * KHID + k] = acc3;
    }

    if (t < 32) {
        const int bi = t >> 3, h = t & 7;
        float a = 0.f;
        for (int e = 0; e < HYP; ++e)
            a = fmaf(rowbuf[bi][NSEL + e], wh_W2[h * HYP + e], a);
        wh_out[(b0 + bi) * NH + h] = fabsf(a + wh_b2[h]);
    } else if (t < 36) {
        const int bi = t - 32;
        float a = 0.f;
        for (int e = 0; e < HYP; ++e)
            a = fmaf(rowbuf[bi][NSEL + 256 + e], v_W2[e], a);
        v_out[b0 + bi] = a + v_b2[0];
    }
}

// ---------------------------------------------------------------------------
// K3: logits[b,h,a] = sum_k relu(units[b,a]·key_W1[h,k] + key_b1[h,k]) * m[b,h,k]
// One wave per (b,h). Lane t caches key_W1 rows t and t+64 in registers; units
// rows broadcast from LDS; butterfly-reduce over 64 lanes per agent.
// ---------------------------------------------------------------------------
#define DOT4(Q, I)                                         \
    d0 = fmaf(Q.x, w0[I],     d0); d1 = fmaf(Q.x, w1[I],     d1); \
    d0 = fmaf(Q.y, w0[(I)+1], d0); d1 = fmaf(Q.y, w1[(I)+1], d1); \
    d0 = fmaf(Q.z, w0[(I)+2], d0); d1 = fmaf(Q.z, w1[(I)+2], d1); \
    d0 = fmaf(Q.w, w0[(I)+3], d0); d1 = fmaf(Q.w, w1[(I)+3], d1);

__global__ __launch_bounds__(64) void k_logits(
    const float* __restrict__ states, const float* __restrict__ agent_qs,
    const float* __restrict__ key_W1, const float* __restrict__ key_b1,
    const float* __restrict__ m_in, float* __restrict__ logits)
{
    __shared__ float W1s[128 * 33];
    __shared__ __align__(16) float units[32][36];
    const int t = threadIdx.x;
    const int b = blockIdx.x, h = blockIdx.y;

    const float* W1g = key_W1 + (size_t)h * 128 * 33;
    for (int j = 0; j < 66; ++j) W1s[j * 64 + t] = W1g[j * 64 + t];
    {
        const float* srow = states + (size_t)b * SDIM;
        const int a = t >> 1, u0 = (t & 1) * 16;
        float4 x0 = *(const float4*)(srow + a * 32 + u0);
        float4 x1 = *(const float4*)(srow + a * 32 + u0 + 4);
        float4 x2 = *(const float4*)(srow + a * 32 + u0 + 8);
        float4 x3 = *(const float4*)(srow + a * 32 + u0 + 12);
        *(float4*)&units[a][u0]      = x0;
        *(float4*)&units[a][u0 + 4]  = x1;
        *(float4*)&units[a][u0 + 8]  = x2;
        *(float4*)&units[a][u0 + 12] = x3;
        if (t < NA) units[t][32] = agent_qs[(size_t)b * NA + t];
    }
    const float b1r0 = key_b1[h * 128 + t];
    const float b1r1 = key_b1[h * 128 + 64 + t];
    const float m0 = m_in[((size_t)b * NH + h) * KHID + t];
    const float m1 = m_in[((size_t)b * NH + h) * KHID + 64 + t];
    __syncthreads();

    float w0[33], w1[33];
    #pragma unroll
    for (int u = 0; u < 33; ++u) {
        w0[u] = W1s[t * 33 + u];
        w1[u] = W1s[(t + 64) * 33 + u];
    }

    float myLogit = 0.f;
    #pragma unroll
    for (int a = 0; a < NA; ++a) {
        float4 ua0 = *(const float4*)&units[a][0];
        float4 ua1 = *(const float4*)&units[a][4];
        float4 ua2 = *(const float4*)&units[a][8];
        float4 ua3 = *(const float4*)&units[a][12];
        float4 ua4 = *(const float4*)&units[a][16];
        float4 ua5 = *(const float4*)&units[a][20];
        float4 ua6 = *(const float4*)&units[a][24];
        float4 ua7 = *(const float4*)&units[a][28];
        const float uq = units[a][32];
        float d0 = b1r0, d1 = b1r1;
        DOT4(ua0, 0)  DOT4(ua1, 4)  DOT4(ua2, 8)  DOT4(ua3, 12)
        DOT4(ua4, 16) DOT4(ua5, 20) DOT4(ua6, 24) DOT4(ua7, 28)
        d0 = fmaf(uq, w0[32], d0);
        d1 = fmaf(uq, w1[32], d1);
        d0 = fmaxf(d0, 0.f);
        d1 = fmaxf(d1, 0.f);
        float p = fmaf(d0, m0, d1 * m1);
        p += __shfl_xor(p, 32);
        p += __shfl_xor(p, 16);
        p += __shfl_xor(p, 8);
        p += __shfl_xor(p, 4);
        p += __shfl_xor(p, 2);
        p += __shfl_xor(p, 1);
        if (t == a) myLogit = p;
    }
    if (t < NA) logits[((size_t)b * NH + h) * NA + t] = myLogit;
}

// ---------------------------------------------------------------------------
// K4: masked softmax over agents, head_q, final mix, and reduction partials.
// 256 threads per b: thread = (h = t/32, a = t%32); 32-lane-group shuffles.
// ---------------------------------------------------------------------------
__global__ __launch_bounds__(256) void k_softmax(
    const float* __restrict__ logits, const float* __restrict__ agent_qs,
    const int* __restrict__ actions, const float* __restrict__ wh,
    const float* __restrict__ v, float* __restrict__ out, float* __restrict__ acc)
{
    __shared__ float qs[NA];
    __shared__ int   act_s[NA];
    __shared__ float whs[NH];
    __shared__ float hq[NH];
    __shared__ float vs;
    const int b = blockIdx.x, t = threadIdx.x;
    if (t < NA) {
        qs[t]    = agent_qs[(size_t)b * NA + t];
        act_s[t] = actions[(size_t)b * NA + t];
    } else if (t < NA + NH) {
        whs[t - NA] = wh[(size_t)b * NH + (t - NA)];
    } else if (t == NA + NH) {
        vs = v[b];
    }
    __syncthreads();

    const int h = t >> 5, a = t & 31;
    const float lg = logits[((size_t)b * NH + h) * NA + a];
    float sc = (act_s[a] == 0) ? -99999999.0f : lg * 0.125f;  // /sqrt(64)

    float mx = sc;
    #pragma unroll
    for (int off = 16; off >= 1; off >>= 1) mx = fmaxf(mx, __shfl_xor(mx, off, 32));
    const float e = expf(sc - mx);
    float sum = e;
    #pragma unroll
    for (int off = 16; off >= 1; off >>= 1) sum += __shfl_xor(sum, off, 32);
    const float w = e / sum;

    float r_sq  = lg * lg;
    float r_hq  = qs[a] * w;
    float r_ent = -w * logf(w + 1e-8f);
    #pragma unroll
    for (int off = 16; off >= 1; off >>= 1) {
        r_sq  += __shfl_xor(r_sq,  off, 32);
        r_hq  += __shfl_xor(r_hq,  off, 32);
        r_ent += __shfl_xor(r_ent, off, 32);
    }
    if (a == 0) {
        hq[h] = r_hq;
        atomicAdd(&acc[h], r_sq);
        atomicAdd(&acc[NH + h], r_ent);
    }
    __syncthreads();
    if (t == 0) {
        float y = vs;
        #pragma unroll
        for (int i = 0; i < NH; ++i) y = fmaf(whs[i], hq[i], y);
        out[b] = y;
    }
}

__global__ void k_final(const float* __restrict__ acc, float* __restrict__ out) {
    const int t = threadIdx.x;
    if (t == 0) {
        float s = 0.f;
        for (int i = 0; i < NH; ++i) s += acc[i];
        out[B_TOT] = 0.001f * (s / (float)((size_t)B_TOT * NA));
    }
    if (t < NH) out[B_TOT + 1 + t] = acc[NH + t] / (float)B_TOT;
}

extern "C" void kernel_launch(void* const* d_in, const int* in_sizes, int n_in,
                              void* d_out, int out_size, void* d_ws, size_t ws_size,
                              hipStream_t stream) {
    (void)in_sizes; (void)n_in; (void)out_size; (void)ws_size;
    const float* agent_qs = (const float*)d_in[0];
    const float* states   = (const float*)d_in[1];
    const int*   actions  = (const int*)d_in[2];
    const float* sel_W1   = (const float*)d_in[3];
    const float* sel_b1   = (const float*)d_in[4];
    const float* sel_W2   = (const float*)d_in[5];
    const float* key_W1   = (const float*)d_in[6];
    const float* key_b1   = (const float*)d_in[7];
    const float* key_W2   = (const float*)d_in[8];
    const float* wh_W1    = (const float*)d_in[9];
    const float* wh_b1    = (const float*)d_in[10];
    const float* wh_W2    = (const float*)d_in[11];
    const float* wh_b2    = (const float*)d_in[12];
    const float* v_W1     = (const float*)d_in[13];
    const float* v_b1     = (const float*)d_in[14];
    const float* v_W2     = (const float*)d_in[15];
    const float* v_b2     = (const float*)d_in[16];

    float* out = (float*)d_out;
    float* ws  = (float*)d_ws;
    float* h1_all = ws + WS_H1;
    float* m_buf  = ws + WS_M;
    float* wh_buf = ws + WS_WH;
    float* v_buf  = ws + WS_V;
    float* lg_buf = ws + WS_LG;
    float* acc    = ws + WS_ACC;

    k_zero<<<1, 64, 0, stream>>>(acc);
    k_gemm1<<<dim3(NTOT / 128, B_TOT / 128), 256, 0, stream>>>(
        states, sel_W1, sel_b1, wh_W1, wh_b1, v_W1, v_b1, h1_all);
    k_second<<<dim3(B_TOT / BT), 256, 0, stream>>>(
        h1_all, sel_W2, key_W2, wh_W2, wh_b2, v_W2, v_b2, m_buf, wh_buf, v_buf);
    k_logits<<<dim3(B_TOT, NH), 64, 0, stream>>>(
        states, agent_qs, key_W1, key_b1, m_buf, lg_buf);
    k_softmax<<<dim3(B_TOT), 256, 0, stream>>>(
        lg_buf, agent_qs, actions, wh_buf, v_buf, out, acc);
    k_final<<<1, 64, 0, stream>>>(acc, out);
}

// Round 2
// 710.648 us; speedup vs baseline: 1.4979x; 1.4979x over previous
//
#include <hip/hip_runtime.h>

#define B_TOT 4096
#define SDIM  1200
#define NA    32
#define NH    8
#define EMB   64
#define KHID  128
#define HYP   256
#define NSEL  2048   // NH*HYP
#define NTOT  2560   // NSEL + 256 (wh hid) + 256 (v hid)

// workspace layout (float offsets)
#define WS_H1   0
#define WS_M    (WS_H1 + (size_t)B_TOT * NTOT)            // 10,485,760
#define WS_WH   (WS_M  + (size_t)B_TOT * NH * KHID)       // +4,194,304
#define WS_V    (WS_WH + (size_t)B_TOT * NH)
#define WS_LG   (WS_V  + (size_t)B_TOT)
#define WS_PART (WS_LG + (size_t)B_TOT * NH * NA)         // [B_TOT][16] partials

// ---------------------------------------------------------------------------
// K1: fused hypernet first layers.
// h1_all[b][n] = relu( states[b]·W[n] + bias[n] ), n<2048: sel_W1 (h=n/256,e=n%256),
// 2048..2303: wh_W1, 2304..2559: v_W1.  GEMM M=4096 N=2560 K=1200, 128x128 tile,
// 256 threads, 8x8 per thread, BK=16.
// ---------------------------------------------------------------------------
__global__ __launch_bounds__(256) void k_gemm1(
    const float* __restrict__ states,
    const float* __restrict__ sel_W1, const float* __restrict__ sel_b1,
    const float* __restrict__ wh_W1,  const float* __restrict__ wh_b1,
    const float* __restrict__ v_W1,   const float* __restrict__ v_b1,
    float* __restrict__ h1_all)
{
    __shared__ __align__(16) float As[16][132];
    __shared__ __align__(16) float Bs[16][132];
    const int tid  = threadIdx.x;
    const int tx   = tid & 15;        // N sub-tile
    const int ty   = tid >> 4;        // M sub-tile
    const int row_l = tid >> 1;       // 0..127 staging row
    const int col8  = (tid & 1) * 8;  // 0 or 8 staging col
    const int arow = blockIdx.y * 128 + row_l;
    const int nrow = blockIdx.x * 128 + row_l;
    const float* wptr = (nrow < NSEL)       ? (sel_W1 + (size_t)nrow * SDIM)
                      : (nrow < NSEL + HYP) ? (wh_W1 + (size_t)(nrow - NSEL) * SDIM)
                                            : (v_W1  + (size_t)(nrow - NSEL - HYP) * SDIM);
    const float* aptr = states + (size_t)arow * SDIM;

    float c[8][8] = {};
    for (int k0 = 0; k0 < SDIM; k0 += 16) {
        float4 a0 = *(const float4*)(aptr + k0 + col8);
        float4 a1 = *(const float4*)(aptr + k0 + col8 + 4);
        float4 b0 = *(const float4*)(wptr + k0 + col8);
        float4 b1 = *(const float4*)(wptr + k0 + col8 + 4);
        As[col8 + 0][row_l] = a0.x; As[col8 + 1][row_l] = a0.y;
        As[col8 + 2][row_l] = a0.z; As[col8 + 3][row_l] = a0.w;
        As[col8 + 4][row_l] = a1.x; As[col8 + 5][row_l] = a1.y;
        As[col8 + 6][row_l] = a1.z; As[col8 + 7][row_l] = a1.w;
        Bs[col8 + 0][row_l] = b0.x; Bs[col8 + 1][row_l] = b0.y;
        Bs[col8 + 2][row_l] = b0.z; Bs[col8 + 3][row_l] = b0.w;
        Bs[col8 + 4][row_l] = b1.x; Bs[col8 + 5][row_l] = b1.y;
        Bs[col8 + 6][row_l] = b1.z; Bs[col8 + 7][row_l] = b1.w;
        __syncthreads();
        #pragma unroll
        for (int kk = 0; kk < 16; ++kk) {
            float4 x0 = *(const float4*)&As[kk][ty * 8];
            float4 x1 = *(const float4*)&As[kk][ty * 8 + 4];
            float4 y0 = *(const float4*)&Bs[kk][tx * 8];
            float4 y1 = *(const float4*)&Bs[kk][tx * 8 + 4];
            float am[8] = {x0.x, x0.y, x0.z, x0.w, x1.x, x1.y, x1.z, x1.w};
            float bn[8] = {y0.x, y0.y, y0.z, y0.w, y1.x, y1.y, y1.z, y1.w};
            #pragma unroll
            for (int i = 0; i < 8; ++i)
                #pragma unroll
                for (int j = 0; j < 8; ++j)
                    c[i][j] = fmaf(am[i], bn[j], c[i][j]);
        }
        __syncthreads();
    }

    const int colbase = blockIdx.x * 128 + tx * 8;   // segment boundaries are /8 aligned
    const float* bptr = (colbase < NSEL)       ? (sel_b1 + colbase)
                      : (colbase < NSEL + HYP) ? (wh_b1 + colbase - NSEL)
                                               : (v_b1  + colbase - NSEL - HYP);
    float bias[8];
    #pragma unroll
    for (int j = 0; j < 8; ++j) bias[j] = bptr[j];
    #pragma unroll
    for (int i = 0; i < 8; ++i) {
        const int row = blockIdx.y * 128 + ty * 8 + i;
        float4 o0, o1;
        o0.x = fmaxf(c[i][0] + bias[0], 0.f); o0.y = fmaxf(c[i][1] + bias[1], 0.f);
        o0.z = fmaxf(c[i][2] + bias[2], 0.f); o0.w = fmaxf(c[i][3] + bias[3], 0.f);
        o1.x = fmaxf(c[i][4] + bias[4], 0.f); o1.y = fmaxf(c[i][5] + bias[5], 0.f);
        o1.z = fmaxf(c[i][6] + bias[6], 0.f); o1.w = fmaxf(c[i][7] + bias[7], 0.f);
        *(float4*)(h1_all + (size_t)row * NTOT + colbase)     = o0;
        *(float4*)(h1_all + (size_t)row * NTOT + colbase + 4) = o1;
    }
}

// ---------------------------------------------------------------------------
// K2: second layers, 4 batch rows per block.
// ---------------------------------------------------------------------------
#define BT 4
__global__ __launch_bounds__(256) void k_second(
    const float* __restrict__ h1_all, const float* __restrict__ sel_W2,
    const float* __restrict__ key_W2, const float* __restrict__ wh_W2,
    const float* __restrict__ wh_b2,  const float* __restrict__ v_W2,
    const float* __restrict__ v_b2,
    float* __restrict__ m_out, float* __restrict__ wh_out, float* __restrict__ v_out)
{
    __shared__ __align__(16) float rowbuf[BT][NTOT];
    __shared__ __align__(16) float sel_lds[BT][NH * EMB];
    const int t  = threadIdx.x;
    const int b0 = blockIdx.x * BT;

    #pragma unroll
    for (int bi = 0; bi < BT; ++bi)
        #pragma unroll
        for (int j = 0; j < NTOT / 256; ++j)
            rowbuf[bi][j * 256 + t] = h1_all[(size_t)(b0 + bi) * NTOT + j * 256 + t];
    __syncthreads();

    // sel: 512 outputs, 2 per thread (h wave-uniform -> broadcast LDS reads)
    #pragma unroll
    for (int rep = 0; rep < 2; ++rep) {
        const int o = t + rep * 256;
        const int h = o >> 6, d = o & 63;
        const float* w = sel_W2 + (size_t)(h * EMB + d) * HYP;
        float acc0 = 0.f, acc1 = 0.f, acc2 = 0.f, acc3 = 0.f;
        for (int e = 0; e < HYP; e += 4) {
            float4 wv = *(const float4*)(w + e);
            float4 r0 = *(const float4*)&rowbuf[0][h * HYP + e];
            float4 r1 = *(const float4*)&rowbuf[1][h * HYP + e];
            float4 r2 = *(const float4*)&rowbuf[2][h * HYP + e];
            float4 r3 = *(const float4*)&rowbuf[3][h * HYP + e];
            acc0 += r0.x * wv.x + r0.y * wv.y + r0.z * wv.z + r0.w * wv.w;
            acc1 += r1.x * wv.x + r1.y * wv.y + r1.z * wv.z + r1.w * wv.w;
            acc2 += r2.x * wv.x + r2.y * wv.y + r2.z * wv.z + r2.w * wv.w;
            acc3 += r3.x * wv.x + r3.y * wv.y + r3.z * wv.z + r3.w * wv.w;
        }
        sel_lds[0][o] = acc0; sel_lds[1][o] = acc1;
        sel_lds[2][o] = acc2; sel_lds[3][o] = acc3;
    }
    __syncthreads();

    // m: 1024 outputs, 4 per thread; key_W2 reads coalesced over k
    #pragma unroll
    for (int jj = 0; jj < 4; ++jj) {
        const int o = t + jj * 256;
        const int h = o >> 7, k = o & 127;
        float acc0 = 0.f, acc1 = 0.f, acc2 = 0.f, acc3 = 0.f;
        for (int d = 0; d < EMB; ++d) {
            const float wv = key_W2[(size_t)(h * EMB + d) * KHID + k];
            acc0 = fmaf(sel_lds[0][h * EMB + d], wv, acc0);
            acc1 = fmaf(sel_lds[1][h * EMB + d], wv, acc1);
            acc2 = fmaf(sel_lds[2][h * EMB + d], wv, acc2);
            acc3 = fmaf(sel_lds[3][h * EMB + d], wv, acc3);
        }
        m_out[((size_t)(b0 + 0) * NH + h) * KHID + k] = acc0;
        m_out[((size_t)(b0 + 1) * NH + h) * KHID + k] = acc1;
        m_out[((size_t)(b0 + 2) * NH + h) * KHID + k] = acc2;
        m_out[((size_t)(b0 + 3) * NH + h) * KHID + k] = acc3;
    }

    if (t < 32) {
        const int bi = t >> 3, h = t & 7;
        float a = 0.f;
        for (int e = 0; e < HYP; ++e)
            a = fmaf(rowbuf[bi][NSEL + e], wh_W2[h * HYP + e], a);
        wh_out[(b0 + bi) * NH + h] = fabsf(a + wh_b2[h]);
    } else if (t < 36) {
        const int bi = t - 32;
        float a = 0.f;
        for (int e = 0; e < HYP; ++e)
            a = fmaf(rowbuf[bi][NSEL + 256 + e], v_W2[e], a);
        v_out[b0 + bi] = a + v_b2[0];
    }
}

// ---------------------------------------------------------------------------
// K3: logits[b,h,a] = sum_k relu(units[b,a]·key_W1[h,k] + key_b1[h,k]) * m[b,h,k]
// One wave per (b,h).
// ---------------------------------------------------------------------------
#define DOT4(Q, I)                                         \
    d0 = fmaf(Q.x, w0[I],     d0); d1 = fmaf(Q.x, w1[I],     d1); \
    d0 = fmaf(Q.y, w0[(I)+1], d0); d1 = fmaf(Q.y, w1[(I)+1], d1); \
    d0 = fmaf(Q.z, w0[(I)+2], d0); d1 = fmaf(Q.z, w1[(I)+2], d1); \
    d0 = fmaf(Q.w, w0[(I)+3], d0); d1 = fmaf(Q.w, w1[(I)+3], d1);

__global__ __launch_bounds__(64) void k_logits(
    const float* __restrict__ states, const float* __restrict__ agent_qs,
    const float* __restrict__ key_W1, const float* __restrict__ key_b1,
    const float* __restrict__ m_in, float* __restrict__ logits)
{
    __shared__ float W1s[128 * 33];
    __shared__ __align__(16) float units[32][36];
    const int t = threadIdx.x;
    const int b = blockIdx.x, h = blockIdx.y;

    const float* W1g = key_W1 + (size_t)h * 128 * 33;
    for (int j = 0; j < 66; ++j) W1s[j * 64 + t] = W1g[j * 64 + t];
    {
        const float* srow = states + (size_t)b * SDIM;
        const int a = t >> 1, u0 = (t & 1) * 16;
        float4 x0 = *(const float4*)(srow + a * 32 + u0);
        float4 x1 = *(const float4*)(srow + a * 32 + u0 + 4);
        float4 x2 = *(const float4*)(srow + a * 32 + u0 + 8);
        float4 x3 = *(const float4*)(srow + a * 32 + u0 + 12);
        *(float4*)&units[a][u0]      = x0;
        *(float4*)&units[a][u0 + 4]  = x1;
        *(float4*)&units[a][u0 + 8]  = x2;
        *(float4*)&units[a][u0 + 12] = x3;
        if (t < NA) units[t][32] = agent_qs[(size_t)b * NA + t];
    }
    const float b1r0 = key_b1[h * 128 + t];
    const float b1r1 = key_b1[h * 128 + 64 + t];
    const float m0 = m_in[((size_t)b * NH + h) * KHID + t];
    const float m1 = m_in[((size_t)b * NH + h) * KHID + 64 + t];
    __syncthreads();

    float w0[33], w1[33];
    #pragma unroll
    for (int u = 0; u < 33; ++u) {
        w0[u] = W1s[t * 33 + u];
        w1[u] = W1s[(t + 64) * 33 + u];
    }

    float myLogit = 0.f;
    #pragma unroll
    for (int a = 0; a < NA; ++a) {
        float4 ua0 = *(const float4*)&units[a][0];
        float4 ua1 = *(const float4*)&units[a][4];
        float4 ua2 = *(const float4*)&units[a][8];
        float4 ua3 = *(const float4*)&units[a][12];
        float4 ua4 = *(const float4*)&units[a][16];
        float4 ua5 = *(const float4*)&units[a][20];
        float4 ua6 = *(const float4*)&units[a][24];
        float4 ua7 = *(const float4*)&units[a][28];
        const float uq = units[a][32];
        float d0 = b1r0, d1 = b1r1;
        DOT4(ua0, 0)  DOT4(ua1, 4)  DOT4(ua2, 8)  DOT4(ua3, 12)
        DOT4(ua4, 16) DOT4(ua5, 20) DOT4(ua6, 24) DOT4(ua7, 28)
        d0 = fmaf(uq, w0[32], d0);
        d1 = fmaf(uq, w1[32], d1);
        d0 = fmaxf(d0, 0.f);
        d1 = fmaxf(d1, 0.f);
        float p = fmaf(d0, m0, d1 * m1);
        p += __shfl_xor(p, 32);
        p += __shfl_xor(p, 16);
        p += __shfl_xor(p, 8);
        p += __shfl_xor(p, 4);
        p += __shfl_xor(p, 2);
        p += __shfl_xor(p, 1);
        if (t == a) myLogit = p;
    }
    if (t < NA) logits[((size_t)b * NH + h) * NA + t] = myLogit;
}

// ---------------------------------------------------------------------------
// K4: masked softmax over agents, head_q, final mix. NO ATOMICS: per-block
// partials (16 floats: [sq x8 | ent x8]) go to ws; k_final reduces.
// ---------------------------------------------------------------------------
__global__ __launch_bounds__(256) void k_softmax(
    const float* __restrict__ logits, const float* __restrict__ agent_qs,
    const int* __restrict__ actions, const float* __restrict__ wh,
    const float* __restrict__ v, float* __restrict__ out,
    float* __restrict__ part)
{
    __shared__ float qs[NA];
    __shared__ int   act_s[NA];
    __shared__ float whs[NH];
    __shared__ float hq[NH];
    __shared__ float vs;
    const int b = blockIdx.x, t = threadIdx.x;
    if (t < NA) {
        qs[t]    = agent_qs[(size_t)b * NA + t];
        act_s[t] = actions[(size_t)b * NA + t];
    } else if (t < NA + NH) {
        whs[t - NA] = wh[(size_t)b * NH + (t - NA)];
    } else if (t == NA + NH) {
        vs = v[b];
    }
    __syncthreads();

    const int h = t >> 5, a = t & 31;
    const float lg = logits[((size_t)b * NH + h) * NA + a];
    float sc = (act_s[a] == 0) ? -99999999.0f : lg * 0.125f;  // /sqrt(64)

    float mx = sc;
    #pragma unroll
    for (int off = 16; off >= 1; off >>= 1) mx = fmaxf(mx, __shfl_xor(mx, off, 32));
    const float e = expf(sc - mx);
    float sum = e;
    #pragma unroll
    for (int off = 16; off >= 1; off >>= 1) sum += __shfl_xor(sum, off, 32);
    const float w = e / sum;

    float r_sq  = lg * lg;
    float r_hq  = qs[a] * w;
    float r_ent = -w * logf(w + 1e-8f);
    #pragma unroll
    for (int off = 16; off >= 1; off >>= 1) {
        r_sq  += __shfl_xor(r_sq,  off, 32);
        r_hq  += __shfl_xor(r_hq,  off, 32);
        r_ent += __shfl_xor(r_ent, off, 32);
    }
    if (a == 0) {
        hq[h] = r_hq;
        part[(size_t)b * 16 + h]     = r_sq;
        part[(size_t)b * 16 + 8 + h] = r_ent;
    }
    __syncthreads();
    if (t == 0) {
        float y = vs;
        #pragma unroll
        for (int i = 0; i < NH; ++i) y = fmaf(whs[i], hq[i], y);
        out[b] = y;
    }
}

// ---------------------------------------------------------------------------
// K5: reduce [B_TOT][16] partials -> reg scalar + 8 entropies.
// Thread t: c = t&15 (output), r = t>>4 (row group); reads are coalesced
// (address = t + j*256).
// ---------------------------------------------------------------------------
__global__ __launch_bounds__(256) void k_final(
    const float* __restrict__ part, float* __restrict__ out)
{
    __shared__ float red[16][17];
    const int t = threadIdx.x;
    const int c = t & 15, r = t >> 4;
    float val = 0.f;
    for (int b = r; b < B_TOT; b += 16)
        val += part[(size_t)b * 16 + c];
    red[r][c] = val;
    __syncthreads();
    if (t < 16) {
        float s = 0.f;
        #pragma unroll
        for (int i = 0; i < 16; ++i) s += red[i][t];
        red[16][t] = s;  // unused slot trick avoided; store to row 0 area
        // t<8: sq sums per head; t>=8: entropy sums per head
    }
    __syncthreads();
    if (t == 0) {
        float s = 0.f;
        #pragma unroll
        for (int i = 0; i < 8; ++i) s += red[16][i];
        out[B_TOT] = 0.001f * (s / (float)((size_t)B_TOT * NA));
    }
    if (t >= 8 && t < 16)
        out[B_TOT + 1 + (t - 8)] = red[16][t] / (float)B_TOT;
}

extern "C" void kernel_launch(void* const* d_in, const int* in_sizes, int n_in,
                              void* d_out, int out_size, void* d_ws, size_t ws_size,
                              hipStream_t stream) {
    (void)in_sizes; (void)n_in; (void)out_size; (void)ws_size;
    const float* agent_qs = (const float*)d_in[0];
    const float* states   = (const float*)d_in[1];
    const int*   actions  = (const int*)d_in[2];
    const float* sel_W1   = (const float*)d_in[3];
    const float* sel_b1   = (const float*)d_in[4];
    const float* sel_W2   = (const float*)d_in[5];
    const float* key_W1   = (const float*)d_in[6];
    const float* key_b1   = (const float*)d_in[7];
    const float* key_W2   = (const float*)d_in[8];
    const float* wh_W1    = (const float*)d_in[9];
    const float* wh_b1    = (const float*)d_in[10];
    const float* wh_W2    = (const float*)d_in[11];
    const float* wh_b2    = (const float*)d_in[12];
    const float* v_W1     = (const float*)d_in[13];
    const float* v_b1     = (const float*)d_in[14];
    const float* v_W2     = (const float*)d_in[15];
    const float* v_b2     = (const float*)d_in[16];

    float* out = (float*)d_out;
    float* ws  = (float*)d_ws;
    float* h1_all = ws + WS_H1;
    float* m_buf  = ws + WS_M;
    float* wh_buf = ws + WS_WH;
    float* v_buf  = ws + WS_V;
    float* lg_buf = ws + WS_LG;
    float* part   = ws + WS_PART;

    k_gemm1<<<dim3(NTOT / 128, B_TOT / 128), 256, 0, stream>>>(
        states, sel_W1, sel_b1, wh_W1, wh_b1, v_W1, v_b1, h1_all);
    k_second<<<dim3(B_TOT / BT), 256, 0, stream>>>(
        h1_all, sel_W2, key_W2, wh_W2, wh_b2, v_W2, v_b2, m_buf, wh_buf, v_buf);
    k_logits<<<dim3(B_TOT, NH), 64, 0, stream>>>(
        states, agent_qs, key_W1, key_b1, m_buf, lg_buf);
    k_softmax<<<dim3(B_TOT), 256, 0, stream>>>(
        lg_buf, agent_qs, actions, wh_buf, v_buf, out, part);
    k_final<<<1, 256, 0, stream>>>(part, out);
}

// Round 3
// 412.011 us; speedup vs baseline: 2.5836x; 1.7248x over previous
//
#include <hip/hip_runtime.h>

#define B_TOT 4096
#define SDIM  1200
#define KPAD  1216   // SDIM padded to multiple of 64 for MFMA K-loop
#define NA    32
#define NH    8
#define EMB   64
#define KHID  128
#define HYP   256
#define NSEL  2048   // NH*HYP
#define NTOT  2560   // NSEL + 256 (wh hid) + 256 (v hid)

// workspace layout (float offsets)
#define WS_H1   0
#define WS_M    (WS_H1 + (size_t)B_TOT * NTOT)
#define WS_WH   (WS_M  + (size_t)B_TOT * NH * KHID)
#define WS_V    (WS_WH + (size_t)B_TOT * NH)
#define WS_LG   (WS_V  + (size_t)B_TOT)
#define WS_PART (WS_LG + (size_t)B_TOT * NH * NA)
#define WS_ABF  (WS_PART + (size_t)B_TOT * 16)                 // bf16 states [B_TOT][KPAD]
#define WS_WBF  (WS_ABF + ((size_t)B_TOT * KPAD + 1) / 2)      // bf16 weights [NTOT][KPAD]

typedef __attribute__((ext_vector_type(8))) short short8v;
typedef __attribute__((ext_vector_type(4))) float floatx4;

__device__ __forceinline__ ushort f2bf(float x) {
    unsigned u = __builtin_bit_cast(unsigned, x);
    unsigned r = (u + 0x7FFFu + ((u >> 16) & 1u)) >> 16;
    return (ushort)r;
}

// ---------------------------------------------------------------------------
// Conversion: fp32 -> bf16 (RTNE), rows padded from 1200 to 1216 with zeros.
// One ushort4 (4 elems) per thread-iteration; 304 groups per row.
// ---------------------------------------------------------------------------
__global__ __launch_bounds__(256) void k_cvt_states(
    const float* __restrict__ src, ushort* __restrict__ dst)
{
    const size_t g = (size_t)blockIdx.x * 256 + threadIdx.x;
    if (g >= (size_t)B_TOT * (KPAD / 4)) return;
    const int row = (int)(g / (KPAD / 4));
    const int c4  = (int)(g % (KPAD / 4)) * 4;
    ushort4 o = {0, 0, 0, 0};
    if (c4 < SDIM) {
        float4 v = *(const float4*)(src + (size_t)row * SDIM + c4);
        o.x = f2bf(v.x); o.y = f2bf(v.y); o.z = f2bf(v.z); o.w = f2bf(v.w);
    }
    *(ushort4*)(dst + (size_t)row * KPAD + c4) = o;
}

__global__ __launch_bounds__(256) void k_cvt_w(
    const float* __restrict__ sel_W1, const float* __restrict__ wh_W1,
    const float* __restrict__ v_W1, ushort* __restrict__ dst)
{
    const size_t g = (size_t)blockIdx.x * 256 + threadIdx.x;
    if (g >= (size_t)NTOT * (KPAD / 4)) return;
    const int row = (int)(g / (KPAD / 4));
    const int c4  = (int)(g % (KPAD / 4)) * 4;
    const float* src = (row < NSEL)       ? (sel_W1 + (size_t)row * SDIM)
                     : (row < NSEL + HYP) ? (wh_W1 + (size_t)(row - NSEL) * SDIM)
                                          : (v_W1  + (size_t)(row - NSEL - HYP) * SDIM);
    ushort4 o = {0, 0, 0, 0};
    if (c4 < SDIM) {
        float4 v = *(const float4*)(src + c4);
        o.x = f2bf(v.x); o.y = f2bf(v.y); o.z = f2bf(v.z); o.w = f2bf(v.w);
    }
    *(ushort4*)(dst + (size_t)row * KPAD + c4) = o;
}

// ---------------------------------------------------------------------------
// K1: bf16 MFMA GEMM (m97 structure). M=4096 N=2560 K=1216(padded).
// 128x128 tile, 4 waves (2Mx2N), each wave 64x64 = 4x4 frags of 16x16x32.
// global_load_lds width-16 staging, 2-barrier K-loop, BK=32.
// Epilogue: +bias, relu, fp32 store to h1_all.
// ---------------------------------------------------------------------------
#define BK 32
__global__ __launch_bounds__(256) void k_gemm1_mfma(
    const ushort* __restrict__ Abf, const ushort* __restrict__ Wbf,
    const float* __restrict__ sel_b1, const float* __restrict__ wh_b1,
    const float* __restrict__ v_b1, float* __restrict__ h1_all)
{
    __shared__ ushort As[128 * BK];
    __shared__ ushort Bs[128 * BK];
    const int tid = threadIdx.x;
    const int l   = tid & 63;
    const int w   = tid >> 6;
    const int wM  = w >> 1, wN = w & 1;
    const int arow0 = blockIdx.y * 128;
    const int nrow0 = blockIdx.x * 128;

    // staging: thread t covers tile-row (inst*64 + t/4), k-chunk (t&3)*8
    const int srow = tid >> 2;
    const int skof = (tid & 3) * 8;
    const ushort* gA = Abf + (size_t)(arow0 + srow) * KPAD + skof;
    const ushort* gB = Wbf + (size_t)(nrow0 + srow) * KPAD + skof;
    ushort* lA = &As[srow * BK + skof];
    ushort* lB = &Bs[srow * BK + skof];

    floatx4 acc[4][4] = {};

    for (int k0 = 0; k0 < KPAD; k0 += BK) {
        __builtin_amdgcn_global_load_lds(
            (const __attribute__((address_space(1))) unsigned int*)(gA + k0),
            (__attribute__((address_space(3))) unsigned int*)lA, 16, 0, 0);
        __builtin_amdgcn_global_load_lds(
            (const __attribute__((address_space(1))) unsigned int*)(gA + (size_t)64 * KPAD + k0),
            (__attribute__((address_space(3))) unsigned int*)(lA + 64 * BK), 16, 0, 0);
        __builtin_amdgcn_global_load_lds(
            (const __attribute__((address_space(1))) unsigned int*)(gB + k0),
            (__attribute__((address_space(3))) unsigned int*)lB, 16, 0, 0);
        __builtin_amdgcn_global_load_lds(
            (const __attribute__((address_space(1))) unsigned int*)(gB + (size_t)64 * KPAD + k0),
            (__attribute__((address_space(3))) unsigned int*)(lB + 64 * BK), 16, 0, 0);
        __syncthreads();   // drains vmcnt + barrier

        const int kch = (l >> 4) * 8;
        short8v av[4], bv[4];
        #pragma unroll
        for (int mi = 0; mi < 4; ++mi)
            av[mi] = *(const short8v*)&As[(wM * 64 + mi * 16 + (l & 15)) * BK + kch];
        #pragma unroll
        for (int ni = 0; ni < 4; ++ni)
            bv[ni] = *(const short8v*)&Bs[(wN * 64 + ni * 16 + (l & 15)) * BK + kch];
        #pragma unroll
        for (int mi = 0; mi < 4; ++mi)
            #pragma unroll
            for (int ni = 0; ni < 4; ++ni)
                acc[mi][ni] = __builtin_amdgcn_mfma_f32_16x16x32_bf16(
                    av[mi], bv[ni], acc[mi][ni], 0, 0, 0);
        __syncthreads();   // protect LDS before next stage
    }

    // epilogue: bias + relu, fp32 store
    float bias_n[4];
    #pragma unroll
    for (int ni = 0; ni < 4; ++ni) {
        const int col = nrow0 + wN * 64 + ni * 16 + (l & 15);
        bias_n[ni] = (col < NSEL)       ? sel_b1[col]
                   : (col < NSEL + HYP) ? wh_b1[col - NSEL]
                                        : v_b1[col - NSEL - HYP];
    }
    #pragma unroll
    for (int mi = 0; mi < 4; ++mi) {
        const int row = arow0 + wM * 64 + mi * 16 + (l >> 4) * 4;
        #pragma unroll
        for (int ni = 0; ni < 4; ++ni) {
            const int col = nrow0 + wN * 64 + ni * 16 + (l & 15);
            #pragma unroll
            for (int r = 0; r < 4; ++r)
                h1_all[(size_t)(row + r) * NTOT + col] =
                    fmaxf(acc[mi][ni][r] + bias_n[ni], 0.f);
        }
    }
}

// ---------------------------------------------------------------------------
// K2: second layers, 4 batch rows per block.
// ---------------------------------------------------------------------------
#define BT 4
__global__ __launch_bounds__(256) void k_second(
    const float* __restrict__ h1_all, const float* __restrict__ sel_W2,
    const float* __restrict__ key_W2, const float* __restrict__ wh_W2,
    const float* __restrict__ wh_b2,  const float* __restrict__ v_W2,
    const float* __restrict__ v_b2,
    float* __restrict__ m_out, float* __restrict__ wh_out, float* __restrict__ v_out)
{
    __shared__ __align__(16) float rowbuf[BT][NTOT];
    __shared__ __align__(16) float sel_lds[BT][NH * EMB];
    const int t  = threadIdx.x;
    const int b0 = blockIdx.x * BT;

    #pragma unroll
    for (int bi = 0; bi < BT; ++bi)
        #pragma unroll
        for (int j = 0; j < NTOT / 256; ++j)
            rowbuf[bi][j * 256 + t] = h1_all[(size_t)(b0 + bi) * NTOT + j * 256 + t];
    __syncthreads();

    #pragma unroll
    for (int rep = 0; rep < 2; ++rep) {
        const int o = t + rep * 256;
        const int h = o >> 6, d = o & 63;
        const float* w = sel_W2 + (size_t)(h * EMB + d) * HYP;
        float acc0 = 0.f, acc1 = 0.f, acc2 = 0.f, acc3 = 0.f;
        for (int e = 0; e < HYP; e += 4) {
            float4 wv = *(const float4*)(w + e);
            float4 r0 = *(const float4*)&rowbuf[0][h * HYP + e];
            float4 r1 = *(const float4*)&rowbuf[1][h * HYP + e];
            float4 r2 = *(const float4*)&rowbuf[2][h * HYP + e];
            float4 r3 = *(const float4*)&rowbuf[3][h * HYP + e];
            acc0 += r0.x * wv.x + r0.y * wv.y + r0.z * wv.z + r0.w * wv.w;
            acc1 += r1.x * wv.x + r1.y * wv.y + r1.z * wv.z + r1.w * wv.w;
            acc2 += r2.x * wv.x + r2.y * wv.y + r2.z * wv.z + r2.w * wv.w;
            acc3 += r3.x * wv.x + r3.y * wv.y + r3.z * wv.z + r3.w * wv.w;
        }
        sel_lds[0][o] = acc0; sel_lds[1][o] = acc1;
        sel_lds[2][o] = acc2; sel_lds[3][o] = acc3;
    }
    __syncthreads();

    #pragma unroll
    for (int jj = 0; jj < 4; ++jj) {
        const int o = t + jj * 256;
        const int h = o >> 7, k = o & 127;
        float acc0 = 0.f, acc1 = 0.f, acc2 = 0.f, acc3 = 0.f;
        for (int d = 0; d < EMB; ++d) {
            const float wv = key_W2[(size_t)(h * EMB + d) * KHID + k];
            acc0 = fmaf(sel_lds[0][h * EMB + d], wv, acc0);
            acc1 = fmaf(sel_lds[1][h * EMB + d], wv, acc1);
            acc2 = fmaf(sel_lds[2][h * EMB + d], wv, acc2);
            acc3 = fmaf(sel_lds[3][h * EMB + d], wv, acc3);
        }
        m_out[((size_t)(b0 + 0) * NH + h) * KHID + k] = acc0;
        m_out[((size_t)(b0 + 1) * NH + h) * KHID + k] = acc1;
        m_out[((size_t)(b0 + 2) * NH + h) * KHID + k] = acc2;
        m_out[((size_t)(b0 + 3) * NH + h) * KHID + k] = acc3;
    }

    if (t < 32) {
        const int bi = t >> 3, h = t & 7;
        float a = 0.f;
        for (int e = 0; e < HYP; ++e)
            a = fmaf(rowbuf[bi][NSEL + e], wh_W2[h * HYP + e], a);
        wh_out[(b0 + bi) * NH + h] = fabsf(a + wh_b2[h]);
    } else if (t < 36) {
        const int bi = t - 32;
        float a = 0.f;
        for (int e = 0; e < HYP; ++e)
            a = fmaf(rowbuf[bi][NSEL + 256 + e], v_W2[e], a);
        v_out[b0 + bi] = a + v_b2[0];
    }
}

// ---------------------------------------------------------------------------
// K3: logits[b,h,a] = sum_k relu(units[b,a]·key_W1[h,k] + key_b1[h,k]) * m[b,h,k]
// ---------------------------------------------------------------------------
#define DOT4(Q, I)                                         \
    d0 = fmaf(Q.x, w0[I],     d0); d1 = fmaf(Q.x, w1[I],     d1); \
    d0 = fmaf(Q.y, w0[(I)+1], d0); d1 = fmaf(Q.y, w1[(I)+1], d1); \
    d0 = fmaf(Q.z, w0[(I)+2], d0); d1 = fmaf(Q.z, w1[(I)+2], d1); \
    d0 = fmaf(Q.w, w0[(I)+3], d0); d1 = fmaf(Q.w, w1[(I)+3], d1);

__global__ __launch_bounds__(64) void k_logits(
    const float* __restrict__ states, const float* __restrict__ agent_qs,
    const float* __restrict__ key_W1, const float* __restrict__ key_b1,
    const float* __restrict__ m_in, float* __restrict__ logits)
{
    __shared__ float W1s[128 * 33];
    __shared__ __align__(16) float units[32][36];
    const int t = threadIdx.x;
    const int b = blockIdx.x, h = blockIdx.y;

    const float* W1g = key_W1 + (size_t)h * 128 * 33;
    for (int j = 0; j < 66; ++j) W1s[j * 64 + t] = W1g[j * 64 + t];
    {
        const float* srow = states + (size_t)b * SDIM;
        const int a = t >> 1, u0 = (t & 1) * 16;
        float4 x0 = *(const float4*)(srow + a * 32 + u0);
        float4 x1 = *(const float4*)(srow + a * 32 + u0 + 4);
        float4 x2 = *(const float4*)(srow + a * 32 + u0 + 8);
        float4 x3 = *(const float4*)(srow + a * 32 + u0 + 12);
        *(float4*)&units[a][u0]      = x0;
        *(float4*)&units[a][u0 + 4]  = x1;
        *(float4*)&units[a][u0 + 8]  = x2;
        *(float4*)&units[a][u0 + 12] = x3;
        if (t < NA) units[t][32] = agent_qs[(size_t)b * NA + t];
    }
    const float b1r0 = key_b1[h * 128 + t];
    const float b1r1 = key_b1[h * 128 + 64 + t];
    const float m0 = m_in[((size_t)b * NH + h) * KHID + t];
    const float m1 = m_in[((size_t)b * NH + h) * KHID + 64 + t];
    __syncthreads();

    float w0[33], w1[33];
    #pragma unroll
    for (int u = 0; u < 33; ++u) {
        w0[u] = W1s[t * 33 + u];
        w1[u] = W1s[(t + 64) * 33 + u];
    }

    float myLogit = 0.f;
    #pragma unroll
    for (int a = 0; a < NA; ++a) {
        float4 ua0 = *(const float4*)&units[a][0];
        float4 ua1 = *(const float4*)&units[a][4];
        float4 ua2 = *(const float4*)&units[a][8];
        float4 ua3 = *(const float4*)&units[a][12];
        float4 ua4 = *(const float4*)&units[a][16];
        float4 ua5 = *(const float4*)&units[a][20];
        float4 ua6 = *(const float4*)&units[a][24];
        float4 ua7 = *(const float4*)&units[a][28];
        const float uq = units[a][32];
        float d0 = b1r0, d1 = b1r1;
        DOT4(ua0, 0)  DOT4(ua1, 4)  DOT4(ua2, 8)  DOT4(ua3, 12)
        DOT4(ua4, 16) DOT4(ua5, 20) DOT4(ua6, 24) DOT4(ua7, 28)
        d0 = fmaf(uq, w0[32], d0);
        d1 = fmaf(uq, w1[32], d1);
        d0 = fmaxf(d0, 0.f);
        d1 = fmaxf(d1, 0.f);
        float p = fmaf(d0, m0, d1 * m1);
        p += __shfl_xor(p, 32);
        p += __shfl_xor(p, 16);
        p += __shfl_xor(p, 8);
        p += __shfl_xor(p, 4);
        p += __shfl_xor(p, 2);
        p += __shfl_xor(p, 1);
        if (t == a) myLogit = p;
    }
    if (t < NA) logits[((size_t)b * NH + h) * NA + t] = myLogit;
}

// ---------------------------------------------------------------------------
// K4: masked softmax, head_q, final mix; per-block partials (no atomics).
// ---------------------------------------------------------------------------
__global__ __launch_bounds__(256) void k_softmax(
    const float* __restrict__ logits, const float* __restrict__ agent_qs,
    const int* __restrict__ actions, const float* __restrict__ wh,
    const float* __restrict__ v, float* __restrict__ out,
    float* __restrict__ part)
{
    __shared__ float qs[NA];
    __shared__ int   act_s[NA];
    __shared__ float whs[NH];
    __shared__ float hq[NH];
    __shared__ float vs;
    const int b = blockIdx.x, t = threadIdx.x;
    if (t < NA) {
        qs[t]    = agent_qs[(size_t)b * NA + t];
        act_s[t] = actions[(size_t)b * NA + t];
    } else if (t < NA + NH) {
        whs[t - NA] = wh[(size_t)b * NH + (t - NA)];
    } else if (t == NA + NH) {
        vs = v[b];
    }
    __syncthreads();

    const int h = t >> 5, a = t & 31;
    const float lg = logits[((size_t)b * NH + h) * NA + a];
    float sc = (act_s[a] == 0) ? -99999999.0f : lg * 0.125f;

    float mx = sc;
    #pragma unroll
    for (int off = 16; off >= 1; off >>= 1) mx = fmaxf(mx, __shfl_xor(mx, off, 32));
    const float e = expf(sc - mx);
    float sum = e;
    #pragma unroll
    for (int off = 16; off >= 1; off >>= 1) sum += __shfl_xor(sum, off, 32);
    const float w = e / sum;

    float r_sq  = lg * lg;
    float r_hq  = qs[a] * w;
    float r_ent = -w * logf(w + 1e-8f);
    #pragma unroll
    for (int off = 16; off >= 1; off >>= 1) {
        r_sq  += __shfl_xor(r_sq,  off, 32);
        r_hq  += __shfl_xor(r_hq,  off, 32);
        r_ent += __shfl_xor(r_ent, off, 32);
    }
    if (a == 0) {
        hq[h] = r_hq;
        part[(size_t)b * 16 + h]     = r_sq;
        part[(size_t)b * 16 + 8 + h] = r_ent;
    }
    __syncthreads();
    if (t == 0) {
        float y = vs;
        #pragma unroll
        for (int i = 0; i < NH; ++i) y = fmaf(whs[i], hq[i], y);
        out[b] = y;
    }
}

// ---------------------------------------------------------------------------
// K5: reduce [B_TOT][16] partials.
// ---------------------------------------------------------------------------
__global__ __launch_bounds__(256) void k_final(
    const float* __restrict__ part, float* __restrict__ out)
{
    __shared__ float red[17][17];
    const int t = threadIdx.x;
    const int c = t & 15, r = t >> 4;
    float val = 0.f;
    for (int b = r; b < B_TOT; b += 16)
        val += part[(size_t)b * 16 + c];
    red[r][c] = val;
    __syncthreads();
    if (t < 16) {
        float s = 0.f;
        #pragma unroll
        for (int i = 0; i < 16; ++i) s += red[i][t];
        red[16][t] = s;
    }
    __syncthreads();
    if (t == 0) {
        float s = 0.f;
        #pragma unroll
        for (int i = 0; i < 8; ++i) s += red[16][i];
        out[B_TOT] = 0.001f * (s / (float)((size_t)B_TOT * NA));
    }
    if (t >= 8 && t < 16)
        out[B_TOT + 1 + (t - 8)] = red[16][t] / (float)B_TOT;
}

extern "C" void kernel_launch(void* const* d_in, const int* in_sizes, int n_in,
                              void* d_out, int out_size, void* d_ws, size_t ws_size,
                              hipStream_t stream) {
    (void)in_sizes; (void)n_in; (void)out_size; (void)ws_size;
    const float* agent_qs = (const float*)d_in[0];
    const float* states   = (const float*)d_in[1];
    const int*   actions  = (const int*)d_in[2];
    const float* sel_W1   = (const float*)d_in[3];
    const float* sel_b1   = (const float*)d_in[4];
    const float* sel_W2   = (const float*)d_in[5];
    const float* key_W1   = (const float*)d_in[6];
    const float* key_b1   = (const float*)d_in[7];
    const float* key_W2   = (const float*)d_in[8];
    const float* wh_W1    = (const float*)d_in[9];
    const float* wh_b1    = (const float*)d_in[10];
    const float* wh_W2    = (const float*)d_in[11];
    const float* wh_b2    = (const float*)d_in[12];
    const float* v_W1     = (const float*)d_in[13];
    const float* v_b1     = (const float*)d_in[14];
    const float* v_W2     = (const float*)d_in[15];
    const float* v_b2     = (const float*)d_in[16];

    float* out = (float*)d_out;
    float* ws  = (float*)d_ws;
    float* h1_all = ws + WS_H1;
    float* m_buf  = ws + WS_M;
    float* wh_buf = ws + WS_WH;
    float* v_buf  = ws + WS_V;
    float* lg_buf = ws + WS_LG;
    float* part   = ws + WS_PART;
    ushort* Abf   = (ushort*)(ws + WS_ABF);
    ushort* Wbf   = (ushort*)(ws + WS_WBF);

    {
        const int groups_a = B_TOT * (KPAD / 4);
        const int groups_w = NTOT * (KPAD / 4);
        k_cvt_states<<<(groups_a + 255) / 256, 256, 0, stream>>>(states, Abf);
        k_cvt_w<<<(groups_w + 255) / 256, 256, 0, stream>>>(sel_W1, wh_W1, v_W1, Wbf);
    }
    k_gemm1_mfma<<<dim3(NTOT / 128, B_TOT / 128), 256, 0, stream>>>(
        Abf, Wbf, sel_b1, wh_b1, v_b1, h1_all);
    k_second<<<dim3(B_TOT / BT), 256, 0, stream>>>(
        h1_all, sel_W2, key_W2, wh_W2, wh_b2, v_W2, v_b2, m_buf, wh_buf, v_buf);
    k_logits<<<dim3(B_TOT, NH), 64, 0, stream>>>(
        states, agent_qs, key_W1, key_b1, m_buf, lg_buf);
    k_softmax<<<dim3(B_TOT), 256, 0, stream>>>(
        lg_buf, agent_qs, actions, wh_buf, v_buf, out, part);
    k_final<<<1, 256, 0, stream>>>(part, out);
}

// Round 4
// 283.692 us; speedup vs baseline: 3.7522x; 1.4523x over previous
//
#include <hip/hip_runtime.h>

#define B_TOT 4096
#define SDIM  1200
#define KPAD  1216   // SDIM padded to multiple of 64 for MFMA K-loop
#define NA    32
#define NH    8
#define EMB   64
#define KHID  128
#define HYP   256
#define NSEL  2048   // NH*HYP
#define NTOT  2560   // NSEL + 256 (wh hid) + 256 (v hid)
#define UKP   64     // units K (33) padded to 64

// workspace layout (float offsets)
#define WS_H1   0
#define WS_M    (WS_H1 + (size_t)B_TOT * NTOT)
#define WS_WH   (WS_M  + (size_t)B_TOT * NH * KHID)
#define WS_V    (WS_WH + (size_t)B_TOT * NH)
#define WS_LG   (WS_V  + (size_t)B_TOT)
#define WS_PART (WS_LG + (size_t)B_TOT * NH * NA)
#define WS_ABF  (WS_PART + (size_t)B_TOT * 16)                 // bf16 states [B_TOT][KPAD]
#define WS_WBF  (WS_ABF + ((size_t)B_TOT * KPAD) / 2)          // bf16 weights [NTOT][KPAD]
#define WS_KW1  (WS_WBF + ((size_t)NTOT * KPAD) / 2)           // bf16 key_W1 [1024][UKP]
// Ubf [B_TOT*NA][UKP] bf16 aliases h1_all (dead after k_second): 4.2M floats < 10.4M

typedef __attribute__((ext_vector_type(8))) short short8v;
typedef __attribute__((ext_vector_type(4))) float floatx4;

__device__ __forceinline__ ushort f2bf(float x) {
    unsigned u = __builtin_bit_cast(unsigned, x);
    unsigned r = (u + 0x7FFFu + ((u >> 16) & 1u)) >> 16;
    return (ushort)r;
}

// ---------------------------------------------------------------------------
// fp32 -> bf16 conversions
// ---------------------------------------------------------------------------
__global__ __launch_bounds__(256) void k_cvt_states(
    const float* __restrict__ src, ushort* __restrict__ dst)
{
    const size_t g = (size_t)blockIdx.x * 256 + threadIdx.x;
    if (g >= (size_t)B_TOT * (KPAD / 4)) return;
    const int row = (int)(g / (KPAD / 4));
    const int c4  = (int)(g % (KPAD / 4)) * 4;
    ushort4 o = {0, 0, 0, 0};
    if (c4 < SDIM) {
        float4 v = *(const float4*)(src + (size_t)row * SDIM + c4);
        o.x = f2bf(v.x); o.y = f2bf(v.y); o.z = f2bf(v.z); o.w = f2bf(v.w);
    }
    *(ushort4*)(dst + (size_t)row * KPAD + c4) = o;
}

__global__ __launch_bounds__(256) void k_cvt_w(
    const float* __restrict__ sel_W1, const float* __restrict__ wh_W1,
    const float* __restrict__ v_W1, ushort* __restrict__ dst)
{
    const size_t g = (size_t)blockIdx.x * 256 + threadIdx.x;
    if (g >= (size_t)NTOT * (KPAD / 4)) return;
    const int row = (int)(g / (KPAD / 4));
    const int c4  = (int)(g % (KPAD / 4)) * 4;
    const float* src = (row < NSEL)       ? (sel_W1 + (size_t)row * SDIM)
                     : (row < NSEL + HYP) ? (wh_W1 + (size_t)(row - NSEL) * SDIM)
                                          : (v_W1  + (size_t)(row - NSEL - HYP) * SDIM);
    ushort4 o = {0, 0, 0, 0};
    if (c4 < SDIM) {
        float4 v = *(const float4*)(src + c4);
        o.x = f2bf(v.x); o.y = f2bf(v.y); o.z = f2bf(v.z); o.w = f2bf(v.w);
    }
    *(ushort4*)(dst + (size_t)row * KPAD + c4) = o;
}

// units[b][a][u] = states[b][a*32+u] (u<32), q (u=32), 0 pad to 64. Row = b*32+a.
__global__ __launch_bounds__(256) void k_cvt_units(
    const float* __restrict__ states, const float* __restrict__ agent_qs,
    ushort* __restrict__ dst)
{
    const size_t g = (size_t)blockIdx.x * 256 + threadIdx.x;   // one short8 each
    if (g >= (size_t)B_TOT * NA * (UKP / 8)) return;
    const int row = (int)(g >> 3);
    const int seg = ((int)g & 7) * 8;
    const int b = row >> 5, a = row & 31;
    ushort o[8] = {0, 0, 0, 0, 0, 0, 0, 0};
    if (seg < 32) {
        const float* s = states + (size_t)b * SDIM + a * 32 + seg;
        float4 v0 = *(const float4*)(s);
        float4 v1 = *(const float4*)(s + 4);
        o[0] = f2bf(v0.x); o[1] = f2bf(v0.y); o[2] = f2bf(v0.z); o[3] = f2bf(v0.w);
        o[4] = f2bf(v1.x); o[5] = f2bf(v1.y); o[6] = f2bf(v1.z); o[7] = f2bf(v1.w);
    } else if (seg == 32) {
        o[0] = f2bf(agent_qs[(size_t)b * NA + a]);
    }
    *(ushort4*)(dst + (size_t)row * UKP + seg)     = *(ushort4*)&o[0];
    *(ushort4*)(dst + (size_t)row * UKP + seg + 4) = *(ushort4*)&o[4];
}

// key_W1 [8][128][33] -> bf16 [1024][UKP], zero-padded
__global__ __launch_bounds__(256) void k_cvt_kw1(
    const float* __restrict__ key_W1, ushort* __restrict__ dst)
{
    const int g = blockIdx.x * 256 + threadIdx.x;   // one short8 each
    if (g >= 1024 * (UKP / 8)) return;
    const int row = g >> 3;
    const int seg = (g & 7) * 8;
    ushort o[8] = {0, 0, 0, 0, 0, 0, 0, 0};
    #pragma unroll
    for (int j = 0; j < 8; ++j) {
        const int u = seg + j;
        if (u < 33) o[j] = f2bf(key_W1[(size_t)row * 33 + u]);
    }
    *(ushort4*)(dst + (size_t)row * UKP + seg)     = *(ushort4*)&o[0];
    *(ushort4*)(dst + (size_t)row * UKP + seg + 4) = *(ushort4*)&o[4];
}

// ---------------------------------------------------------------------------
// K1: bf16 MFMA GEMM. M=4096 N=2560 K=1216. 128x128 tile, 4 waves, BK=32.
// ---------------------------------------------------------------------------
#define BK 32
__global__ __launch_bounds__(256) void k_gemm1_mfma(
    const ushort* __restrict__ Abf, const ushort* __restrict__ Wbf,
    const float* __restrict__ sel_b1, const float* __restrict__ wh_b1,
    const float* __restrict__ v_b1, float* __restrict__ h1_all)
{
    __shared__ ushort As[128 * BK];
    __shared__ ushort Bs[128 * BK];
    const int tid = threadIdx.x;
    const int l   = tid & 63;
    const int w   = tid >> 6;
    const int wM  = w >> 1, wN = w & 1;
    const int arow0 = blockIdx.y * 128;
    const int nrow0 = blockIdx.x * 128;

    const int srow = tid >> 2;
    const int skof = (tid & 3) * 8;
    const ushort* gA = Abf + (size_t)(arow0 + srow) * KPAD + skof;
    const ushort* gB = Wbf + (size_t)(nrow0 + srow) * KPAD + skof;
    ushort* lA = &As[srow * BK + skof];
    ushort* lB = &Bs[srow * BK + skof];

    floatx4 acc[4][4] = {};

    for (int k0 = 0; k0 < KPAD; k0 += BK) {
        __builtin_amdgcn_global_load_lds(
            (const __attribute__((address_space(1))) unsigned int*)(gA + k0),
            (__attribute__((address_space(3))) unsigned int*)lA, 16, 0, 0);
        __builtin_amdgcn_global_load_lds(
            (const __attribute__((address_space(1))) unsigned int*)(gA + (size_t)64 * KPAD + k0),
            (__attribute__((address_space(3))) unsigned int*)(lA + 64 * BK), 16, 0, 0);
        __builtin_amdgcn_global_load_lds(
            (const __attribute__((address_space(1))) unsigned int*)(gB + k0),
            (__attribute__((address_space(3))) unsigned int*)lB, 16, 0, 0);
        __builtin_amdgcn_global_load_lds(
            (const __attribute__((address_space(1))) unsigned int*)(gB + (size_t)64 * KPAD + k0),
            (__attribute__((address_space(3))) unsigned int*)(lB + 64 * BK), 16, 0, 0);
        __syncthreads();

        const int kch = (l >> 4) * 8;
        short8v av[4], bv[4];
        #pragma unroll
        for (int mi = 0; mi < 4; ++mi)
            av[mi] = *(const short8v*)&As[(wM * 64 + mi * 16 + (l & 15)) * BK + kch];
        #pragma unroll
        for (int ni = 0; ni < 4; ++ni)
            bv[ni] = *(const short8v*)&Bs[(wN * 64 + ni * 16 + (l & 15)) * BK + kch];
        #pragma unroll
        for (int mi = 0; mi < 4; ++mi)
            #pragma unroll
            for (int ni = 0; ni < 4; ++ni)
                acc[mi][ni] = __builtin_amdgcn_mfma_f32_16x16x32_bf16(
                    av[mi], bv[ni], acc[mi][ni], 0, 0, 0);
        __syncthreads();
    }

    float bias_n[4];
    #pragma unroll
    for (int ni = 0; ni < 4; ++ni) {
        const int col = nrow0 + wN * 64 + ni * 16 + (l & 15);
        bias_n[ni] = (col < NSEL)       ? sel_b1[col]
                   : (col < NSEL + HYP) ? wh_b1[col - NSEL]
                                        : v_b1[col - NSEL - HYP];
    }
    #pragma unroll
    for (int mi = 0; mi < 4; ++mi) {
        const int row = arow0 + wM * 64 + mi * 16 + (l >> 4) * 4;
        #pragma unroll
        for (int ni = 0; ni < 4; ++ni) {
            const int col = nrow0 + wN * 64 + ni * 16 + (l & 15);
            #pragma unroll
            for (int r = 0; r < 4; ++r)
                h1_all[(size_t)(row + r) * NTOT + col] =
                    fmaxf(acc[mi][ni][r] + bias_n[ni], 0.f);
        }
    }
}

// ---------------------------------------------------------------------------
// K2: second layers, 4 batch rows per block.
// ---------------------------------------------------------------------------
#define BT 4
__global__ __launch_bounds__(256) void k_second(
    const float* __restrict__ h1_all, const float* __restrict__ sel_W2,
    const float* __restrict__ key_W2, const float* __restrict__ wh_W2,
    const float* __restrict__ wh_b2,  const float* __restrict__ v_W2,
    const float* __restrict__ v_b2,
    float* __restrict__ m_out, float* __restrict__ wh_out, float* __restrict__ v_out)
{
    __shared__ __align__(16) float rowbuf[BT][NTOT];
    __shared__ __align__(16) float sel_lds[BT][NH * EMB];
    const int t  = threadIdx.x;
    const int b0 = blockIdx.x * BT;

    #pragma unroll
    for (int bi = 0; bi < BT; ++bi)
        #pragma unroll
        for (int j = 0; j < NTOT / 256; ++j)
            rowbuf[bi][j * 256 + t] = h1_all[(size_t)(b0 + bi) * NTOT + j * 256 + t];
    __syncthreads();

    #pragma unroll
    for (int rep = 0; rep < 2; ++rep) {
        const int o = t + rep * 256;
        const int h = o >> 6, d = o & 63;
        const float* w = sel_W2 + (size_t)(h * EMB + d) * HYP;
        float acc0 = 0.f, acc1 = 0.f, acc2 = 0.f, acc3 = 0.f;
        for (int e = 0; e < HYP; e += 4) {
            float4 wv = *(const float4*)(w + e);
            float4 r0 = *(const float4*)&rowbuf[0][h * HYP + e];
            float4 r1 = *(const float4*)&rowbuf[1][h * HYP + e];
            float4 r2 = *(const float4*)&rowbuf[2][h * HYP + e];
            float4 r3 = *(const float4*)&rowbuf[3][h * HYP + e];
            acc0 += r0.x * wv.x + r0.y * wv.y + r0.z * wv.z + r0.w * wv.w;
            acc1 += r1.x * wv.x + r1.y * wv.y + r1.z * wv.z + r1.w * wv.w;
            acc2 += r2.x * wv.x + r2.y * wv.y + r2.z * wv.z + r2.w * wv.w;
            acc3 += r3.x * wv.x + r3.y * wv.y + r3.z * wv.z + r3.w * wv.w;
        }
        sel_lds[0][o] = acc0; sel_lds[1][o] = acc1;
        sel_lds[2][o] = acc2; sel_lds[3][o] = acc3;
    }
    __syncthreads();

    #pragma unroll
    for (int jj = 0; jj < 4; ++jj) {
        const int o = t + jj * 256;
        const int h = o >> 7, k = o & 127;
        float acc0 = 0.f, acc1 = 0.f, acc2 = 0.f, acc3 = 0.f;
        for (int d = 0; d < EMB; ++d) {
            const float wv = key_W2[(size_t)(h * EMB + d) * KHID + k];
            acc0 = fmaf(sel_lds[0][h * EMB + d], wv, acc0);
            acc1 = fmaf(sel_lds[1][h * EMB + d], wv, acc1);
            acc2 = fmaf(sel_lds[2][h * EMB + d], wv, acc2);
            acc3 = fmaf(sel_lds[3][h * EMB + d], wv, acc3);
        }
        m_out[((size_t)(b0 + 0) * NH + h) * KHID + k] = acc0;
        m_out[((size_t)(b0 + 1) * NH + h) * KHID + k] = acc1;
        m_out[((size_t)(b0 + 2) * NH + h) * KHID + k] = acc2;
        m_out[((size_t)(b0 + 3) * NH + h) * KHID + k] = acc3;
    }

    if (t < 32) {
        const int bi = t >> 3, h = t & 7;
        float a = 0.f;
        for (int e = 0; e < HYP; ++e)
            a = fmaf(rowbuf[bi][NSEL + e], wh_W2[h * HYP + e], a);
        wh_out[(b0 + bi) * NH + h] = fabsf(a + wh_b2[h]);
    } else if (t < 36) {
        const int bi = t - 32;
        float a = 0.f;
        for (int e = 0; e < HYP; ++e)
            a = fmaf(rowbuf[bi][NSEL + 256 + e], v_W2[e], a);
        v_out[b0 + bi] = a + v_b2[0];
    }
}

// ---------------------------------------------------------------------------
// K3: MFMA logits. Grid (h, row-tile). Tile: 128 U-rows x 128 k-cols, K=64.
// Epilogue fuses relu(+b1)*m and the col-reduction -> logits[b,h,a].
// ---------------------------------------------------------------------------
__global__ __launch_bounds__(256) void k_logits_mfma(
    const ushort* __restrict__ Ubf, const ushort* __restrict__ KW1bf,
    const float* __restrict__ key_b1, const float* __restrict__ m_in,
    float* __restrict__ logits)
{
    __shared__ ushort Us[128 * UKP];
    __shared__ ushort Ws[128 * UKP];
    __shared__ float m_lds[4][KHID];
    __shared__ float b1_lds[KHID];
    __shared__ float red[128][2];
    const int tid = threadIdx.x;
    const int l = tid & 63;
    const int w = tid >> 6;
    const int wM = w >> 1, wN = w & 1;
    const int h  = blockIdx.x;
    const int r0 = blockIdx.y * 128;   // U row base
    const int b0 = blockIdx.y * 4;     // batch base

    // stage: 4 issues each; lds byte = 16*tid + c*4096 (wave-uniform + 16*lane)
    const int srow = tid >> 3;
    const int sel8 = (tid & 7) * 8;
    #pragma unroll
    for (int c = 0; c < 4; ++c)
        __builtin_amdgcn_global_load_lds(
            (const __attribute__((address_space(1))) unsigned int*)
                (Ubf + (size_t)(r0 + srow + c * 32) * UKP + sel8),
            (__attribute__((address_space(3))) unsigned int*)
                (&Us[0] + (size_t)tid * 8 + c * 2048), 16, 0, 0);
    #pragma unroll
    for (int c = 0; c < 4; ++c)
        __builtin_amdgcn_global_load_lds(
            (const __attribute__((address_space(1))) unsigned int*)
                (KW1bf + (size_t)(h * 128 + srow + c * 32) * UKP + sel8),
            (__attribute__((address_space(3))) unsigned int*)
                (&Ws[0] + (size_t)tid * 8 + c * 2048), 16, 0, 0);
    #pragma unroll
    for (int j = 0; j < 2; ++j) {
        const int idx = tid + j * 256;
        m_lds[idx >> 7][idx & 127] =
            m_in[((size_t)(b0 + (idx >> 7)) * NH + h) * KHID + (idx & 127)];
    }
    if (tid < 128) b1_lds[tid] = key_b1[h * KHID + tid];
    __syncthreads();

    floatx4 acc[4][4] = {};
    short8v bv[4][2];
    #pragma unroll
    for (int ni = 0; ni < 4; ++ni)
        #pragma unroll
        for (int kc = 0; kc < 2; ++kc)
            bv[ni][kc] = *(const short8v*)
                &Ws[(wN * 64 + ni * 16 + (l & 15)) * UKP + kc * 32 + (l >> 4) * 8];
    #pragma unroll
    for (int mi = 0; mi < 4; ++mi) {
        short8v av0 = *(const short8v*)
            &Us[(wM * 64 + mi * 16 + (l & 15)) * UKP + (l >> 4) * 8];
        short8v av1 = *(const short8v*)
            &Us[(wM * 64 + mi * 16 + (l & 15)) * UKP + 32 + (l >> 4) * 8];
        #pragma unroll
        for (int ni = 0; ni < 4; ++ni) {
            acc[mi][ni] = __builtin_amdgcn_mfma_f32_16x16x32_bf16(
                av0, bv[ni][0], acc[mi][ni], 0, 0, 0);
            acc[mi][ni] = __builtin_amdgcn_mfma_f32_16x16x32_bf16(
                av1, bv[ni][1], acc[mi][ni], 0, 0, 0);
        }
    }

    // epilogue: relu(+b1)*m, reduce over cols
    #pragma unroll
    for (int mi = 0; mi < 4; ++mi) {
        const int rowbase = wM * 64 + mi * 16 + (l >> 4) * 4;
        const int bi = (wM * 64 + mi * 16) >> 5;
        float s0 = 0.f, s1 = 0.f, s2 = 0.f, s3 = 0.f;
        #pragma unroll
        for (int ni = 0; ni < 4; ++ni) {
            const int col = wN * 64 + ni * 16 + (l & 15);
            const float b1v = b1_lds[col];
            const float mv  = m_lds[bi][col];
            s0 = fmaf(fmaxf(acc[mi][ni][0] + b1v, 0.f), mv, s0);
            s1 = fmaf(fmaxf(acc[mi][ni][1] + b1v, 0.f), mv, s1);
            s2 = fmaf(fmaxf(acc[mi][ni][2] + b1v, 0.f), mv, s2);
            s3 = fmaf(fmaxf(acc[mi][ni][3] + b1v, 0.f), mv, s3);
        }
        #pragma unroll
        for (int off = 8; off >= 1; off >>= 1) {
            s0 += __shfl_xor(s0, off);
            s1 += __shfl_xor(s1, off);
            s2 += __shfl_xor(s2, off);
            s3 += __shfl_xor(s3, off);
        }
        if ((l & 15) == 0) {
            red[rowbase + 0][wN] = s0;
            red[rowbase + 1][wN] = s1;
            red[rowbase + 2][wN] = s2;
            red[rowbase + 3][wN] = s3;
        }
    }
    __syncthreads();
    if (tid < 128) {
        const float sum = red[tid][0] + red[tid][1];
        const int b = b0 + (tid >> 5), a = tid & 31;
        logits[((size_t)b * NH + h) * NA + a] = sum;
    }
}

// ---------------------------------------------------------------------------
// K4: masked softmax, head_q, final mix; per-block partials (no atomics).
// ---------------------------------------------------------------------------
__global__ __launch_bounds__(256) void k_softmax(
    const float* __restrict__ logits, const float* __restrict__ agent_qs,
    const int* __restrict__ actions, const float* __restrict__ wh,
    const float* __restrict__ v, float* __restrict__ out,
    float* __restrict__ part)
{
    __shared__ float qs[NA];
    __shared__ int   act_s[NA];
    __shared__ float whs[NH];
    __shared__ float hq[NH];
    __shared__ float vs;
    const int b = blockIdx.x, t = threadIdx.x;
    if (t < NA) {
        qs[t]    = agent_qs[(size_t)b * NA + t];
        act_s[t] = actions[(size_t)b * NA + t];
    } else if (t < NA + NH) {
        whs[t - NA] = wh[(size_t)b * NH + (t - NA)];
    } else if (t == NA + NH) {
        vs = v[b];
    }
    __syncthreads();

    const int h = t >> 5, a = t & 31;
    const float lg = logits[((size_t)b * NH + h) * NA + a];
    float sc = (act_s[a] == 0) ? -99999999.0f : lg * 0.125f;

    float mx = sc;
    #pragma unroll
    for (int off = 16; off >= 1; off >>= 1) mx = fmaxf(mx, __shfl_xor(mx, off, 32));
    const float e = expf(sc - mx);
    float sum = e;
    #pragma unroll
    for (int off = 16; off >= 1; off >>= 1) sum += __shfl_xor(sum, off, 32);
    const float w = e / sum;

    float r_sq  = lg * lg;
    float r_hq  = qs[a] * w;
    float r_ent = -w * logf(w + 1e-8f);
    #pragma unroll
    for (int off = 16; off >= 1; off >>= 1) {
        r_sq  += __shfl_xor(r_sq,  off, 32);
        r_hq  += __shfl_xor(r_hq,  off, 32);
        r_ent += __shfl_xor(r_ent, off, 32);
    }
    if (a == 0) {
        hq[h] = r_hq;
        part[(size_t)b * 16 + h]     = r_sq;
        part[(size_t)b * 16 + 8 + h] = r_ent;
    }
    __syncthreads();
    if (t == 0) {
        float y = vs;
        #pragma unroll
        for (int i = 0; i < NH; ++i) y = fmaf(whs[i], hq[i], y);
        out[b] = y;
    }
}

// ---------------------------------------------------------------------------
// K5: reduce [B_TOT][16] partials.
// ---------------------------------------------------------------------------
__global__ __launch_bounds__(256) void k_final(
    const float* __restrict__ part, float* __restrict__ out)
{
    __shared__ float red[17][17];
    const int t = threadIdx.x;
    const int c = t & 15, r = t >> 4;
    float val = 0.f;
    for (int b = r; b < B_TOT; b += 16)
        val += part[(size_t)b * 16 + c];
    red[r][c] = val;
    __syncthreads();
    if (t < 16) {
        float s = 0.f;
        #pragma unroll
        for (int i = 0; i < 16; ++i) s += red[i][t];
        red[16][t] = s;
    }
    __syncthreads();
    if (t == 0) {
        float s = 0.f;
        #pragma unroll
        for (int i = 0; i < 8; ++i) s += red[16][i];
        out[B_TOT] = 0.001f * (s / (float)((size_t)B_TOT * NA));
    }
    if (t >= 8 && t < 16)
        out[B_TOT + 1 + (t - 8)] = red[16][t] / (float)B_TOT;
}

extern "C" void kernel_launch(void* const* d_in, const int* in_sizes, int n_in,
                              void* d_out, int out_size, void* d_ws, size_t ws_size,
                              hipStream_t stream) {
    (void)in_sizes; (void)n_in; (void)out_size; (void)ws_size;
    const float* agent_qs = (const float*)d_in[0];
    const float* states   = (const float*)d_in[1];
    const int*   actions  = (const int*)d_in[2];
    const float* sel_W1   = (const float*)d_in[3];
    const float* sel_b1   = (const float*)d_in[4];
    const float* sel_W2   = (const float*)d_in[5];
    const float* key_W1   = (const float*)d_in[6];
    const float* key_b1   = (const float*)d_in[7];
    const float* key_W2   = (const float*)d_in[8];
    const float* wh_W1    = (const float*)d_in[9];
    const float* wh_b1    = (const float*)d_in[10];
    const float* wh_W2    = (const float*)d_in[11];
    const float* wh_b2    = (const float*)d_in[12];
    const float* v_W1     = (const float*)d_in[13];
    const float* v_b1     = (const float*)d_in[14];
    const float* v_W2     = (const float*)d_in[15];
    const float* v_b2     = (const float*)d_in[16];

    float* out = (float*)d_out;
    float* ws  = (float*)d_ws;
    float* h1_all = ws + WS_H1;
    float* m_buf  = ws + WS_M;
    float* wh_buf = ws + WS_WH;
    float* v_buf  = ws + WS_V;
    float* lg_buf = ws + WS_LG;
    float* part   = ws + WS_PART;
    ushort* Abf   = (ushort*)(ws + WS_ABF);
    ushort* Wbf   = (ushort*)(ws + WS_WBF);
    ushort* KW1bf = (ushort*)(ws + WS_KW1);
    ushort* Ubf   = (ushort*)(ws + WS_H1);   // aliases h1_all (dead after k_second)

    {
        const int groups_a = B_TOT * (KPAD / 4);
        const int groups_w = NTOT * (KPAD / 4);
        k_cvt_states<<<(groups_a + 255) / 256, 256, 0, stream>>>(states, Abf);
        k_cvt_w<<<(groups_w + 255) / 256, 256, 0, stream>>>(sel_W1, wh_W1, v_W1, Wbf);
        k_cvt_kw1<<<32, 256, 0, stream>>>(key_W1, KW1bf);
    }
    k_gemm1_mfma<<<dim3(NTOT / 128, B_TOT / 128), 256, 0, stream>>>(
        Abf, Wbf, sel_b1, wh_b1, v_b1, h1_all);
    k_second<<<dim3(B_TOT / BT), 256, 0, stream>>>(
        h1_all, sel_W2, key_W2, wh_W2, wh_b2, v_W2, v_b2, m_buf, wh_buf, v_buf);
    // h1_all dead from here; Ubf reuses its storage
    k_cvt_units<<<(B_TOT * NA * (UKP / 8) + 255) / 256, 256, 0, stream>>>(
        states, agent_qs, Ubf);
    k_logits_mfma<<<dim3(NH, (B_TOT * NA) / 128), 256, 0, stream>>>(
        Ubf, KW1bf, key_b1, m_buf, lg_buf);
    k_softmax<<<dim3(B_TOT), 256, 0, stream>>>(
        lg_buf, agent_qs, actions, wh_buf, v_buf, out, part);
    k_final<<<1, 256, 0, stream>>>(part, out);
}

// Round 5
// 197.782 us; speedup vs baseline: 5.3820x; 1.4344x over previous
//
#include <hip/hip_runtime.h>

#define B_TOT 4096
#define SDIM  1200
#define KPAD  1216   // SDIM padded to multiple of 64 for MFMA K-loop
#define NA    32
#define NH    8
#define EMB   64
#define KHID  128
#define HYP   256
#define NSEL  2048   // NH*HYP
#define NTOT  2560   // NSEL + 256 (wh hid) + 256 (v hid)
#define UKP   64     // units K (33) padded to 64

// workspace layout (float offsets)
#define WS_H1BF 0                                              // bf16 h1 [B_TOT][NTOT] (10.49M ushorts)
#define WS_M    (WS_H1BF + (size_t)B_TOT * NTOT / 2)           // fp32 m [B_TOT][NH][KHID]
#define WS_LG   (WS_M    + (size_t)B_TOT * NH * KHID)
#define WS_PART (WS_LG   + (size_t)B_TOT * NH * NA)
#define WS_ABF  (WS_PART + (size_t)B_TOT * 16)                 // bf16 states [B_TOT][KPAD]
#define WS_WBF  (WS_ABF  + (size_t)B_TOT * KPAD / 2)           // bf16 W1 [NTOT][KPAD]
#define WS_KW1  (WS_WBF  + (size_t)NTOT * KPAD / 2)            // bf16 key_W1 [1024][UKP]
#define WS_M2T  (WS_KW1  + (size_t)1024 * UKP / 2)             // bf16 M2T [NH][KHID][HYP]
#define WS_UBF  (WS_M2T  + (size_t)NH * KHID * HYP / 2)        // bf16 units [B_TOT*NA][UKP]

typedef __attribute__((ext_vector_type(8))) short short8v;
typedef __attribute__((ext_vector_type(4))) float floatx4;

__device__ __forceinline__ ushort f2bf(float x) {
    unsigned u = __builtin_bit_cast(unsigned, x);
    unsigned r = (u + 0x7FFFu + ((u >> 16) & 1u)) >> 16;
    return (ushort)r;
}
__device__ __forceinline__ float bf2f(ushort u) {
    unsigned x = ((unsigned)u) << 16;
    return __builtin_bit_cast(float, x);
}

// ---------------------------------------------------------------------------
// fp32 -> bf16 conversions
// ---------------------------------------------------------------------------
__global__ __launch_bounds__(256) void k_cvt_states(
    const float* __restrict__ src, ushort* __restrict__ dst)
{
    const size_t g = (size_t)blockIdx.x * 256 + threadIdx.x;
    if (g >= (size_t)B_TOT * (KPAD / 4)) return;
    const int row = (int)(g / (KPAD / 4));
    const int c4  = (int)(g % (KPAD / 4)) * 4;
    ushort4 o = {0, 0, 0, 0};
    if (c4 < SDIM) {
        float4 v = *(const float4*)(src + (size_t)row * SDIM + c4);
        o.x = f2bf(v.x); o.y = f2bf(v.y); o.z = f2bf(v.z); o.w = f2bf(v.w);
    }
    *(ushort4*)(dst + (size_t)row * KPAD + c4) = o;
}

__global__ __launch_bounds__(256) void k_cvt_w(
    const float* __restrict__ sel_W1, const float* __restrict__ wh_W1,
    const float* __restrict__ v_W1, ushort* __restrict__ dst)
{
    const size_t g = (size_t)blockIdx.x * 256 + threadIdx.x;
    if (g >= (size_t)NTOT * (KPAD / 4)) return;
    const int row = (int)(g / (KPAD / 4));
    const int c4  = (int)(g % (KPAD / 4)) * 4;
    const float* src = (row < NSEL)       ? (sel_W1 + (size_t)row * SDIM)
                     : (row < NSEL + HYP) ? (wh_W1 + (size_t)(row - NSEL) * SDIM)
                                          : (v_W1  + (size_t)(row - NSEL - HYP) * SDIM);
    ushort4 o = {0, 0, 0, 0};
    if (c4 < SDIM) {
        float4 v = *(const float4*)(src + c4);
        o.x = f2bf(v.x); o.y = f2bf(v.y); o.z = f2bf(v.z); o.w = f2bf(v.w);
    }
    *(ushort4*)(dst + (size_t)row * KPAD + c4) = o;
}

// units[b][a][u] = states[b][a*32+u] (u<32), q (u=32), 0 pad to 64. Row = b*32+a.
__global__ __launch_bounds__(256) void k_cvt_units(
    const float* __restrict__ states, const float* __restrict__ agent_qs,
    ushort* __restrict__ dst)
{
    const size_t g = (size_t)blockIdx.x * 256 + threadIdx.x;   // one short8 each
    if (g >= (size_t)B_TOT * NA * (UKP / 8)) return;
    const int row = (int)(g >> 3);
    const int seg = ((int)g & 7) * 8;
    const int b = row >> 5, a = row & 31;
    ushort o[8] = {0, 0, 0, 0, 0, 0, 0, 0};
    if (seg < 32) {
        const float* s = states + (size_t)b * SDIM + a * 32 + seg;
        float4 v0 = *(const float4*)(s);
        float4 v1 = *(const float4*)(s + 4);
        o[0] = f2bf(v0.x); o[1] = f2bf(v0.y); o[2] = f2bf(v0.z); o[3] = f2bf(v0.w);
        o[4] = f2bf(v1.x); o[5] = f2bf(v1.y); o[6] = f2bf(v1.z); o[7] = f2bf(v1.w);
    } else if (seg == 32) {
        o[0] = f2bf(agent_qs[(size_t)b * NA + a]);
    }
    *(ushort4*)(dst + (size_t)row * UKP + seg)     = *(ushort4*)&o[0];
    *(ushort4*)(dst + (size_t)row * UKP + seg + 4) = *(ushort4*)&o[4];
}

// key_W1 [8][128][33] -> bf16 [1024][UKP], zero-padded
__global__ __launch_bounds__(256) void k_cvt_kw1(
    const float* __restrict__ key_W1, ushort* __restrict__ dst)
{
    const int g = blockIdx.x * 256 + threadIdx.x;   // one short8 each
    if (g >= 1024 * (UKP / 8)) return;
    const int row = g >> 3;
    const int seg = (g & 7) * 8;
    ushort o[8] = {0, 0, 0, 0, 0, 0, 0, 0};
    #pragma unroll
    for (int j = 0; j < 8; ++j) {
        const int u = seg + j;
        if (u < 33) o[j] = f2bf(key_W1[(size_t)row * 33 + u]);
    }
    *(ushort4*)(dst + (size_t)row * UKP + seg)     = *(ushort4*)&o[0];
    *(ushort4*)(dst + (size_t)row * UKP + seg + 4) = *(ushort4*)&o[4];
}

// ---------------------------------------------------------------------------
// M2T[h][k][e] = sum_d sel_W2[h][d][e] * key_W2[h][d][k]  (bf16 out)
// Grid (NH, KHID/8). Block stages sel_W2[h] (64KB) + key_W2 k-slice.
// ---------------------------------------------------------------------------
__global__ __launch_bounds__(256) void k_m2(
    const float* __restrict__ sel_W2, const float* __restrict__ key_W2,
    ushort* __restrict__ M2T)
{
    __shared__ float ssel[EMB * HYP];   // [d][e], 64 KB
    __shared__ float skey[EMB][8];
    const int t  = threadIdx.x;
    const int h  = blockIdx.x;
    const int k0 = blockIdx.y * 8;

    const float4* sw = (const float4*)(sel_W2 + (size_t)h * EMB * HYP);
    #pragma unroll
    for (int j = 0; j < 16; ++j)
        ((float4*)ssel)[j * 256 + t] = sw[j * 256 + t];
    if (t < EMB) {
        #pragma unroll
        for (int kk = 0; kk < 8; ++kk)
            skey[t][kk] = key_W2[((size_t)h * EMB + t) * KHID + k0 + kk];
    }
    __syncthreads();

    const int e = t;
    float acc[8] = {};
    for (int d = 0; d < EMB; ++d) {
        const float sv = ssel[d * HYP + e];
        #pragma unroll
        for (int kk = 0; kk < 8; ++kk)
            acc[kk] = fmaf(sv, skey[d][kk], acc[kk]);
    }
    #pragma unroll
    for (int kk = 0; kk < 8; ++kk)
        M2T[((size_t)h * KHID + k0 + kk) * HYP + e] = f2bf(acc[kk]);
}

// ---------------------------------------------------------------------------
// K1: bf16 MFMA GEMM. M=4096 N=2560 K=1216. 128x128 tile, 4 waves, BK=32.
// Epilogue: +bias, relu, bf16 store.
// ---------------------------------------------------------------------------
#define BK 32
__global__ __launch_bounds__(256) void k_gemm1_mfma(
    const ushort* __restrict__ Abf, const ushort* __restrict__ Wbf,
    const float* __restrict__ sel_b1, const float* __restrict__ wh_b1,
    const float* __restrict__ v_b1, ushort* __restrict__ h1bf)
{
    __shared__ ushort As[128 * BK];
    __shared__ ushort Bs[128 * BK];
    const int tid = threadIdx.x;
    const int l   = tid & 63;
    const int w   = tid >> 6;
    const int wM  = w >> 1, wN = w & 1;
    const int arow0 = blockIdx.y * 128;
    const int nrow0 = blockIdx.x * 128;

    const int srow = tid >> 2;
    const int skof = (tid & 3) * 8;
    const ushort* gA = Abf + (size_t)(arow0 + srow) * KPAD + skof;
    const ushort* gB = Wbf + (size_t)(nrow0 + srow) * KPAD + skof;
    ushort* lA = &As[srow * BK + skof];
    ushort* lB = &Bs[srow * BK + skof];

    floatx4 acc[4][4] = {};

    for (int k0 = 0; k0 < KPAD; k0 += BK) {
        __builtin_amdgcn_global_load_lds(
            (const __attribute__((address_space(1))) unsigned int*)(gA + k0),
            (__attribute__((address_space(3))) unsigned int*)lA, 16, 0, 0);
        __builtin_amdgcn_global_load_lds(
            (const __attribute__((address_space(1))) unsigned int*)(gA + (size_t)64 * KPAD + k0),
            (__attribute__((address_space(3))) unsigned int*)(lA + 64 * BK), 16, 0, 0);
        __builtin_amdgcn_global_load_lds(
            (const __attribute__((address_space(1))) unsigned int*)(gB + k0),
            (__attribute__((address_space(3))) unsigned int*)lB, 16, 0, 0);
        __builtin_amdgcn_global_load_lds(
            (const __attribute__((address_space(1))) unsigned int*)(gB + (size_t)64 * KPAD + k0),
            (__attribute__((address_space(3))) unsigned int*)(lB + 64 * BK), 16, 0, 0);
        __syncthreads();

        const int kch = (l >> 4) * 8;
        short8v av[4], bv[4];
        #pragma unroll
        for (int mi = 0; mi < 4; ++mi)
            av[mi] = *(const short8v*)&As[(wM * 64 + mi * 16 + (l & 15)) * BK + kch];
        #pragma unroll
        for (int ni = 0; ni < 4; ++ni)
            bv[ni] = *(const short8v*)&Bs[(wN * 64 + ni * 16 + (l & 15)) * BK + kch];
        #pragma unroll
        for (int mi = 0; mi < 4; ++mi)
            #pragma unroll
            for (int ni = 0; ni < 4; ++ni)
                acc[mi][ni] = __builtin_amdgcn_mfma_f32_16x16x32_bf16(
                    av[mi], bv[ni], acc[mi][ni], 0, 0, 0);
        __syncthreads();
    }

    float bias_n[4];
    #pragma unroll
    for (int ni = 0; ni < 4; ++ni) {
        const int col = nrow0 + wN * 64 + ni * 16 + (l & 15);
        bias_n[ni] = (col < NSEL)       ? sel_b1[col]
                   : (col < NSEL + HYP) ? wh_b1[col - NSEL]
                                        : v_b1[col - NSEL - HYP];
    }
    #pragma unroll
    for (int mi = 0; mi < 4; ++mi) {
        const int row = arow0 + wM * 64 + mi * 16 + (l >> 4) * 4;
        #pragma unroll
        for (int ni = 0; ni < 4; ++ni) {
            const int col = nrow0 + wN * 64 + ni * 16 + (l & 15);
            #pragma unroll
            for (int r = 0; r < 4; ++r)
                h1bf[(size_t)(row + r) * NTOT + col] =
                    f2bf(fmaxf(acc[mi][ni][r] + bias_n[ni], 0.f));
        }
    }
}

// ---------------------------------------------------------------------------
// K2: per-head m GEMM. m[b,h,k] = sum_e h1bf[b, h*256+e] * M2T[h][k][e].
// Grid (NH, B_TOT/128). Same 128x128x(K=256) MFMA structure as K1.
// ---------------------------------------------------------------------------
__global__ __launch_bounds__(256) void k_m_mfma(
    const ushort* __restrict__ h1bf, const ushort* __restrict__ M2T,
    float* __restrict__ m_out)
{
    __shared__ ushort As[128 * BK];
    __shared__ ushort Bs[128 * BK];
    const int tid = threadIdx.x;
    const int l   = tid & 63;
    const int w   = tid >> 6;
    const int wM  = w >> 1, wN = w & 1;
    const int h     = blockIdx.x;
    const int brow0 = blockIdx.y * 128;

    const int srow = tid >> 2;
    const int skof = (tid & 3) * 8;
    const ushort* gA = h1bf + (size_t)(brow0 + srow) * NTOT + h * HYP + skof;
    const ushort* gB = M2T + ((size_t)h * KHID + srow) * HYP + skof;
    ushort* lA = &As[srow * BK + skof];
    ushort* lB = &Bs[srow * BK + skof];

    floatx4 acc[4][4] = {};

    for (int k0 = 0; k0 < HYP; k0 += BK) {
        __builtin_amdgcn_global_load_lds(
            (const __attribute__((address_space(1))) unsigned int*)(gA + k0),
            (__attribute__((address_space(3))) unsigned int*)lA, 16, 0, 0);
        __builtin_amdgcn_global_load_lds(
            (const __attribute__((address_space(1))) unsigned int*)(gA + (size_t)64 * NTOT + k0),
            (__attribute__((address_space(3))) unsigned int*)(lA + 64 * BK), 16, 0, 0);
        __builtin_amdgcn_global_load_lds(
            (const __attribute__((address_space(1))) unsigned int*)(gB + k0),
            (__attribute__((address_space(3))) unsigned int*)lB, 16, 0, 0);
        __builtin_amdgcn_global_load_lds(
            (const __attribute__((address_space(1))) unsigned int*)(gB + (size_t)64 * HYP + k0),
            (__attribute__((address_space(3))) unsigned int*)(lB + 64 * BK), 16, 0, 0);
        __syncthreads();

        const int kch = (l >> 4) * 8;
        short8v av[4], bv[4];
        #pragma unroll
        for (int mi = 0; mi < 4; ++mi)
            av[mi] = *(const short8v*)&As[(wM * 64 + mi * 16 + (l & 15)) * BK + kch];
        #pragma unroll
        for (int ni = 0; ni < 4; ++ni)
            bv[ni] = *(const short8v*)&Bs[(wN * 64 + ni * 16 + (l & 15)) * BK + kch];
        #pragma unroll
        for (int mi = 0; mi < 4; ++mi)
            #pragma unroll
            for (int ni = 0; ni < 4; ++ni)
                acc[mi][ni] = __builtin_amdgcn_mfma_f32_16x16x32_bf16(
                    av[mi], bv[ni], acc[mi][ni], 0, 0, 0);
        __syncthreads();
    }

    #pragma unroll
    for (int mi = 0; mi < 4; ++mi) {
        const int row = brow0 + wM * 64 + mi * 16 + (l >> 4) * 4;
        #pragma unroll
        for (int ni = 0; ni < 4; ++ni) {
            const int col = wN * 64 + ni * 16 + (l & 15);
            #pragma unroll
            for (int r = 0; r < 4; ++r)
                m_out[((size_t)(row + r) * NH + h) * KHID + col] = acc[mi][ni][r];
        }
    }
}

// ---------------------------------------------------------------------------
// K3: MFMA logits. Grid (h, row-tile). Tile: 128 U-rows x 128 k-cols, K=64.
// Epilogue fuses relu(+b1)*m and the col-reduction -> logits[b,h,a].
// ---------------------------------------------------------------------------
__global__ __launch_bounds__(256) void k_logits_mfma(
    const ushort* __restrict__ Ubf, const ushort* __restrict__ KW1bf,
    const float* __restrict__ key_b1, const float* __restrict__ m_in,
    float* __restrict__ logits)
{
    __shared__ ushort Us[128 * UKP];
    __shared__ ushort Ws[128 * UKP];
    __shared__ float m_lds[4][KHID];
    __shared__ float b1_lds[KHID];
    __shared__ float red[128][2];
    const int tid = threadIdx.x;
    const int l = tid & 63;
    const int w = tid >> 6;
    const int wM = w >> 1, wN = w & 1;
    const int h  = blockIdx.x;
    const int r0 = blockIdx.y * 128;   // U row base
    const int b0 = blockIdx.y * 4;     // batch base

    const int srow = tid >> 3;
    const int sel8 = (tid & 7) * 8;
    #pragma unroll
    for (int c = 0; c < 4; ++c)
        __builtin_amdgcn_global_load_lds(
            (const __attribute__((address_space(1))) unsigned int*)
                (Ubf + (size_t)(r0 + srow + c * 32) * UKP + sel8),
            (__attribute__((address_space(3))) unsigned int*)
                (&Us[0] + (size_t)tid * 8 + c * 2048), 16, 0, 0);
    #pragma unroll
    for (int c = 0; c < 4; ++c)
        __builtin_amdgcn_global_load_lds(
            (const __attribute__((address_space(1))) unsigned int*)
                (KW1bf + (size_t)(h * 128 + srow + c * 32) * UKP + sel8),
            (__attribute__((address_space(3))) unsigned int*)
                (&Ws[0] + (size_t)tid * 8 + c * 2048), 16, 0, 0);
    #pragma unroll
    for (int j = 0; j < 2; ++j) {
        const int idx = tid + j * 256;
        m_lds[idx >> 7][idx & 127] =
            m_in[((size_t)(b0 + (idx >> 7)) * NH + h) * KHID + (idx & 127)];
    }
    if (tid < 128) b1_lds[tid] = key_b1[h * KHID + tid];
    __syncthreads();

    floatx4 acc[4][4] = {};
    short8v bv[4][2];
    #pragma unroll
    for (int ni = 0; ni < 4; ++ni)
        #pragma unroll
        for (int kc = 0; kc < 2; ++kc)
            bv[ni][kc] = *(const short8v*)
                &Ws[(wN * 64 + ni * 16 + (l & 15)) * UKP + kc * 32 + (l >> 4) * 8];
    #pragma unroll
    for (int mi = 0; mi < 4; ++mi) {
        short8v av0 = *(const short8v*)
            &Us[(wM * 64 + mi * 16 + (l & 15)) * UKP + (l >> 4) * 8];
        short8v av1 = *(const short8v*)
            &Us[(wM * 64 + mi * 16 + (l & 15)) * UKP + 32 + (l >> 4) * 8];
        #pragma unroll
        for (int ni = 0; ni < 4; ++ni) {
            acc[mi][ni] = __builtin_amdgcn_mfma_f32_16x16x32_bf16(
                av0, bv[ni][0], acc[mi][ni], 0, 0, 0);
            acc[mi][ni] = __builtin_amdgcn_mfma_f32_16x16x32_bf16(
                av1, bv[ni][1], acc[mi][ni], 0, 0, 0);
        }
    }

    #pragma unroll
    for (int mi = 0; mi < 4; ++mi) {
        const int rowbase = wM * 64 + mi * 16 + (l >> 4) * 4;
        const int bi = (wM * 64 + mi * 16) >> 5;
        float s0 = 0.f, s1 = 0.f, s2 = 0.f, s3 = 0.f;
        #pragma unroll
        for (int ni = 0; ni < 4; ++ni) {
            const int col = wN * 64 + ni * 16 + (l & 15);
            const float b1v = b1_lds[col];
            const float mv  = m_lds[bi][col];
            s0 = fmaf(fmaxf(acc[mi][ni][0] + b1v, 0.f), mv, s0);
            s1 = fmaf(fmaxf(acc[mi][ni][1] + b1v, 0.f), mv, s1);
            s2 = fmaf(fmaxf(acc[mi][ni][2] + b1v, 0.f), mv, s2);
            s3 = fmaf(fmaxf(acc[mi][ni][3] + b1v, 0.f), mv, s3);
        }
        #pragma unroll
        for (int off = 8; off >= 1; off >>= 1) {
            s0 += __shfl_xor(s0, off);
            s1 += __shfl_xor(s1, off);
            s2 += __shfl_xor(s2, off);
            s3 += __shfl_xor(s3, off);
        }
        if ((l & 15) == 0) {
            red[rowbase + 0][wN] = s0;
            red[rowbase + 1][wN] = s1;
            red[rowbase + 2][wN] = s2;
            red[rowbase + 3][wN] = s3;
        }
    }
    __syncthreads();
    if (tid < 128) {
        const float sum = red[tid][0] + red[tid][1];
        const int b = b0 + (tid >> 5), a = tid & 31;
        logits[((size_t)b * NH + h) * NA + a] = sum;
    }
}

// ---------------------------------------------------------------------------
// K4: wh/v second layers + masked softmax + head_q + final mix.
// wh[b,h] = |sum_e h1bf[b,2048+e]*wh_W2[h,e] + wh_b2[h]|
// v[b]    =  sum_e h1bf[b,2304+e]*v_W2[e] + v_b2
// ---------------------------------------------------------------------------
__global__ __launch_bounds__(256) void k_softmax(
    const float* __restrict__ logits, const float* __restrict__ agent_qs,
    const int* __restrict__ actions, const ushort* __restrict__ h1bf,
    const float* __restrict__ wh_W2, const float* __restrict__ wh_b2,
    const float* __restrict__ v_W2, const float* __restrict__ v_b2,
    float* __restrict__ out, float* __restrict__ part)
{
    __shared__ float qs[NA];
    __shared__ int   act_s[NA];
    __shared__ float whs[NH];
    __shared__ float hq[NH];
    __shared__ float vred[4];
    const int b = blockIdx.x, t = threadIdx.x;
    if (t < NA) {
        qs[t]    = agent_qs[(size_t)b * NA + t];
        act_s[t] = actions[(size_t)b * NA + t];
    }
    const int h = t >> 5, a = t & 31;
    {   // wh: 8 groups of 32 lanes, each group one head
        float acc = 0.f;
        #pragma unroll
        for (int j = 0; j < 8; ++j) {
            const int e = a + 32 * j;
            acc = fmaf(bf2f(h1bf[(size_t)b * NTOT + NSEL + e]),
                       wh_W2[h * HYP + e], acc);
        }
        #pragma unroll
        for (int off = 16; off >= 1; off >>= 1) acc += __shfl_xor(acc, off, 32);
        if (a == 0) whs[h] = fabsf(acc + wh_b2[h]);
    }
    {   // v: one elem per thread, 64-wide wave reduce + LDS combine
        float acc = bf2f(h1bf[(size_t)b * NTOT + NSEL + HYP + t]) * v_W2[t];
        #pragma unroll
        for (int off = 32; off >= 1; off >>= 1) acc += __shfl_xor(acc, off);
        if ((t & 63) == 0) vred[t >> 6] = acc;
    }
    __syncthreads();

    const float lg = logits[((size_t)b * NH + h) * NA + a];
    float sc = (act_s[a] == 0) ? -99999999.0f : lg * 0.125f;

    float mx = sc;
    #pragma unroll
    for (int off = 16; off >= 1; off >>= 1) mx = fmaxf(mx, __shfl_xor(mx, off, 32));
    const float e = expf(sc - mx);
    float sum = e;
    #pragma unroll
    for (int off = 16; off >= 1; off >>= 1) sum += __shfl_xor(sum, off, 32);
    const float wgt = e / sum;

    float r_sq  = lg * lg;
    float r_hq  = qs[a] * wgt;
    float r_ent = -wgt * logf(wgt + 1e-8f);
    #pragma unroll
    for (int off = 16; off >= 1; off >>= 1) {
        r_sq  += __shfl_xor(r_sq,  off, 32);
        r_hq  += __shfl_xor(r_hq,  off, 32);
        r_ent += __shfl_xor(r_ent, off, 32);
    }
    if (a == 0) {
        hq[h] = r_hq;
        part[(size_t)b * 16 + h]     = r_sq;
        part[(size_t)b * 16 + 8 + h] = r_ent;
    }
    __syncthreads();
    if (t == 0) {
        float y = vred[0] + vred[1] + vred[2] + vred[3] + v_b2[0];
        #pragma unroll
        for (int i = 0; i < NH; ++i) y = fmaf(whs[i], hq[i], y);
        out[b] = y;
    }
}

// ---------------------------------------------------------------------------
// K5: reduce [B_TOT][16] partials.
// ---------------------------------------------------------------------------
__global__ __launch_bounds__(256) void k_final(
    const float* __restrict__ part, float* __restrict__ out)
{
    __shared__ float red[17][17];
    const int t = threadIdx.x;
    const int c = t & 15, r = t >> 4;
    float val = 0.f;
    for (int b = r; b < B_TOT; b += 16)
        val += part[(size_t)b * 16 + c];
    red[r][c] = val;
    __syncthreads();
    if (t < 16) {
        float s = 0.f;
        #pragma unroll
        for (int i = 0; i < 16; ++i) s += red[i][t];
        red[16][t] = s;
    }
    __syncthreads();
    if (t == 0) {
        float s = 0.f;
        #pragma unroll
        for (int i = 0; i < 8; ++i) s += red[16][i];
        out[B_TOT] = 0.001f * (s / (float)((size_t)B_TOT * NA));
    }
    if (t >= 8 && t < 16)
        out[B_TOT + 1 + (t - 8)] = red[16][t] / (float)B_TOT;
}

extern "C" void kernel_launch(void* const* d_in, const int* in_sizes, int n_in,
                              void* d_out, int out_size, void* d_ws, size_t ws_size,
                              hipStream_t stream) {
    (void)in_sizes; (void)n_in; (void)out_size; (void)ws_size;
    const float* agent_qs = (const float*)d_in[0];
    const float* states   = (const float*)d_in[1];
    const int*   actions  = (const int*)d_in[2];
    const float* sel_W1   = (const float*)d_in[3];
    const float* sel_b1   = (const float*)d_in[4];
    const float* sel_W2   = (const float*)d_in[5];
    const float* key_W1   = (const float*)d_in[6];
    const float* key_b1   = (const float*)d_in[7];
    const float* key_W2   = (const float*)d_in[8];
    const float* wh_W1    = (const float*)d_in[9];
    const float* wh_b1    = (const float*)d_in[10];
    const float* wh_W2    = (const float*)d_in[11];
    const float* wh_b2    = (const float*)d_in[12];
    const float* v_W1     = (const float*)d_in[13];
    const float* v_b1     = (const float*)d_in[14];
    const float* v_W2     = (const float*)d_in[15];
    const float* v_b2     = (const float*)d_in[16];

    float* out = (float*)d_out;
    float* ws  = (float*)d_ws;
    ushort* h1bf  = (ushort*)(ws + WS_H1BF);
    float* m_buf  = ws + WS_M;
    float* lg_buf = ws + WS_LG;
    float* part   = ws + WS_PART;
    ushort* Abf   = (ushort*)(ws + WS_ABF);
    ushort* Wbf   = (ushort*)(ws + WS_WBF);
    ushort* KW1bf = (ushort*)(ws + WS_KW1);
    ushort* M2T   = (ushort*)(ws + WS_M2T);
    ushort* Ubf   = (ushort*)(ws + WS_UBF);

    {
        const int groups_a = B_TOT * (KPAD / 4);
        const int groups_w = NTOT * (KPAD / 4);
        k_cvt_states<<<(groups_a + 255) / 256, 256, 0, stream>>>(states, Abf);
        k_cvt_w<<<(groups_w + 255) / 256, 256, 0, stream>>>(sel_W1, wh_W1, v_W1, Wbf);
        k_cvt_kw1<<<32, 256, 0, stream>>>(key_W1, KW1bf);
        k_cvt_units<<<(B_TOT * NA * (UKP / 8) + 255) / 256, 256, 0, stream>>>(
            states, agent_qs, Ubf);
        k_m2<<<dim3(NH, KHID / 8), 256, 0, stream>>>(sel_W2, key_W2, M2T);
    }
    k_gemm1_mfma<<<dim3(NTOT / 128, B_TOT / 128), 256, 0, stream>>>(
        Abf, Wbf, sel_b1, wh_b1, v_b1, h1bf);
    k_m_mfma<<<dim3(NH, B_TOT / 128), 256, 0, stream>>>(h1bf, M2T, m_buf);
    k_logits_mfma<<<dim3(NH, (B_TOT * NA) / 128), 256, 0, stream>>>(
        Ubf, KW1bf, key_b1, m_buf, lg_buf);
    k_softmax<<<dim3(B_TOT), 256, 0, stream>>>(
        lg_buf, agent_qs, actions, h1bf, wh_W2, wh_b2, v_W2, v_b2, out, part);
    k_final<<<1, 256, 0, stream>>>(part, out);
}

// Round 6
// 140.286 us; speedup vs baseline: 7.5878x; 1.4098x over previous
//
#include <hip/hip_runtime.h>

#define B_TOT 4096
#define SDIM  1200
#define KPAD  1216   // SDIM padded to multiple of 64 for MFMA K-loop
#define NA    32
#define NH    8
#define EMB   64
#define KHID  128
#define HYP   256
#define NSEL  2048   // NH*HYP
#define NTOT  2560   // NSEL + 256 (wh hid) + 256 (v hid)
#define UKP   64     // units K (33) padded to 64

// workspace layout (float offsets)
#define WS_H1BF 0                                              // bf16 h1 [B_TOT][NTOT]
#define WS_M    (WS_H1BF + (size_t)B_TOT * NTOT / 2)           // fp32 m [B_TOT][NH][KHID]
#define WS_LG   (WS_M    + (size_t)B_TOT * NH * KHID)
#define WS_PART (WS_LG   + (size_t)B_TOT * NH * NA)
#define WS_P2   (WS_PART + (size_t)B_TOT * 16)                 // stage-2 partials [32][16]
#define WS_ABF  (WS_P2   + (size_t)32 * 16)                    // bf16 states [B_TOT][KPAD]
#define WS_WBF  (WS_ABF  + (size_t)B_TOT * KPAD / 2)           // bf16 W1 [NTOT][KPAD]
#define WS_KW1  (WS_WBF  + (size_t)NTOT * KPAD / 2)            // bf16 key_W1 [1024][UKP]
#define WS_M2T  (WS_KW1  + (size_t)1024 * UKP / 2)             // bf16 M2T [NH][KHID][HYP]
#define WS_UBF  (WS_M2T  + (size_t)NH * KHID * HYP / 2)        // bf16 units [B_TOT*NA][UKP]

typedef __attribute__((ext_vector_type(8))) short short8v;
typedef __attribute__((ext_vector_type(4))) float floatx4;

__device__ __forceinline__ ushort f2bf(float x) {
    unsigned u = __builtin_bit_cast(unsigned, x);
    unsigned r = (u + 0x7FFFu + ((u >> 16) & 1u)) >> 16;
    return (ushort)r;
}
__device__ __forceinline__ float bf2f(ushort u) {
    unsigned x = ((unsigned)u) << 16;
    return __builtin_bit_cast(float, x);
}

// ---------------------------------------------------------------------------
// fp32 -> bf16 conversions
// ---------------------------------------------------------------------------
__global__ __launch_bounds__(256) void k_cvt_states(
    const float* __restrict__ src, ushort* __restrict__ dst)
{
    const size_t g = (size_t)blockIdx.x * 256 + threadIdx.x;
    if (g >= (size_t)B_TOT * (KPAD / 4)) return;
    const int row = (int)(g / (KPAD / 4));
    const int c4  = (int)(g % (KPAD / 4)) * 4;
    ushort4 o = {0, 0, 0, 0};
    if (c4 < SDIM) {
        float4 v = *(const float4*)(src + (size_t)row * SDIM + c4);
        o.x = f2bf(v.x); o.y = f2bf(v.y); o.z = f2bf(v.z); o.w = f2bf(v.w);
    }
    *(ushort4*)(dst + (size_t)row * KPAD + c4) = o;
}

__global__ __launch_bounds__(256) void k_cvt_w(
    const float* __restrict__ sel_W1, const float* __restrict__ wh_W1,
    const float* __restrict__ v_W1, ushort* __restrict__ dst)
{
    const size_t g = (size_t)blockIdx.x * 256 + threadIdx.x;
    if (g >= (size_t)NTOT * (KPAD / 4)) return;
    const int row = (int)(g / (KPAD / 4));
    const int c4  = (int)(g % (KPAD / 4)) * 4;
    const float* src = (row < NSEL)       ? (sel_W1 + (size_t)row * SDIM)
                     : (row < NSEL + HYP) ? (wh_W1 + (size_t)(row - NSEL) * SDIM)
                                          : (v_W1  + (size_t)(row - NSEL - HYP) * SDIM);
    ushort4 o = {0, 0, 0, 0};
    if (c4 < SDIM) {
        float4 v = *(const float4*)(src + c4);
        o.x = f2bf(v.x); o.y = f2bf(v.y); o.z = f2bf(v.z); o.w = f2bf(v.w);
    }
    *(ushort4*)(dst + (size_t)row * KPAD + c4) = o;
}

// units[b][a][u] = states[b][a*32+u] (u<32), q (u=32), 0 pad to 64. Row = b*32+a.
__global__ __launch_bounds__(256) void k_cvt_units(
    const float* __restrict__ states, const float* __restrict__ agent_qs,
    ushort* __restrict__ dst)
{
    const size_t g = (size_t)blockIdx.x * 256 + threadIdx.x;   // one short8 each
    if (g >= (size_t)B_TOT * NA * (UKP / 8)) return;
    const int row = (int)(g >> 3);
    const int seg = ((int)g & 7) * 8;
    const int b = row >> 5, a = row & 31;
    ushort o[8] = {0, 0, 0, 0, 0, 0, 0, 0};
    if (seg < 32) {
        const float* s = states + (size_t)b * SDIM + a * 32 + seg;
        float4 v0 = *(const float4*)(s);
        float4 v1 = *(const float4*)(s + 4);
        o[0] = f2bf(v0.x); o[1] = f2bf(v0.y); o[2] = f2bf(v0.z); o[3] = f2bf(v0.w);
        o[4] = f2bf(v1.x); o[5] = f2bf(v1.y); o[6] = f2bf(v1.z); o[7] = f2bf(v1.w);
    } else if (seg == 32) {
        o[0] = f2bf(agent_qs[(size_t)b * NA + a]);
    }
    *(ushort4*)(dst + (size_t)row * UKP + seg)     = *(ushort4*)&o[0];
    *(ushort4*)(dst + (size_t)row * UKP + seg + 4) = *(ushort4*)&o[4];
}

// key_W1 [8][128][33] -> bf16 [1024][UKP], zero-padded
__global__ __launch_bounds__(256) void k_cvt_kw1(
    const float* __restrict__ key_W1, ushort* __restrict__ dst)
{
    const int g = blockIdx.x * 256 + threadIdx.x;   // one short8 each
    if (g >= 1024 * (UKP / 8)) return;
    const int row = g >> 3;
    const int seg = (g & 7) * 8;
    ushort o[8] = {0, 0, 0, 0, 0, 0, 0, 0};
    #pragma unroll
    for (int j = 0; j < 8; ++j) {
        const int u = seg + j;
        if (u < 33) o[j] = f2bf(key_W1[(size_t)row * 33 + u]);
    }
    *(ushort4*)(dst + (size_t)row * UKP + seg)     = *(ushort4*)&o[0];
    *(ushort4*)(dst + (size_t)row * UKP + seg + 4) = *(ushort4*)&o[4];
}

// ---------------------------------------------------------------------------
// M2T[h][k][e] = sum_d sel_W2[h][d][e] * key_W2[h][d][k]  (bf16 out)
// ---------------------------------------------------------------------------
__global__ __launch_bounds__(256) void k_m2(
    const float* __restrict__ sel_W2, const float* __restrict__ key_W2,
    ushort* __restrict__ M2T)
{
    __shared__ float ssel[EMB * HYP];   // [d][e], 64 KB
    __shared__ float skey[EMB][8];
    const int t  = threadIdx.x;
    const int h  = blockIdx.x;
    const int k0 = blockIdx.y * 8;

    const float4* sw = (const float4*)(sel_W2 + (size_t)h * EMB * HYP);
    #pragma unroll
    for (int j = 0; j < 16; ++j)
        ((float4*)ssel)[j * 256 + t] = sw[j * 256 + t];
    if (t < EMB) {
        #pragma unroll
        for (int kk = 0; kk < 8; ++kk)
            skey[t][kk] = key_W2[((size_t)h * EMB + t) * KHID + k0 + kk];
    }
    __syncthreads();

    const int e = t;
    float acc[8] = {};
    for (int d = 0; d < EMB; ++d) {
        const float sv = ssel[d * HYP + e];
        #pragma unroll
        for (int kk = 0; kk < 8; ++kk)
            acc[kk] = fmaf(sv, skey[d][kk], acc[kk]);
    }
    #pragma unroll
    for (int kk = 0; kk < 8; ++kk)
        M2T[((size_t)h * KHID + k0 + kk) * HYP + e] = f2bf(acc[kk]);
}

// ---------------------------------------------------------------------------
// K1: bf16 MFMA GEMM. M=4096 N=2560 K=1216. 128x128 tile, 4 waves, BK=32.
// ---------------------------------------------------------------------------
#define BK 32
__global__ __launch_bounds__(256) void k_gemm1_mfma(
    const ushort* __restrict__ Abf, const ushort* __restrict__ Wbf,
    const float* __restrict__ sel_b1, const float* __restrict__ wh_b1,
    const float* __restrict__ v_b1, ushort* __restrict__ h1bf)
{
    __shared__ ushort As[128 * BK];
    __shared__ ushort Bs[128 * BK];
    const int tid = threadIdx.x;
    const int l   = tid & 63;
    const int w   = tid >> 6;
    const int wM  = w >> 1, wN = w & 1;
    const int arow0 = blockIdx.y * 128;
    const int nrow0 = blockIdx.x * 128;

    const int srow = tid >> 2;
    const int skof = (tid & 3) * 8;
    const ushort* gA = Abf + (size_t)(arow0 + srow) * KPAD + skof;
    const ushort* gB = Wbf + (size_t)(nrow0 + srow) * KPAD + skof;
    ushort* lA = &As[srow * BK + skof];
    ushort* lB = &Bs[srow * BK + skof];

    floatx4 acc[4][4] = {};

    for (int k0 = 0; k0 < KPAD; k0 += BK) {
        __builtin_amdgcn_global_load_lds(
            (const __attribute__((address_space(1))) unsigned int*)(gA + k0),
            (__attribute__((address_space(3))) unsigned int*)lA, 16, 0, 0);
        __builtin_amdgcn_global_load_lds(
            (const __attribute__((address_space(1))) unsigned int*)(gA + (size_t)64 * KPAD + k0),
            (__attribute__((address_space(3))) unsigned int*)(lA + 64 * BK), 16, 0, 0);
        __builtin_amdgcn_global_load_lds(
            (const __attribute__((address_space(1))) unsigned int*)(gB + k0),
            (__attribute__((address_space(3))) unsigned int*)lB, 16, 0, 0);
        __builtin_amdgcn_global_load_lds(
            (const __attribute__((address_space(1))) unsigned int*)(gB + (size_t)64 * KPAD + k0),
            (__attribute__((address_space(3))) unsigned int*)(lB + 64 * BK), 16, 0, 0);
        __syncthreads();

        const int kch = (l >> 4) * 8;
        short8v av[4], bv[4];
        #pragma unroll
        for (int mi = 0; mi < 4; ++mi)
            av[mi] = *(const short8v*)&As[(wM * 64 + mi * 16 + (l & 15)) * BK + kch];
        #pragma unroll
        for (int ni = 0; ni < 4; ++ni)
            bv[ni] = *(const short8v*)&Bs[(wN * 64 + ni * 16 + (l & 15)) * BK + kch];
        #pragma unroll
        for (int mi = 0; mi < 4; ++mi)
            #pragma unroll
            for (int ni = 0; ni < 4; ++ni)
                acc[mi][ni] = __builtin_amdgcn_mfma_f32_16x16x32_bf16(
                    av[mi], bv[ni], acc[mi][ni], 0, 0, 0);
        __syncthreads();
    }

    float bias_n[4];
    #pragma unroll
    for (int ni = 0; ni < 4; ++ni) {
        const int col = nrow0 + wN * 64 + ni * 16 + (l & 15);
        bias_n[ni] = (col < NSEL)       ? sel_b1[col]
                   : (col < NSEL + HYP) ? wh_b1[col - NSEL]
                                        : v_b1[col - NSEL - HYP];
    }
    #pragma unroll
    for (int mi = 0; mi < 4; ++mi) {
        const int row = arow0 + wM * 64 + mi * 16 + (l >> 4) * 4;
        #pragma unroll
        for (int ni = 0; ni < 4; ++ni) {
            const int col = nrow0 + wN * 64 + ni * 16 + (l & 15);
            #pragma unroll
            for (int r = 0; r < 4; ++r)
                h1bf[(size_t)(row + r) * NTOT + col] =
                    f2bf(fmaxf(acc[mi][ni][r] + bias_n[ni], 0.f));
        }
    }
}

// ---------------------------------------------------------------------------
// K2: per-head m GEMM. m[b,h,k] = sum_e h1bf[b, h*256+e] * M2T[h][k][e].
// ---------------------------------------------------------------------------
__global__ __launch_bounds__(256) void k_m_mfma(
    const ushort* __restrict__ h1bf, const ushort* __restrict__ M2T,
    float* __restrict__ m_out)
{
    __shared__ ushort As[128 * BK];
    __shared__ ushort Bs[128 * BK];
    const int tid = threadIdx.x;
    const int l   = tid & 63;
    const int w   = tid >> 6;
    const int wM  = w >> 1, wN = w & 1;
    const int h     = blockIdx.x;
    const int brow0 = blockIdx.y * 128;

    const int srow = tid >> 2;
    const int skof = (tid & 3) * 8;
    const ushort* gA = h1bf + (size_t)(brow0 + srow) * NTOT + h * HYP + skof;
    const ushort* gB = M2T + ((size_t)h * KHID + srow) * HYP + skof;
    ushort* lA = &As[srow * BK + skof];
    ushort* lB = &Bs[srow * BK + skof];

    floatx4 acc[4][4] = {};

    for (int k0 = 0; k0 < HYP; k0 += BK) {
        __builtin_amdgcn_global_load_lds(
            (const __attribute__((address_space(1))) unsigned int*)(gA + k0),
            (__attribute__((address_space(3))) unsigned int*)lA, 16, 0, 0);
        __builtin_amdgcn_global_load_lds(
            (const __attribute__((address_space(1))) unsigned int*)(gA + (size_t)64 * NTOT + k0),
            (__attribute__((address_space(3))) unsigned int*)(lA + 64 * BK), 16, 0, 0);
        __builtin_amdgcn_global_load_lds(
            (const __attribute__((address_space(1))) unsigned int*)(gB + k0),
            (__attribute__((address_space(3))) unsigned int*)lB, 16, 0, 0);
        __builtin_amdgcn_global_load_lds(
            (const __attribute__((address_space(1))) unsigned int*)(gB + (size_t)64 * HYP + k0),
            (__attribute__((address_space(3))) unsigned int*)(lB + 64 * BK), 16, 0, 0);
        __syncthreads();

        const int kch = (l >> 4) * 8;
        short8v av[4], bv[4];
        #pragma unroll
        for (int mi = 0; mi < 4; ++mi)
            av[mi] = *(const short8v*)&As[(wM * 64 + mi * 16 + (l & 15)) * BK + kch];
        #pragma unroll
        for (int ni = 0; ni < 4; ++ni)
            bv[ni] = *(const short8v*)&Bs[(wN * 64 + ni * 16 + (l & 15)) * BK + kch];
        #pragma unroll
        for (int mi = 0; mi < 4; ++mi)
            #pragma unroll
            for (int ni = 0; ni < 4; ++ni)
                acc[mi][ni] = __builtin_amdgcn_mfma_f32_16x16x32_bf16(
                    av[mi], bv[ni], acc[mi][ni], 0, 0, 0);
        __syncthreads();
    }

    #pragma unroll
    for (int mi = 0; mi < 4; ++mi) {
        const int row = brow0 + wM * 64 + mi * 16 + (l >> 4) * 4;
        #pragma unroll
        for (int ni = 0; ni < 4; ++ni) {
            const int col = wN * 64 + ni * 16 + (l & 15);
            #pragma unroll
            for (int r = 0; r < 4; ++r)
                m_out[((size_t)(row + r) * NH + h) * KHID + col] = acc[mi][ni][r];
        }
    }
}

// ---------------------------------------------------------------------------
// K3: MFMA logits. Grid (h, row-tile). Tile: 128 U-rows x 128 k-cols, K=64.
// ---------------------------------------------------------------------------
__global__ __launch_bounds__(256) void k_logits_mfma(
    const ushort* __restrict__ Ubf, const ushort* __restrict__ KW1bf,
    const float* __restrict__ key_b1, const float* __restrict__ m_in,
    float* __restrict__ logits)
{
    __shared__ ushort Us[128 * UKP];
    __shared__ ushort Ws[128 * UKP];
    __shared__ float m_lds[4][KHID];
    __shared__ float b1_lds[KHID];
    __shared__ float red[128][2];
    const int tid = threadIdx.x;
    const int l = tid & 63;
    const int w = tid >> 6;
    const int wM = w >> 1, wN = w & 1;
    const int h  = blockIdx.x;
    const int r0 = blockIdx.y * 128;   // U row base
    const int b0 = blockIdx.y * 4;     // batch base

    const int srow = tid >> 3;
    const int sel8 = (tid & 7) * 8;
    #pragma unroll
    for (int c = 0; c < 4; ++c)
        __builtin_amdgcn_global_load_lds(
            (const __attribute__((address_space(1))) unsigned int*)
                (Ubf + (size_t)(r0 + srow + c * 32) * UKP + sel8),
            (__attribute__((address_space(3))) unsigned int*)
                (&Us[0] + (size_t)tid * 8 + c * 2048), 16, 0, 0);
    #pragma unroll
    for (int c = 0; c < 4; ++c)
        __builtin_amdgcn_global_load_lds(
            (const __attribute__((address_space(1))) unsigned int*)
                (KW1bf + (size_t)(h * 128 + srow + c * 32) * UKP + sel8),
            (__attribute__((address_space(3))) unsigned int*)
                (&Ws[0] + (size_t)tid * 8 + c * 2048), 16, 0, 0);
    #pragma unroll
    for (int j = 0; j < 2; ++j) {
        const int idx = tid + j * 256;
        m_lds[idx >> 7][idx & 127] =
            m_in[((size_t)(b0 + (idx >> 7)) * NH + h) * KHID + (idx & 127)];
    }
    if (tid < 128) b1_lds[tid] = key_b1[h * KHID + tid];
    __syncthreads();

    floatx4 acc[4][4] = {};
    short8v bv[4][2];
    #pragma unroll
    for (int ni = 0; ni < 4; ++ni)
        #pragma unroll
        for (int kc = 0; kc < 2; ++kc)
            bv[ni][kc] = *(const short8v*)
                &Ws[(wN * 64 + ni * 16 + (l & 15)) * UKP + kc * 32 + (l >> 4) * 8];
    #pragma unroll
    for (int mi = 0; mi < 4; ++mi) {
        short8v av0 = *(const short8v*)
            &Us[(wM * 64 + mi * 16 + (l & 15)) * UKP + (l >> 4) * 8];
        short8v av1 = *(const short8v*)
            &Us[(wM * 64 + mi * 16 + (l & 15)) * UKP + 32 + (l >> 4) * 8];
        #pragma unroll
        for (int ni = 0; ni < 4; ++ni) {
            acc[mi][ni] = __builtin_amdgcn_mfma_f32_16x16x32_bf16(
                av0, bv[ni][0], acc[mi][ni], 0, 0, 0);
            acc[mi][ni] = __builtin_amdgcn_mfma_f32_16x16x32_bf16(
                av1, bv[ni][1], acc[mi][ni], 0, 0, 0);
        }
    }

    #pragma unroll
    for (int mi = 0; mi < 4; ++mi) {
        const int rowbase = wM * 64 + mi * 16 + (l >> 4) * 4;
        const int bi = (wM * 64 + mi * 16) >> 5;
        float s0 = 0.f, s1 = 0.f, s2 = 0.f, s3 = 0.f;
        #pragma unroll
        for (int ni = 0; ni < 4; ++ni) {
            const int col = wN * 64 + ni * 16 + (l & 15);
            const float b1v = b1_lds[col];
            const float mv  = m_lds[bi][col];
            s0 = fmaf(fmaxf(acc[mi][ni][0] + b1v, 0.f), mv, s0);
            s1 = fmaf(fmaxf(acc[mi][ni][1] + b1v, 0.f), mv, s1);
            s2 = fmaf(fmaxf(acc[mi][ni][2] + b1v, 0.f), mv, s2);
            s3 = fmaf(fmaxf(acc[mi][ni][3] + b1v, 0.f), mv, s3);
        }
        #pragma unroll
        for (int off = 8; off >= 1; off >>= 1) {
            s0 += __shfl_xor(s0, off);
            s1 += __shfl_xor(s1, off);
            s2 += __shfl_xor(s2, off);
            s3 += __shfl_xor(s3, off);
        }
        if ((l & 15) == 0) {
            red[rowbase + 0][wN] = s0;
            red[rowbase + 1][wN] = s1;
            red[rowbase + 2][wN] = s2;
            red[rowbase + 3][wN] = s3;
        }
    }
    __syncthreads();
    if (tid < 128) {
        const float sum = red[tid][0] + red[tid][1];
        const int b = b0 + (tid >> 5), a = tid & 31;
        logits[((size_t)b * NH + h) * NA + a] = sum;
    }
}

// ---------------------------------------------------------------------------
// K4: wh/v second layers + masked softmax + head_q + final mix.
// ---------------------------------------------------------------------------
__global__ __launch_bounds__(256) void k_softmax(
    const float* __restrict__ logits, const float* __restrict__ agent_qs,
    const int* __restrict__ actions, const ushort* __restrict__ h1bf,
    const float* __restrict__ wh_W2, const float* __restrict__ wh_b2,
    const float* __restrict__ v_W2, const float* __restrict__ v_b2,
    float* __restrict__ out, float* __restrict__ part)
{
    __shared__ float qs[NA];
    __shared__ int   act_s[NA];
    __shared__ float whs[NH];
    __shared__ float hq[NH];
    __shared__ float vred[4];
    const int b = blockIdx.x, t = threadIdx.x;
    if (t < NA) {
        qs[t]    = agent_qs[(size_t)b * NA + t];
        act_s[t] = actions[(size_t)b * NA + t];
    }
    const int h = t >> 5, a = t & 31;
    {   // wh: 8 groups of 32 lanes, each group one head
        float acc = 0.f;
        #pragma unroll
        for (int j = 0; j < 8; ++j) {
            const int e = a + 32 * j;
            acc = fmaf(bf2f(h1bf[(size_t)b * NTOT + NSEL + e]),
                       wh_W2[h * HYP + e], acc);
        }
        #pragma unroll
        for (int off = 16; off >= 1; off >>= 1) acc += __shfl_xor(acc, off, 32);
        if (a == 0) whs[h] = fabsf(acc + wh_b2[h]);
    }
    {   // v: one elem per thread, 64-wide wave reduce + LDS combine
        float acc = bf2f(h1bf[(size_t)b * NTOT + NSEL + HYP + t]) * v_W2[t];
        #pragma unroll
        for (int off = 32; off >= 1; off >>= 1) acc += __shfl_xor(acc, off);
        if ((t & 63) == 0) vred[t >> 6] = acc;
    }
    __syncthreads();

    const float lg = logits[((size_t)b * NH + h) * NA + a];
    float sc = (act_s[a] == 0) ? -99999999.0f : lg * 0.125f;

    float mx = sc;
    #pragma unroll
    for (int off = 16; off >= 1; off >>= 1) mx = fmaxf(mx, __shfl_xor(mx, off, 32));
    const float e = expf(sc - mx);
    float sum = e;
    #pragma unroll
    for (int off = 16; off >= 1; off >>= 1) sum += __shfl_xor(sum, off, 32);
    const float wgt = e / sum;

    float r_sq  = lg * lg;
    float r_hq  = qs[a] * wgt;
    float r_ent = -wgt * logf(wgt + 1e-8f);
    #pragma unroll
    for (int off = 16; off >= 1; off >>= 1) {
        r_sq  += __shfl_xor(r_sq,  off, 32);
        r_hq  += __shfl_xor(r_hq,  off, 32);
        r_ent += __shfl_xor(r_ent, off, 32);
    }
    if (a == 0) {
        hq[h] = r_hq;
        part[(size_t)b * 16 + h]     = r_sq;
        part[(size_t)b * 16 + 8 + h] = r_ent;
    }
    __syncthreads();
    if (t == 0) {
        float y = vred[0] + vred[1] + vred[2] + vred[3] + v_b2[0];
        #pragma unroll
        for (int i = 0; i < NH; ++i) y = fmaf(whs[i], hq[i], y);
        out[b] = y;
    }
}

// ---------------------------------------------------------------------------
// K5a: stage-1 reduce. 32 blocks; block bx reduces part rows
// [bx*128, bx*128+128) -> part2[bx*16 + c]. Each thread: 8 independent loads.
// ---------------------------------------------------------------------------
__global__ __launch_bounds__(256) void k_final_s1(
    const float* __restrict__ part, float* __restrict__ part2)
{
    __shared__ float red[16][17];
    const int t = threadIdx.x;
    const int c = t & 15, rl = t >> 4;
    const int rbase = blockIdx.x * 128 + rl;
    float v0 = 0.f, v1 = 0.f, v2 = 0.f, v3 = 0.f;
    #pragma unroll
    for (int j = 0; j < 8; j += 4) {
        v0 += part[(size_t)(rbase + (j + 0) * 16) * 16 + c];
        v1 += part[(size_t)(rbase + (j + 1) * 16) * 16 + c];
        v2 += part[(size_t)(rbase + (j + 2) * 16) * 16 + c];
        v3 += part[(size_t)(rbase + (j + 3) * 16) * 16 + c];
    }
    red[rl][c] = (v0 + v1) + (v2 + v3);
    __syncthreads();
    if (t < 16) {
        float s = 0.f;
        #pragma unroll
        for (int i = 0; i < 16; ++i) s += red[i][t];
        part2[blockIdx.x * 16 + t] = s;
    }
}

// ---------------------------------------------------------------------------
// K5b: stage-2 reduce [32][16] -> outputs.
// ---------------------------------------------------------------------------
__global__ __launch_bounds__(256) void k_final_s2(
    const float* __restrict__ part2, float* __restrict__ out)
{
    __shared__ float red[16][17];
    __shared__ float tot[16];
    const int t = threadIdx.x;
    if (t < 256) {
        const int g = t >> 4, c = t & 15;
        const float val = part2[t] + part2[t + 256];
        red[g][c] = val;
    }
    __syncthreads();
    if (t < 16) {
        float s = 0.f;
        #pragma unroll
        for (int i = 0; i < 16; ++i) s += red[i][t];
        tot[t] = s;
    }
    __syncthreads();
    if (t == 0) {
        float s = 0.f;
        #pragma unroll
        for (int i = 0; i < 8; ++i) s += tot[i];
        out[B_TOT] = 0.001f * (s / (float)((size_t)B_TOT * NA));
    }
    if (t >= 8 && t < 16)
        out[B_TOT + 1 + (t - 8)] = tot[t] / (float)B_TOT;
}

extern "C" void kernel_launch(void* const* d_in, const int* in_sizes, int n_in,
                              void* d_out, int out_size, void* d_ws, size_t ws_size,
                              hipStream_t stream) {
    (void)in_sizes; (void)n_in; (void)out_size; (void)ws_size;
    const float* agent_qs = (const float*)d_in[0];
    const float* states   = (const float*)d_in[1];
    const int*   actions  = (const int*)d_in[2];
    const float* sel_W1   = (const float*)d_in[3];
    const float* sel_b1   = (const float*)d_in[4];
    const float* sel_W2   = (const float*)d_in[5];
    const float* key_W1   = (const float*)d_in[6];
    const float* key_b1   = (const float*)d_in[7];
    const float* key_W2   = (const float*)d_in[8];
    const float* wh_W1    = (const float*)d_in[9];
    const float* wh_b1    = (const float*)d_in[10];
    const float* wh_W2    = (const float*)d_in[11];
    const float* wh_b2    = (const float*)d_in[12];
    const float* v_W1     = (const float*)d_in[13];
    const float* v_b1     = (const float*)d_in[14];
    const float* v_W2     = (const float*)d_in[15];
    const float* v_b2     = (const float*)d_in[16];

    float* out = (float*)d_out;
    float* ws  = (float*)d_ws;
    ushort* h1bf  = (ushort*)(ws + WS_H1BF);
    float* m_buf  = ws + WS_M;
    float* lg_buf = ws + WS_LG;
    float* part   = ws + WS_PART;
    float* part2  = ws + WS_P2;
    ushort* Abf   = (ushort*)(ws + WS_ABF);
    ushort* Wbf   = (ushort*)(ws + WS_WBF);
    ushort* KW1bf = (ushort*)(ws + WS_KW1);
    ushort* M2T   = (ushort*)(ws + WS_M2T);
    ushort* Ubf   = (ushort*)(ws + WS_UBF);

    {
        const int groups_a = B_TOT * (KPAD / 4);
        const int groups_w = NTOT * (KPAD / 4);
        k_cvt_states<<<(groups_a + 255) / 256, 256, 0, stream>>>(states, Abf);
        k_cvt_w<<<(groups_w + 255) / 256, 256, 0, stream>>>(sel_W1, wh_W1, v_W1, Wbf);
        k_cvt_kw1<<<32, 256, 0, stream>>>(key_W1, KW1bf);
        k_cvt_units<<<(B_TOT * NA * (UKP / 8) + 255) / 256, 256, 0, stream>>>(
            states, agent_qs, Ubf);
        k_m2<<<dim3(NH, KHID / 8), 256, 0, stream>>>(sel_W2, key_W2, M2T);
    }
    k_gemm1_mfma<<<dim3(NTOT / 128, B_TOT / 128), 256, 0, stream>>>(
        Abf, Wbf, sel_b1, wh_b1, v_b1, h1bf);
    k_m_mfma<<<dim3(NH, B_TOT / 128), 256, 0, stream>>>(h1bf, M2T, m_buf);
    k_logits_mfma<<<dim3(NH, (B_TOT * NA) / 128), 256, 0, stream>>>(
        Ubf, KW1bf, key_b1, m_buf, lg_buf);
    k_softmax<<<dim3(B_TOT), 256, 0, stream>>>(
        lg_buf, agent_qs, actions, h1bf, wh_W2, wh_b2, v_W2, v_b2, out, part);
    k_final_s1<<<32, 256, 0, stream>>>(part, part2);
    k_final_s2<<<1, 256, 0, stream>>>(part2, out);
}

// Round 7
// 130.590 us; speedup vs baseline: 8.1511x; 1.0742x over previous
//
#include <hip/hip_runtime.h>

#define B_TOT 4096
#define SDIM  1200
#define KPAD  1216   // SDIM padded to multiple of 64 for MFMA K-loop
#define NA    32
#define NH    8
#define EMB   64
#define KHID  128
#define HYP   256
#define NSEL  2048   // NH*HYP
#define NTOT  2560   // NSEL + 256 (wh hid) + 256 (v hid)

// workspace layout (float offsets)
#define WS_H1BF 0                                              // bf16 h1 [B_TOT][NTOT]
#define WS_M    (WS_H1BF + (size_t)B_TOT * NTOT / 2)           // fp32 m [B_TOT][NH][KHID]
#define WS_LG   (WS_M    + (size_t)B_TOT * NH * KHID)
#define WS_PART (WS_LG   + (size_t)B_TOT * NH * NA)
#define WS_P2   (WS_PART + (size_t)B_TOT * 16)
#define WS_ABF  (WS_P2   + (size_t)32 * 16)                    // bf16 states [B_TOT][KPAD]
#define WS_WBF  (WS_ABF  + (size_t)B_TOT * KPAD / 2)           // bf16 W1 [NTOT][KPAD]
#define WS_KW32 (WS_WBF  + (size_t)NTOT * KPAD / 2)            // bf16 key_W1[:, :32] swizzled [1024][32]
#define WS_W32F (WS_KW32 + (size_t)1024 * 32 / 2)              // fp32 key_W1[:, 32] [1024]
#define WS_M2T  (WS_W32F + (size_t)1024)                       // bf16 M2T [NH][KHID][HYP]
#define WS_UBF  (WS_M2T  + (size_t)NH * KHID * HYP / 2)        // bf16 units [B_TOT*NA][32] swizzled

typedef __attribute__((ext_vector_type(8))) short short8v;
typedef __attribute__((ext_vector_type(4))) float floatx4;

#define GLL16(gsrc, ldst) __builtin_amdgcn_global_load_lds( \
    (const __attribute__((address_space(1))) unsigned int*)(gsrc), \
    (__attribute__((address_space(3))) unsigned int*)(ldst), 16, 0, 0)

__device__ __forceinline__ ushort f2bf(float x) {
    unsigned u = __builtin_bit_cast(unsigned, x);
    unsigned r = (u + 0x7FFFu + ((u >> 16) & 1u)) >> 16;
    return (ushort)r;
}
__device__ __forceinline__ float bf2f(ushort u) {
    unsigned x = ((unsigned)u) << 16;
    return __builtin_bit_cast(float, x);
}

// ---------------------------------------------------------------------------
// fp32 -> bf16 conversions
// ---------------------------------------------------------------------------
__global__ __launch_bounds__(256) void k_cvt_states(
    const float* __restrict__ src, ushort* __restrict__ dst)
{
    const size_t g = (size_t)blockIdx.x * 256 + threadIdx.x;
    if (g >= (size_t)B_TOT * (KPAD / 4)) return;
    const int row = (int)(g / (KPAD / 4));
    const int c4  = (int)(g % (KPAD / 4)) * 4;
    ushort4 o = {0, 0, 0, 0};
    if (c4 < SDIM) {
        float4 v = *(const float4*)(src + (size_t)row * SDIM + c4);
        o.x = f2bf(v.x); o.y = f2bf(v.y); o.z = f2bf(v.z); o.w = f2bf(v.w);
    }
    *(ushort4*)(dst + (size_t)row * KPAD + c4) = o;
}

__global__ __launch_bounds__(256) void k_cvt_w(
    const float* __restrict__ sel_W1, const float* __restrict__ wh_W1,
    const float* __restrict__ v_W1, ushort* __restrict__ dst)
{
    const size_t g = (size_t)blockIdx.x * 256 + threadIdx.x;
    if (g >= (size_t)NTOT * (KPAD / 4)) return;
    const int row = (int)(g / (KPAD / 4));
    const int c4  = (int)(g % (KPAD / 4)) * 4;
    const float* src = (row < NSEL)       ? (sel_W1 + (size_t)row * SDIM)
                     : (row < NSEL + HYP) ? (wh_W1 + (size_t)(row - NSEL) * SDIM)
                                          : (v_W1  + (size_t)(row - NSEL - HYP) * SDIM);
    ushort4 o = {0, 0, 0, 0};
    if (c4 < SDIM) {
        float4 v = *(const float4*)(src + c4);
        o.x = f2bf(v.x); o.y = f2bf(v.y); o.z = f2bf(v.z); o.w = f2bf(v.w);
    }
    *(ushort4*)(dst + (size_t)row * KPAD + c4) = o;
}

// units[b][a][u] bf16 [131072][32], 16B-chunk-swizzled: chunk c of row r stored
// at chunk index c ^ ((r>>1)&3). One thread per row.
__global__ __launch_bounds__(256) void k_cvt_units(
    const float* __restrict__ states, ushort* __restrict__ dst)
{
    const int row = blockIdx.x * 256 + threadIdx.x;
    if (row >= B_TOT * NA) return;
    const int b = row >> 5, a = row & 31;
    const float* s = states + (size_t)b * SDIM + a * 32;
    ushort o[32];
    #pragma unroll
    for (int j = 0; j < 8; ++j) {
        float4 v = *(const float4*)(s + j * 4);
        o[j * 4 + 0] = f2bf(v.x); o[j * 4 + 1] = f2bf(v.y);
        o[j * 4 + 2] = f2bf(v.z); o[j * 4 + 3] = f2bf(v.w);
    }
    const int swz = (row >> 1) & 3;
    #pragma unroll
    for (int c = 0; c < 4; ++c)
        *(short8v*)(dst + (size_t)row * 32 + (c ^ swz) * 8) = *(short8v*)&o[c * 8];
}

// key_W1 [1024][33] -> KW32 bf16 [1024][32] (same chunk swizzle, row-in-tile =
// row&127 but bits 1-2 match) + W32f fp32 [1024] (the q column).
__global__ __launch_bounds__(256) void k_cvt_kw2(
    const float* __restrict__ key_W1, ushort* __restrict__ kw32,
    float* __restrict__ w32f)
{
    const int row = blockIdx.x * 256 + threadIdx.x;
    if (row >= 1024) return;
    const float* srcr = key_W1 + (size_t)row * 33;
    ushort o[32];
    #pragma unroll
    for (int u = 0; u < 32; ++u) o[u] = f2bf(srcr[u]);
    const int swz = (row >> 1) & 3;
    #pragma unroll
    for (int c = 0; c < 4; ++c)
        *(short8v*)(kw32 + (size_t)row * 32 + (c ^ swz) * 8) = *(short8v*)&o[c * 8];
    w32f[row] = srcr[32];
}

// ---------------------------------------------------------------------------
// M2T[h][k][e] = sum_d sel_W2[h][d][e] * key_W2[h][d][k]  (bf16 out)
// ---------------------------------------------------------------------------
__global__ __launch_bounds__(256) void k_m2(
    const float* __restrict__ sel_W2, const float* __restrict__ key_W2,
    ushort* __restrict__ M2T)
{
    __shared__ float ssel[EMB * HYP];
    __shared__ float skey[EMB][8];
    const int t  = threadIdx.x;
    const int h  = blockIdx.x;
    const int k0 = blockIdx.y * 8;

    const float4* sw = (const float4*)(sel_W2 + (size_t)h * EMB * HYP);
    #pragma unroll
    for (int j = 0; j < 16; ++j)
        ((float4*)ssel)[j * 256 + t] = sw[j * 256 + t];
    if (t < EMB) {
        #pragma unroll
        for (int kk = 0; kk < 8; ++kk)
            skey[t][kk] = key_W2[((size_t)h * EMB + t) * KHID + k0 + kk];
    }
    __syncthreads();

    const int e = t;
    float acc[8] = {};
    for (int d = 0; d < EMB; ++d) {
        const float sv = ssel[d * HYP + e];
        #pragma unroll
        for (int kk = 0; kk < 8; ++kk)
            acc[kk] = fmaf(sv, skey[d][kk], acc[kk]);
    }
    #pragma unroll
    for (int kk = 0; kk < 8; ++kk)
        M2T[((size_t)h * KHID + k0 + kk) * HYP + e] = f2bf(acc[kk]);
}

// ---------------------------------------------------------------------------
// K1: bf16 MFMA GEMM. M=4096 N=2560 K=1216. 128x128 tile, 4 waves, BK=32.
// ---------------------------------------------------------------------------
#define BK 32
__global__ __launch_bounds__(256) void k_gemm1_mfma(
    const ushort* __restrict__ Abf, const ushort* __restrict__ Wbf,
    const float* __restrict__ sel_b1, const float* __restrict__ wh_b1,
    const float* __restrict__ v_b1, ushort* __restrict__ h1bf)
{
    __shared__ ushort As[128 * BK];
    __shared__ ushort Bs[128 * BK];
    const int tid = threadIdx.x;
    const int l   = tid & 63;
    const int w   = tid >> 6;
    const int wM  = w >> 1, wN = w & 1;
    const int arow0 = blockIdx.y * 128;
    const int nrow0 = blockIdx.x * 128;

    const int srow = tid >> 2;
    const int skof = (tid & 3) * 8;
    const ushort* gA = Abf + (size_t)(arow0 + srow) * KPAD + skof;
    const ushort* gB = Wbf + (size_t)(nrow0 + srow) * KPAD + skof;
    ushort* lA = &As[srow * BK + skof];
    ushort* lB = &Bs[srow * BK + skof];

    floatx4 acc[4][4] = {};

    for (int k0 = 0; k0 < KPAD; k0 += BK) {
        GLL16(gA + k0, lA);
        GLL16(gA + (size_t)64 * KPAD + k0, lA + 64 * BK);
        GLL16(gB + k0, lB);
        GLL16(gB + (size_t)64 * KPAD + k0, lB + 64 * BK);
        __syncthreads();

        const int kch = (l >> 4) * 8;
        short8v av[4], bv[4];
        #pragma unroll
        for (int mi = 0; mi < 4; ++mi)
            av[mi] = *(const short8v*)&As[(wM * 64 + mi * 16 + (l & 15)) * BK + kch];
        #pragma unroll
        for (int ni = 0; ni < 4; ++ni)
            bv[ni] = *(const short8v*)&Bs[(wN * 64 + ni * 16 + (l & 15)) * BK + kch];
        #pragma unroll
        for (int mi = 0; mi < 4; ++mi)
            #pragma unroll
            for (int ni = 0; ni < 4; ++ni)
                acc[mi][ni] = __builtin_amdgcn_mfma_f32_16x16x32_bf16(
                    av[mi], bv[ni], acc[mi][ni], 0, 0, 0);
        __syncthreads();
    }

    float bias_n[4];
    #pragma unroll
    for (int ni = 0; ni < 4; ++ni) {
        const int col = nrow0 + wN * 64 + ni * 16 + (l & 15);
        bias_n[ni] = (col < NSEL)       ? sel_b1[col]
                   : (col < NSEL + HYP) ? wh_b1[col - NSEL]
                                        : v_b1[col - NSEL - HYP];
    }
    #pragma unroll
    for (int mi = 0; mi < 4; ++mi) {
        const int row = arow0 + wM * 64 + mi * 16 + (l >> 4) * 4;
        #pragma unroll
        for (int ni = 0; ni < 4; ++ni) {
            const int col = nrow0 + wN * 64 + ni * 16 + (l & 15);
            #pragma unroll
            for (int r = 0; r < 4; ++r)
                h1bf[(size_t)(row + r) * NTOT + col] =
                    f2bf(fmaxf(acc[mi][ni][r] + bias_n[ni], 0.f));
        }
    }
}

// ---------------------------------------------------------------------------
// K2: per-head m GEMM. m[b,h,k] = sum_e h1bf[b, h*256+e] * M2T[h][k][e].
// ---------------------------------------------------------------------------
__global__ __launch_bounds__(256) void k_m_mfma(
    const ushort* __restrict__ h1bf, const ushort* __restrict__ M2T,
    float* __restrict__ m_out)
{
    __shared__ ushort As[128 * BK];
    __shared__ ushort Bs[128 * BK];
    const int tid = threadIdx.x;
    const int l   = tid & 63;
    const int w   = tid >> 6;
    const int wM  = w >> 1, wN = w & 1;
    const int h     = blockIdx.x;
    const int brow0 = blockIdx.y * 128;

    const int srow = tid >> 2;
    const int skof = (tid & 3) * 8;
    const ushort* gA = h1bf + (size_t)(brow0 + srow) * NTOT + h * HYP + skof;
    const ushort* gB = M2T + ((size_t)h * KHID + srow) * HYP + skof;
    ushort* lA = &As[srow * BK + skof];
    ushort* lB = &Bs[srow * BK + skof];

    floatx4 acc[4][4] = {};

    for (int k0 = 0; k0 < HYP; k0 += BK) {
        GLL16(gA + k0, lA);
        GLL16(gA + (size_t)64 * NTOT + k0, lA + 64 * BK);
        GLL16(gB + k0, lB);
        GLL16(gB + (size_t)64 * HYP + k0, lB + 64 * BK);
        __syncthreads();

        const int kch = (l >> 4) * 8;
        short8v av[4], bv[4];
        #pragma unroll
        for (int mi = 0; mi < 4; ++mi)
            av[mi] = *(const short8v*)&As[(wM * 64 + mi * 16 + (l & 15)) * BK + kch];
        #pragma unroll
        for (int ni = 0; ni < 4; ++ni)
            bv[ni] = *(const short8v*)&Bs[(wN * 64 + ni * 16 + (l & 15)) * BK + kch];
        #pragma unroll
        for (int mi = 0; mi < 4; ++mi)
            #pragma unroll
            for (int ni = 0; ni < 4; ++ni)
                acc[mi][ni] = __builtin_amdgcn_mfma_f32_16x16x32_bf16(
                    av[mi], bv[ni], acc[mi][ni], 0, 0, 0);
        __syncthreads();
    }

    #pragma unroll
    for (int mi = 0; mi < 4; ++mi) {
        const int row = brow0 + wM * 64 + mi * 16 + (l >> 4) * 4;
        #pragma unroll
        for (int ni = 0; ni < 4; ++ni) {
            const int col = wN * 64 + ni * 16 + (l & 15);
            #pragma unroll
            for (int r = 0; r < 4; ++r)
                m_out[((size_t)(row + r) * NH + h) * KHID + col] = acc[mi][ni][r];
        }
    }
}

// ---------------------------------------------------------------------------
// K3 v2: logits. 1024 blocks x 256 thr. Block = 128 U-rows (4 batches), loops
// all 8 heads with double-buffered W (8KB). K=32; q-term rank-1 in epilogue.
// logits[b,h,a] = sum_k relu(U32.W[h,k] + q*w32[h,k] + b1[h,k]) * m[b,h,k]
// ---------------------------------------------------------------------------
__global__ __launch_bounds__(256) void k_logits_mfma(
    const ushort* __restrict__ Ubf, const ushort* __restrict__ KW32,
    const float* __restrict__ W32f, const float* __restrict__ key_b1,
    const float* __restrict__ agent_qs, const float* __restrict__ m_in,
    float* __restrict__ logits)
{
    __shared__ ushort Us[128 * 32];        // 8 KB (swizzled)
    __shared__ ushort Wd[2][128 * 32];     // 16 KB (swizzled)
    __shared__ float m_lds[4 * NH * KHID]; // 16 KB
    __shared__ float b1_lds[1024];         // 4 KB
    __shared__ float w32_lds[1024];        // 4 KB
    __shared__ float q_lds[128];
    __shared__ float red[128][2];
    const int tid = threadIdx.x;
    const int l = tid & 63;
    const int w = tid >> 6;
    const int wM = w >> 1, wN = w & 1;
    const int r0 = blockIdx.x * 128;   // global U-row base
    const int b0 = blockIdx.x * 4;     // batch base

    // prologue staging — all sources contiguous, LDS linear
    #pragma unroll
    for (int c = 0; c < 2; ++c)
        GLL16(Ubf + (size_t)r0 * 32 + c * 2048 + tid * 8, &Us[c * 2048 + tid * 8]);
    #pragma unroll
    for (int c = 0; c < 2; ++c)
        GLL16(KW32 + c * 2048 + tid * 8, &Wd[0][c * 2048 + tid * 8]);
    #pragma unroll
    for (int c = 0; c < 4; ++c)
        GLL16(m_in + (size_t)b0 * NH * KHID + c * 1024 + tid * 4,
              &m_lds[c * 1024 + tid * 4]);
    GLL16(key_b1 + tid * 4, &b1_lds[tid * 4]);
    GLL16(W32f + tid * 4, &w32_lds[tid * 4]);
    if (tid < 128) q_lds[tid] = agent_qs[r0 + tid];
    __syncthreads();

    // A-fragments + q registers (head-invariant)
    short8v av[4];
    float4 qv[4];
    #pragma unroll
    for (int mi = 0; mi < 4; ++mi) {
        const int row = wM * 64 + mi * 16 + (l & 15);
        av[mi] = *(const short8v*)&Us[row * 32 + (((l >> 4)) ^ ((row >> 1) & 3)) * 8];
        qv[mi] = *(const float4*)&q_lds[wM * 64 + mi * 16 + (l >> 4) * 4];
    }
    const int bi0 = wM * 2, bi1 = wM * 2 + 1;  // mi 0,1 -> bi0 ; mi 2,3 -> bi1

    int cur = 0;
    for (int h = 0; h < NH; ++h) {
        if (h < 7) {
            #pragma unroll
            for (int c = 0; c < 2; ++c)
                GLL16(KW32 + (size_t)(h + 1) * 4096 + c * 2048 + tid * 8,
                      &Wd[cur ^ 1][c * 2048 + tid * 8]);
        }
        short8v bv[4];
        float b1r[4], w32r[4], m0r[4], m1r[4];
        #pragma unroll
        for (int ni = 0; ni < 4; ++ni) {
            const int k = wN * 64 + ni * 16 + (l & 15);
            bv[ni] = *(const short8v*)&Wd[cur][k * 32 + (((l >> 4)) ^ ((k >> 1) & 3)) * 8];
            b1r[ni]  = b1_lds[h * 128 + k];
            w32r[ni] = w32_lds[h * 128 + k];
            m0r[ni]  = m_lds[bi0 * 1024 + h * 128 + k];
            m1r[ni]  = m_lds[bi1 * 1024 + h * 128 + k];
        }
        floatx4 acc[4][4] = {};
        #pragma unroll
        for (int mi = 0; mi < 4; ++mi)
            #pragma unroll
            for (int ni = 0; ni < 4; ++ni)
                acc[mi][ni] = __builtin_amdgcn_mfma_f32_16x16x32_bf16(
                    av[mi], bv[ni], acc[mi][ni], 0, 0, 0);

        #pragma unroll
        for (int mi = 0; mi < 4; ++mi) {
            const int rowbase = wM * 64 + mi * 16 + (l >> 4) * 4;
            float s0 = 0.f, s1 = 0.f, s2 = 0.f, s3 = 0.f;
            #pragma unroll
            for (int ni = 0; ni < 4; ++ni) {
                const float mv = (mi < 2) ? m0r[ni] : m1r[ni];
                s0 = fmaf(fmaxf(fmaf(qv[mi].x, w32r[ni], acc[mi][ni][0] + b1r[ni]), 0.f), mv, s0);
                s1 = fmaf(fmaxf(fmaf(qv[mi].y, w32r[ni], acc[mi][ni][1] + b1r[ni]), 0.f), mv, s1);
                s2 = fmaf(fmaxf(fmaf(qv[mi].z, w32r[ni], acc[mi][ni][2] + b1r[ni]), 0.f), mv, s2);
                s3 = fmaf(fmaxf(fmaf(qv[mi].w, w32r[ni], acc[mi][ni][3] + b1r[ni]), 0.f), mv, s3);
            }
            #pragma unroll
            for (int off = 8; off >= 1; off >>= 1) {
                s0 += __shfl_xor(s0, off);
                s1 += __shfl_xor(s1, off);
                s2 += __shfl_xor(s2, off);
                s3 += __shfl_xor(s3, off);
            }
            if ((l & 15) == 0) {
                red[rowbase + 0][wN] = s0;
                red[rowbase + 1][wN] = s1;
                red[rowbase + 2][wN] = s2;
                red[rowbase + 3][wN] = s3;
            }
        }
        __syncthreads();
        if (tid < 128) {
            const float sum = red[tid][0] + red[tid][1];
            logits[((size_t)(b0 + (tid >> 5)) * NH + h) * NA + (tid & 31)] = sum;
        }
        __syncthreads();
        cur ^= 1;
    }
}

// ---------------------------------------------------------------------------
// K4: wh/v second layers + masked softmax + head_q + final mix.
// ---------------------------------------------------------------------------
__global__ __launch_bounds__(256) void k_softmax(
    const float* __restrict__ logits, const float* __restrict__ agent_qs,
    const int* __restrict__ actions, const ushort* __restrict__ h1bf,
    const float* __restrict__ wh_W2, const float* __restrict__ wh_b2,
    const float* __restrict__ v_W2, const float* __restrict__ v_b2,
    float* __restrict__ out, float* __restrict__ part)
{
    __shared__ float qs[NA];
    __shared__ int   act_s[NA];
    __shared__ float whs[NH];
    __shared__ float hq[NH];
    __shared__ float vred[4];
    const int b = blockIdx.x, t = threadIdx.x;
    if (t < NA) {
        qs[t]    = agent_qs[(size_t)b * NA + t];
        act_s[t] = actions[(size_t)b * NA + t];
    }
    const int h = t >> 5, a = t & 31;
    {
        float acc = 0.f;
        #pragma unroll
        for (int j = 0; j < 8; ++j) {
            const int e = a + 32 * j;
            acc = fmaf(bf2f(h1bf[(size_t)b * NTOT + NSEL + e]),
                       wh_W2[h * HYP + e], acc);
        }
        #pragma unroll
        for (int off = 16; off >= 1; off >>= 1) acc += __shfl_xor(acc, off, 32);
        if (a == 0) whs[h] = fabsf(acc + wh_b2[h]);
    }
    {
        float acc = bf2f(h1bf[(size_t)b * NTOT + NSEL + HYP + t]) * v_W2[t];
        #pragma unroll
        for (int off = 32; off >= 1; off >>= 1) acc += __shfl_xor(acc, off);
        if ((t & 63) == 0) vred[t >> 6] = acc;
    }
    __syncthreads();

    const float lg = logits[((size_t)b * NH + h) * NA + a];
    float sc = (act_s[a] == 0) ? -99999999.0f : lg * 0.125f;

    float mx = sc;
    #pragma unroll
    for (int off = 16; off >= 1; off >>= 1) mx = fmaxf(mx, __shfl_xor(mx, off, 32));
    const float e = expf(sc - mx);
    float sum = e;
    #pragma unroll
    for (int off = 16; off >= 1; off >>= 1) sum += __shfl_xor(sum, off, 32);
    const float wgt = e / sum;

    float r_sq  = lg * lg;
    float r_hq  = qs[a] * wgt;
    float r_ent = -wgt * logf(wgt + 1e-8f);
    #pragma unroll
    for (int off = 16; off >= 1; off >>= 1) {
        r_sq  += __shfl_xor(r_sq,  off, 32);
        r_hq  += __shfl_xor(r_hq,  off, 32);
        r_ent += __shfl_xor(r_ent, off, 32);
    }
    if (a == 0) {
        hq[h] = r_hq;
        part[(size_t)b * 16 + h]     = r_sq;
        part[(size_t)b * 16 + 8 + h] = r_ent;
    }
    __syncthreads();
    if (t == 0) {
        float y = vred[0] + vred[1] + vred[2] + vred[3] + v_b2[0];
        #pragma unroll
        for (int i = 0; i < NH; ++i) y = fmaf(whs[i], hq[i], y);
        out[b] = y;
    }
}

// ---------------------------------------------------------------------------
// K5a/K5b: two-stage partials reduction.
// ---------------------------------------------------------------------------
__global__ __launch_bounds__(256) void k_final_s1(
    const float* __restrict__ part, float* __restrict__ part2)
{
    __shared__ float red[16][17];
    const int t = threadIdx.x;
    const int c = t & 15, rl = t >> 4;
    const int rbase = blockIdx.x * 128 + rl;
    float v0 = 0.f, v1 = 0.f, v2 = 0.f, v3 = 0.f;
    #pragma unroll
    for (int j = 0; j < 8; j += 4) {
        v0 += part[(size_t)(rbase + (j + 0) * 16) * 16 + c];
        v1 += part[(size_t)(rbase + (j + 1) * 16) * 16 + c];
        v2 += part[(size_t)(rbase + (j + 2) * 16) * 16 + c];
        v3 += part[(size_t)(rbase + (j + 3) * 16) * 16 + c];
    }
    red[rl][c] = (v0 + v1) + (v2 + v3);
    __syncthreads();
    if (t < 16) {
        float s = 0.f;
        #pragma unroll
        for (int i = 0; i < 16; ++i) s += red[i][t];
        part2[blockIdx.x * 16 + t] = s;
    }
}

__global__ __launch_bounds__(256) void k_final_s2(
    const float* __restrict__ part2, float* __restrict__ out)
{
    __shared__ float red[16][17];
    __shared__ float tot[16];
    const int t = threadIdx.x;
    {
        const int g = t >> 4, c = t & 15;
        red[g][c] = part2[t] + part2[t + 256];
    }
    __syncthreads();
    if (t < 16) {
        float s = 0.f;
        #pragma unroll
        for (int i = 0; i < 16; ++i) s += red[i][t];
        tot[t] = s;
    }
    __syncthreads();
    if (t == 0) {
        float s = 0.f;
        #pragma unroll
        for (int i = 0; i < 8; ++i) s += tot[i];
        out[B_TOT] = 0.001f * (s / (float)((size_t)B_TOT * NA));
    }
    if (t >= 8 && t < 16)
        out[B_TOT + 1 + (t - 8)] = tot[t] / (float)B_TOT;
}

extern "C" void kernel_launch(void* const* d_in, const int* in_sizes, int n_in,
                              void* d_out, int out_size, void* d_ws, size_t ws_size,
                              hipStream_t stream) {
    (void)in_sizes; (void)n_in; (void)out_size; (void)ws_size;
    const float* agent_qs = (const float*)d_in[0];
    const float* states   = (const float*)d_in[1];
    const int*   actions  = (const int*)d_in[2];
    const float* sel_W1   = (const float*)d_in[3];
    const float* sel_b1   = (const float*)d_in[4];
    const float* sel_W2   = (const float*)d_in[5];
    const float* key_W1   = (const float*)d_in[6];
    const float* key_b1   = (const float*)d_in[7];
    const float* key_W2   = (const float*)d_in[8];
    const float* wh_W1    = (const float*)d_in[9];
    const float* wh_b1    = (const float*)d_in[10];
    const float* wh_W2    = (const float*)d_in[11];
    const float* wh_b2    = (const float*)d_in[12];
    const float* v_W1     = (const float*)d_in[13];
    const float* v_b1     = (const float*)d_in[14];
    const float* v_W2     = (const float*)d_in[15];
    const float* v_b2     = (const float*)d_in[16];

    float* out = (float*)d_out;
    float* ws  = (float*)d_ws;
    ushort* h1bf  = (ushort*)(ws + WS_H1BF);
    float* m_buf  = ws + WS_M;
    float* lg_buf = ws + WS_LG;
    float* part   = ws + WS_PART;
    float* part2  = ws + WS_P2;
    ushort* Abf   = (ushort*)(ws + WS_ABF);
    ushort* Wbf   = (ushort*)(ws + WS_WBF);
    ushort* KW32  = (ushort*)(ws + WS_KW32);
    float*  W32f  = ws + WS_W32F;
    ushort* M2T   = (ushort*)(ws + WS_M2T);
    ushort* Ubf   = (ushort*)(ws + WS_UBF);

    {
        const int groups_a = B_TOT * (KPAD / 4);
        const int groups_w = NTOT * (KPAD / 4);
        k_cvt_states<<<(groups_a + 255) / 256, 256, 0, stream>>>(states, Abf);
        k_cvt_w<<<(groups_w + 255) / 256, 256, 0, stream>>>(sel_W1, wh_W1, v_W1, Wbf);
        k_cvt_kw2<<<4, 256, 0, stream>>>(key_W1, KW32, W32f);
        k_cvt_units<<<(B_TOT * NA + 255) / 256, 256, 0, stream>>>(states, Ubf);
        k_m2<<<dim3(NH, KHID / 8), 256, 0, stream>>>(sel_W2, key_W2, M2T);
    }
    k_gemm1_mfma<<<dim3(NTOT / 128, B_TOT / 128), 256, 0, stream>>>(
        Abf, Wbf, sel_b1, wh_b1, v_b1, h1bf);
    k_m_mfma<<<dim3(NH, B_TOT / 128), 256, 0, stream>>>(h1bf, M2T, m_buf);
    k_logits_mfma<<<dim3((B_TOT * NA) / 128), 256, 0, stream>>>(
        Ubf, KW32, W32f, key_b1, agent_qs, m_buf, lg_buf);
    k_softmax<<<dim3(B_TOT), 256, 0, stream>>>(
        lg_buf, agent_qs, actions, h1bf, wh_W2, wh_b2, v_W2, v_b2, out, part);
    k_final_s1<<<32, 256, 0, stream>>>(part, part2);
    k_final_s2<<<1, 256, 0, stream>>>(part2, out);
}

// Round 8
// 123.144 us; speedup vs baseline: 8.6440x; 1.0605x over previous
//
#include <hip/hip_runtime.h>

#define B_TOT 4096
#define SDIM  1200
#define KPAD  1216   // SDIM padded to multiple of 64 for MFMA K-loop
#define NA    32
#define NH    8
#define EMB   64
#define KHID  128
#define HYP   256
#define NSEL  2048   // NH*HYP
#define NTOT  2560   // NSEL + 256 (wh hid) + 256 (v hid)

// workspace layout (float offsets)
#define WS_H1BF 0                                              // bf16 h1 [B_TOT][NTOT]
#define WS_M    (WS_H1BF + (size_t)B_TOT * NTOT / 2)           // fp32 m [B_TOT][NH][KHID]
#define WS_LG   (WS_M    + (size_t)B_TOT * NH * KHID)
#define WS_PART (WS_LG   + (size_t)B_TOT * NH * NA)
#define WS_P2   (WS_PART + (size_t)B_TOT * 16)
#define WS_ABF  (WS_P2   + (size_t)32 * 16)                    // bf16 states [B_TOT][KPAD]
#define WS_WBF  (WS_ABF  + (size_t)B_TOT * KPAD / 2)           // bf16 W1 [NTOT][KPAD]
#define WS_KW32 (WS_WBF  + (size_t)NTOT * KPAD / 2)            // bf16 key_W1[:, :32] [1024][32] linear
#define WS_W32F (WS_KW32 + (size_t)1024 * 32 / 2)              // fp32 key_W1[:, 32] [1024]
#define WS_M2T  (WS_W32F + (size_t)1024)                       // bf16 M2T [NH][KHID][HYP]
#define WS_UBF  (WS_M2T  + (size_t)NH * KHID * HYP / 2)        // bf16 units [B_TOT*NA][32] linear

typedef __attribute__((ext_vector_type(8))) short short8v;
typedef __attribute__((ext_vector_type(4))) float floatx4;

#define GLL16(gsrc, ldst) __builtin_amdgcn_global_load_lds( \
    (const __attribute__((address_space(1))) unsigned int*)(gsrc), \
    (__attribute__((address_space(3))) unsigned int*)(ldst), 16, 0, 0)

__device__ __forceinline__ ushort f2bf(float x) {
    unsigned u = __builtin_bit_cast(unsigned, x);
    unsigned r = (u + 0x7FFFu + ((u >> 16) & 1u)) >> 16;
    return (ushort)r;
}
__device__ __forceinline__ float bf2f(ushort u) {
    unsigned x = ((unsigned)u) << 16;
    return __builtin_bit_cast(float, x);
}

// ---------------------------------------------------------------------------
// fp32 -> bf16 conversions
// ---------------------------------------------------------------------------
__global__ __launch_bounds__(256) void k_cvt_states(
    const float* __restrict__ src, ushort* __restrict__ dst)
{
    const size_t g = (size_t)blockIdx.x * 256 + threadIdx.x;
    if (g >= (size_t)B_TOT * (KPAD / 4)) return;
    const int row = (int)(g / (KPAD / 4));
    const int c4  = (int)(g % (KPAD / 4)) * 4;
    ushort4 o = {0, 0, 0, 0};
    if (c4 < SDIM) {
        float4 v = *(const float4*)(src + (size_t)row * SDIM + c4);
        o.x = f2bf(v.x); o.y = f2bf(v.y); o.z = f2bf(v.z); o.w = f2bf(v.w);
    }
    *(ushort4*)(dst + (size_t)row * KPAD + c4) = o;
}

__global__ __launch_bounds__(256) void k_cvt_w(
    const float* __restrict__ sel_W1, const float* __restrict__ wh_W1,
    const float* __restrict__ v_W1, ushort* __restrict__ dst)
{
    const size_t g = (size_t)blockIdx.x * 256 + threadIdx.x;
    if (g >= (size_t)NTOT * (KPAD / 4)) return;
    const int row = (int)(g / (KPAD / 4));
    const int c4  = (int)(g % (KPAD / 4)) * 4;
    const float* src = (row < NSEL)       ? (sel_W1 + (size_t)row * SDIM)
                     : (row < NSEL + HYP) ? (wh_W1 + (size_t)(row - NSEL) * SDIM)
                                          : (v_W1  + (size_t)(row - NSEL - HYP) * SDIM);
    ushort4 o = {0, 0, 0, 0};
    if (c4 < SDIM) {
        float4 v = *(const float4*)(src + c4);
        o.x = f2bf(v.x); o.y = f2bf(v.y); o.z = f2bf(v.z); o.w = f2bf(v.w);
    }
    *(ushort4*)(dst + (size_t)row * KPAD + c4) = o;
}

// units[b][a][u] bf16 [131072][32] linear. One thread per row.
__global__ __launch_bounds__(256) void k_cvt_units(
    const float* __restrict__ states, ushort* __restrict__ dst)
{
    const int row = blockIdx.x * 256 + threadIdx.x;
    if (row >= B_TOT * NA) return;
    const int b = row >> 5, a = row & 31;
    const float* s = states + (size_t)b * SDIM + a * 32;
    ushort o[32];
    #pragma unroll
    for (int j = 0; j < 8; ++j) {
        float4 v = *(const float4*)(s + j * 4);
        o[j * 4 + 0] = f2bf(v.x); o[j * 4 + 1] = f2bf(v.y);
        o[j * 4 + 2] = f2bf(v.z); o[j * 4 + 3] = f2bf(v.w);
    }
    #pragma unroll
    for (int c = 0; c < 4; ++c)
        *(short8v*)(dst + (size_t)row * 32 + c * 8) = *(short8v*)&o[c * 8];
}

// key_W1 [1024][33] -> KW32 bf16 [1024][32] linear + W32f fp32 [1024].
__global__ __launch_bounds__(256) void k_cvt_kw2(
    const float* __restrict__ key_W1, ushort* __restrict__ kw32,
    float* __restrict__ w32f)
{
    const int row = blockIdx.x * 256 + threadIdx.x;
    if (row >= 1024) return;
    const float* srcr = key_W1 + (size_t)row * 33;
    ushort o[32];
    #pragma unroll
    for (int u = 0; u < 32; ++u) o[u] = f2bf(srcr[u]);
    #pragma unroll
    for (int c = 0; c < 4; ++c)
        *(short8v*)(kw32 + (size_t)row * 32 + c * 8) = *(short8v*)&o[c * 8];
    w32f[row] = srcr[32];
}

// ---------------------------------------------------------------------------
// M2T[h][k][e] = sum_d sel_W2[h][d][e] * key_W2[h][d][k]  (bf16 out)
// ---------------------------------------------------------------------------
__global__ __launch_bounds__(256) void k_m2(
    const float* __restrict__ sel_W2, const float* __restrict__ key_W2,
    ushort* __restrict__ M2T)
{
    __shared__ float ssel[EMB * HYP];
    __shared__ float skey[EMB][8];
    const int t  = threadIdx.x;
    const int h  = blockIdx.x;
    const int k0 = blockIdx.y * 8;

    const float4* sw = (const float4*)(sel_W2 + (size_t)h * EMB * HYP);
    #pragma unroll
    for (int j = 0; j < 16; ++j)
        ((float4*)ssel)[j * 256 + t] = sw[j * 256 + t];
    if (t < EMB) {
        #pragma unroll
        for (int kk = 0; kk < 8; ++kk)
            skey[t][kk] = key_W2[((size_t)h * EMB + t) * KHID + k0 + kk];
    }
    __syncthreads();

    const int e = t;
    float acc[8] = {};
    for (int d = 0; d < EMB; ++d) {
        const float sv = ssel[d * HYP + e];
        #pragma unroll
        for (int kk = 0; kk < 8; ++kk)
            acc[kk] = fmaf(sv, skey[d][kk], acc[kk]);
    }
    #pragma unroll
    for (int kk = 0; kk < 8; ++kk)
        M2T[((size_t)h * KHID + k0 + kk) * HYP + e] = f2bf(acc[kk]);
}

// ---------------------------------------------------------------------------
// K1: bf16 MFMA GEMM. M=4096 N=2560 K=1216. 128x128 tile, 4 waves, BK=32.
// ---------------------------------------------------------------------------
#define BK 32
__global__ __launch_bounds__(256) void k_gemm1_mfma(
    const ushort* __restrict__ Abf, const ushort* __restrict__ Wbf,
    const float* __restrict__ sel_b1, const float* __restrict__ wh_b1,
    const float* __restrict__ v_b1, ushort* __restrict__ h1bf)
{
    __shared__ ushort As[128 * BK];
    __shared__ ushort Bs[128 * BK];
    const int tid = threadIdx.x;
    const int l   = tid & 63;
    const int w   = tid >> 6;
    const int wM  = w >> 1, wN = w & 1;
    const int arow0 = blockIdx.y * 128;
    const int nrow0 = blockIdx.x * 128;

    const int srow = tid >> 2;
    const int skof = (tid & 3) * 8;
    const ushort* gA = Abf + (size_t)(arow0 + srow) * KPAD + skof;
    const ushort* gB = Wbf + (size_t)(nrow0 + srow) * KPAD + skof;
    ushort* lA = &As[srow * BK + skof];
    ushort* lB = &Bs[srow * BK + skof];

    floatx4 acc[4][4] = {};

    for (int k0 = 0; k0 < KPAD; k0 += BK) {
        GLL16(gA + k0, lA);
        GLL16(gA + (size_t)64 * KPAD + k0, lA + 64 * BK);
        GLL16(gB + k0, lB);
        GLL16(gB + (size_t)64 * KPAD + k0, lB + 64 * BK);
        __syncthreads();

        const int kch = (l >> 4) * 8;
        short8v av[4], bv[4];
        #pragma unroll
        for (int mi = 0; mi < 4; ++mi)
            av[mi] = *(const short8v*)&As[(wM * 64 + mi * 16 + (l & 15)) * BK + kch];
        #pragma unroll
        for (int ni = 0; ni < 4; ++ni)
            bv[ni] = *(const short8v*)&Bs[(wN * 64 + ni * 16 + (l & 15)) * BK + kch];
        #pragma unroll
        for (int mi = 0; mi < 4; ++mi)
            #pragma unroll
            for (int ni = 0; ni < 4; ++ni)
                acc[mi][ni] = __builtin_amdgcn_mfma_f32_16x16x32_bf16(
                    av[mi], bv[ni], acc[mi][ni], 0, 0, 0);
        __syncthreads();
    }

    float bias_n[4];
    #pragma unroll
    for (int ni = 0; ni < 4; ++ni) {
        const int col = nrow0 + wN * 64 + ni * 16 + (l & 15);
        bias_n[ni] = (col < NSEL)       ? sel_b1[col]
                   : (col < NSEL + HYP) ? wh_b1[col - NSEL]
                                        : v_b1[col - NSEL - HYP];
    }
    #pragma unroll
    for (int mi = 0; mi < 4; ++mi) {
        const int row = arow0 + wM * 64 + mi * 16 + (l >> 4) * 4;
        #pragma unroll
        for (int ni = 0; ni < 4; ++ni) {
            const int col = nrow0 + wN * 64 + ni * 16 + (l & 15);
            #pragma unroll
            for (int r = 0; r < 4; ++r)
                h1bf[(size_t)(row + r) * NTOT + col] =
                    f2bf(fmaxf(acc[mi][ni][r] + bias_n[ni], 0.f));
        }
    }
}

// ---------------------------------------------------------------------------
// K2: per-head m GEMM. m[b,h,k] = sum_e h1bf[b, h*256+e] * M2T[h][k][e].
// ---------------------------------------------------------------------------
__global__ __launch_bounds__(256) void k_m_mfma(
    const ushort* __restrict__ h1bf, const ushort* __restrict__ M2T,
    float* __restrict__ m_out)
{
    __shared__ ushort As[128 * BK];
    __shared__ ushort Bs[128 * BK];
    const int tid = threadIdx.x;
    const int l   = tid & 63;
    const int w   = tid >> 6;
    const int wM  = w >> 1, wN = w & 1;
    const int h     = blockIdx.x;
    const int brow0 = blockIdx.y * 128;

    const int srow = tid >> 2;
    const int skof = (tid & 3) * 8;
    const ushort* gA = h1bf + (size_t)(brow0 + srow) * NTOT + h * HYP + skof;
    const ushort* gB = M2T + ((size_t)h * KHID + srow) * HYP + skof;
    ushort* lA = &As[srow * BK + skof];
    ushort* lB = &Bs[srow * BK + skof];

    floatx4 acc[4][4] = {};

    for (int k0 = 0; k0 < HYP; k0 += BK) {
        GLL16(gA + k0, lA);
        GLL16(gA + (size_t)64 * NTOT + k0, lA + 64 * BK);
        GLL16(gB + k0, lB);
        GLL16(gB + (size_t)64 * HYP + k0, lB + 64 * BK);
        __syncthreads();

        const int kch = (l >> 4) * 8;
        short8v av[4], bv[4];
        #pragma unroll
        for (int mi = 0; mi < 4; ++mi)
            av[mi] = *(const short8v*)&As[(wM * 64 + mi * 16 + (l & 15)) * BK + kch];
        #pragma unroll
        for (int ni = 0; ni < 4; ++ni)
            bv[ni] = *(const short8v*)&Bs[(wN * 64 + ni * 16 + (l & 15)) * BK + kch];
        #pragma unroll
        for (int mi = 0; mi < 4; ++mi)
            #pragma unroll
            for (int ni = 0; ni < 4; ++ni)
                acc[mi][ni] = __builtin_amdgcn_mfma_f32_16x16x32_bf16(
                    av[mi], bv[ni], acc[mi][ni], 0, 0, 0);
        __syncthreads();
    }

    #pragma unroll
    for (int mi = 0; mi < 4; ++mi) {
        const int row = brow0 + wM * 64 + mi * 16 + (l >> 4) * 4;
        #pragma unroll
        for (int ni = 0; ni < 4; ++ni) {
            const int col = wN * 64 + ni * 16 + (l & 15);
            #pragma unroll
            for (int r = 0; r < 4; ++r)
                m_out[((size_t)(row + r) * NH + h) * KHID + col] = acc[mi][ni][r];
        }
    }
}

// ---------------------------------------------------------------------------
// K3 v3: logits — barrier-free, LDS-free. Grid 1024x256; wave = one batch.
// Wave computes 32 rows x 128 k per head, fragments loaded straight from
// global (per-lane 16B, coalesced). k-reduction in registers + 16-lane shfl.
// logits[b,h,a] = sum_k relu(U32.W[h,k] + q*w32[h,k] + b1[h,k]) * m[b,h,k]
// ---------------------------------------------------------------------------
__global__ __launch_bounds__(256) void k_logits_mfma(
    const ushort* __restrict__ Ubf, const ushort* __restrict__ KW32,
    const float* __restrict__ W32f, const float* __restrict__ key_b1,
    const float* __restrict__ agent_qs, const float* __restrict__ m_in,
    float* __restrict__ logits)
{
    const int tid = threadIdx.x;
    const int l   = tid & 63;
    const int w   = tid >> 6;
    const int b   = blockIdx.x * 4 + w;    // batch owned by this wave
    const int urow0 = b * NA;              // its 32 unit-rows

    // head-invariant A fragments + q (C-layout rows)
    short8v av[2];
    float4 qv[2];
    #pragma unroll
    for (int mi = 0; mi < 2; ++mi) {
        av[mi] = *(const short8v*)(
            Ubf + (size_t)(urow0 + mi * 16 + (l & 15)) * 32 + (l >> 4) * 8);
        qv[mi] = *(const float4*)(
            agent_qs + (size_t)b * NA + mi * 16 + (l >> 4) * 4);
    }

    for (int h = 0; h < NH; ++h) {
        short8v bv[8];
        float b1r[8], w32r[8], mr[8];
        #pragma unroll
        for (int ni = 0; ni < 8; ++ni) {
            const int k = ni * 16 + (l & 15);
            bv[ni]   = *(const short8v*)(
                KW32 + ((size_t)h * KHID + k) * 32 + (l >> 4) * 8);
            b1r[ni]  = key_b1[h * KHID + k];
            w32r[ni] = W32f[h * KHID + k];
            mr[ni]   = m_in[((size_t)b * NH + h) * KHID + k];
        }
        floatx4 acc[2][8] = {};
        #pragma unroll
        for (int mi = 0; mi < 2; ++mi)
            #pragma unroll
            for (int ni = 0; ni < 8; ++ni)
                acc[mi][ni] = __builtin_amdgcn_mfma_f32_16x16x32_bf16(
                    av[mi], bv[ni], acc[mi][ni], 0, 0, 0);

        #pragma unroll
        for (int mi = 0; mi < 2; ++mi) {
            float s0 = 0.f, s1 = 0.f, s2 = 0.f, s3 = 0.f;
            #pragma unroll
            for (int ni = 0; ni < 8; ++ni) {
                const float b1v = b1r[ni], wv = w32r[ni], mv = mr[ni];
                s0 = fmaf(fmaxf(fmaf(qv[mi].x, wv, acc[mi][ni][0] + b1v), 0.f), mv, s0);
                s1 = fmaf(fmaxf(fmaf(qv[mi].y, wv, acc[mi][ni][1] + b1v), 0.f), mv, s1);
                s2 = fmaf(fmaxf(fmaf(qv[mi].z, wv, acc[mi][ni][2] + b1v), 0.f), mv, s2);
                s3 = fmaf(fmaxf(fmaf(qv[mi].w, wv, acc[mi][ni][3] + b1v), 0.f), mv, s3);
            }
            #pragma unroll
            for (int off = 8; off >= 1; off >>= 1) {
                s0 += __shfl_xor(s0, off);
                s1 += __shfl_xor(s1, off);
                s2 += __shfl_xor(s2, off);
                s3 += __shfl_xor(s3, off);
            }
            if ((l & 15) == 0) {
                float4 o = {s0, s1, s2, s3};
                *(float4*)(logits + ((size_t)b * NH + h) * NA
                           + mi * 16 + (l >> 4) * 4) = o;
            }
        }
    }
}

// ---------------------------------------------------------------------------
// K4: wh/v second layers + masked softmax + head_q + final mix.
// ---------------------------------------------------------------------------
__global__ __launch_bounds__(256) void k_softmax(
    const float* __restrict__ logits, const float* __restrict__ agent_qs,
    const int* __restrict__ actions, const ushort* __restrict__ h1bf,
    const float* __restrict__ wh_W2, const float* __restrict__ wh_b2,
    const float* __restrict__ v_W2, const float* __restrict__ v_b2,
    float* __restrict__ out, float* __restrict__ part)
{
    __shared__ float qs[NA];
    __shared__ int   act_s[NA];
    __shared__ float whs[NH];
    __shared__ float hq[NH];
    __shared__ float vred[4];
    const int b = blockIdx.x, t = threadIdx.x;
    if (t < NA) {
        qs[t]    = agent_qs[(size_t)b * NA + t];
        act_s[t] = actions[(size_t)b * NA + t];
    }
    const int h = t >> 5, a = t & 31;
    {
        float acc = 0.f;
        #pragma unroll
        for (int j = 0; j < 8; ++j) {
            const int e = a + 32 * j;
            acc = fmaf(bf2f(h1bf[(size_t)b * NTOT + NSEL + e]),
                       wh_W2[h * HYP + e], acc);
        }
        #pragma unroll
        for (int off = 16; off >= 1; off >>= 1) acc += __shfl_xor(acc, off, 32);
        if (a == 0) whs[h] = fabsf(acc + wh_b2[h]);
    }
    {
        float acc = bf2f(h1bf[(size_t)b * NTOT + NSEL + HYP + t]) * v_W2[t];
        #pragma unroll
        for (int off = 32; off >= 1; off >>= 1) acc += __shfl_xor(acc, off);
        if ((t & 63) == 0) vred[t >> 6] = acc;
    }
    __syncthreads();

    const float lg = logits[((size_t)b * NH + h) * NA + a];
    float sc = (act_s[a] == 0) ? -99999999.0f : lg * 0.125f;

    float mx = sc;
    #pragma unroll
    for (int off = 16; off >= 1; off >>= 1) mx = fmaxf(mx, __shfl_xor(mx, off, 32));
    const float e = expf(sc - mx);
    float sum = e;
    #pragma unroll
    for (int off = 16; off >= 1; off >>= 1) sum += __shfl_xor(sum, off, 32);
    const float wgt = e / sum;

    float r_sq  = lg * lg;
    float r_hq  = qs[a] * wgt;
    float r_ent = -wgt * logf(wgt + 1e-8f);
    #pragma unroll
    for (int off = 16; off >= 1; off >>= 1) {
        r_sq  += __shfl_xor(r_sq,  off, 32);
        r_hq  += __shfl_xor(r_hq,  off, 32);
        r_ent += __shfl_xor(r_ent, off, 32);
    }
    if (a == 0) {
        hq[h] = r_hq;
        part[(size_t)b * 16 + h]     = r_sq;
        part[(size_t)b * 16 + 8 + h] = r_ent;
    }
    __syncthreads();
    if (t == 0) {
        float y = vred[0] + vred[1] + vred[2] + vred[3] + v_b2[0];
        #pragma unroll
        for (int i = 0; i < NH; ++i) y = fmaf(whs[i], hq[i], y);
        out[b] = y;
    }
}

// ---------------------------------------------------------------------------
// K5a/K5b: two-stage partials reduction.
// ---------------------------------------------------------------------------
__global__ __launch_bounds__(256) void k_final_s1(
    const float* __restrict__ part, float* __restrict__ part2)
{
    __shared__ float red[16][17];
    const int t = threadIdx.x;
    const int c = t & 15, rl = t >> 4;
    const int rbase = blockIdx.x * 128 + rl;
    float v0 = 0.f, v1 = 0.f, v2 = 0.f, v3 = 0.f;
    #pragma unroll
    for (int j = 0; j < 8; j += 4) {
        v0 += part[(size_t)(rbase + (j + 0) * 16) * 16 + c];
        v1 += part[(size_t)(rbase + (j + 1) * 16) * 16 + c];
        v2 += part[(size_t)(rbase + (j + 2) * 16) * 16 + c];
        v3 += part[(size_t)(rbase + (j + 3) * 16) * 16 + c];
    }
    red[rl][c] = (v0 + v1) + (v2 + v3);
    __syncthreads();
    if (t < 16) {
        float s = 0.f;
        #pragma unroll
        for (int i = 0; i < 16; ++i) s += red[i][t];
        part2[blockIdx.x * 16 + t] = s;
    }
}

__global__ __launch_bounds__(256) void k_final_s2(
    const float* __restrict__ part2, float* __restrict__ out)
{
    __shared__ float red[16][17];
    __shared__ float tot[16];
    const int t = threadIdx.x;
    {
        const int g = t >> 4, c = t & 15;
        red[g][c] = part2[t] + part2[t + 256];
    }
    __syncthreads();
    if (t < 16) {
        float s = 0.f;
        #pragma unroll
        for (int i = 0; i < 16; ++i) s += red[i][t];
        tot[t] = s;
    }
    __syncthreads();
    if (t == 0) {
        float s = 0.f;
        #pragma unroll
        for (int i = 0; i < 8; ++i) s += tot[i];
        out[B_TOT] = 0.001f * (s / (float)((size_t)B_TOT * NA));
    }
    if (t >= 8 && t < 16)
        out[B_TOT + 1 + (t - 8)] = tot[t] / (float)B_TOT;
}

extern "C" void kernel_launch(void* const* d_in, const int* in_sizes, int n_in,
                              void* d_out, int out_size, void* d_ws, size_t ws_size,
                              hipStream_t stream) {
    (void)in_sizes; (void)n_in; (void)out_size; (void)ws_size;
    const float* agent_qs = (const float*)d_in[0];
    const float* states   = (const float*)d_in[1];
    const int*   actions  = (const int*)d_in[2];
    const float* sel_W1   = (const float*)d_in[3];
    const float* sel_b1   = (const float*)d_in[4];
    const float* sel_W2   = (const float*)d_in[5];
    const float* key_W1   = (const float*)d_in[6];
    const float* key_b1   = (const float*)d_in[7];
    const float* key_W2   = (const float*)d_in[8];
    const float* wh_W1    = (const float*)d_in[9];
    const float* wh_b1    = (const float*)d_in[10];
    const float* wh_W2    = (const float*)d_in[11];
    const float* wh_b2    = (const float*)d_in[12];
    const float* v_W1     = (const float*)d_in[13];
    const float* v_b1     = (const float*)d_in[14];
    const float* v_W2     = (const float*)d_in[15];
    const float* v_b2     = (const float*)d_in[16];

    float* out = (float*)d_out;
    float* ws  = (float*)d_ws;
    ushort* h1bf  = (ushort*)(ws + WS_H1BF);
    float* m_buf  = ws + WS_M;
    float* lg_buf = ws + WS_LG;
    float* part   = ws + WS_PART;
    float* part2  = ws + WS_P2;
    ushort* Abf   = (ushort*)(ws + WS_ABF);
    ushort* Wbf   = (ushort*)(ws + WS_WBF);
    ushort* KW32  = (ushort*)(ws + WS_KW32);
    float*  W32f  = ws + WS_W32F;
    ushort* M2T   = (ushort*)(ws + WS_M2T);
    ushort* Ubf   = (ushort*)(ws + WS_UBF);

    {
        const int groups_a = B_TOT * (KPAD / 4);
        const int groups_w = NTOT * (KPAD / 4);
        k_cvt_states<<<(groups_a + 255) / 256, 256, 0, stream>>>(states, Abf);
        k_cvt_w<<<(groups_w + 255) / 256, 256, 0, stream>>>(sel_W1, wh_W1, v_W1, Wbf);
        k_cvt_kw2<<<4, 256, 0, stream>>>(key_W1, KW32, W32f);
        k_cvt_units<<<(B_TOT * NA + 255) / 256, 256, 0, stream>>>(states, Ubf);
        k_m2<<<dim3(NH, KHID / 8), 256, 0, stream>>>(sel_W2, key_W2, M2T);
    }
    k_gemm1_mfma<<<dim3(NTOT / 128, B_TOT / 128), 256, 0, stream>>>(
        Abf, Wbf, sel_b1, wh_b1, v_b1, h1bf);
    k_m_mfma<<<dim3(NH, B_TOT / 128), 256, 0, stream>>>(h1bf, M2T, m_buf);
    k_logits_mfma<<<dim3(B_TOT / 4), 256, 0, stream>>>(
        Ubf, KW32, W32f, key_b1, agent_qs, m_buf, lg_buf);
    k_softmax<<<dim3(B_TOT), 256, 0, stream>>>(
        lg_buf, agent_qs, actions, h1bf, wh_W2, wh_b2, v_W2, v_b2, out, part);
    k_final_s1<<<32, 256, 0, stream>>>(part, part2);
    k_final_s2<<<1, 256, 0, stream>>>(part2, out);
}